// Round 8
// baseline (282.942 us; speedup 1.0000x reference)
//
#include <hip/hip_runtime.h>
#include <hip/hip_bf16.h>

typedef __attribute__((ext_vector_type(8))) short bf16x8;
typedef __attribute__((ext_vector_type(4))) float f32x4;
typedef __attribute__((ext_vector_type(4))) short s16x4;

#define GLOBAL_AS(p) ((const __attribute__((address_space(1))) void*)(p))
#define LDS_AS(p)    ((__attribute__((address_space(3))) void*)(p))

__device__ __forceinline__ short f2bf(float f) {
  return __builtin_bit_cast(short, __float2bfloat16(f));   // HW RNE cvt
}
__device__ __forceinline__ float bf2f(short s) {
  return __bfloat162float(__builtin_bit_cast(__hip_bfloat16, s));
}

// ---------------- weight prep (LDS-tiled, coalesced both sides) ----------------
// Q-projection weights pre-scaled by 1/sqrt(dh)=0.125 (exact in bf16).
__global__ __launch_bounds__(256) void pack_qkv_kernel(
    const float* __restrict__ WQ, const float* __restrict__ WK,
    const float* __restrict__ WV, short* __restrict__ out) {
  __shared__ short Ls[64][66];
  const int tid = threadIdx.x;
  const int l = tid & 63, q4 = tid >> 6;
  const int hh = blockIdx.y & 15, proj = blockIdx.y >> 4;
  const float* W = (proj == 0) ? WQ : ((proj == 1) ? WK : WV);
  const float scl = (proj == 0) ? 0.125f : 1.f;
  const int d0 = blockIdx.x * 64;
#pragma unroll
  for (int rep = 0; rep < 16; ++rep) {
    int dd = q4 * 16 + rep;
    Ls[dd][l] = f2bf(W[(size_t)hh * 65536 + (size_t)(d0 + dd) * 64 + l] * scl);
  }
  __syncthreads();
#pragma unroll
  for (int rep = 0; rep < 16; ++rep) {
    int ee = q4 * 16 + rep;
    out[(size_t)(proj * 1024 + hh * 64 + ee) * 1024 + d0 + l] = Ls[l][ee];
  }
}

__global__ __launch_bounds__(256) void transpose_bf16_kernel(
    const float* __restrict__ in, short* __restrict__ out, int R, int C) {
  __shared__ short Ls[64][66];
  const int tid = threadIdx.x;
  const int l = tid & 63, q4 = tid >> 6;
  const int c0 = blockIdx.x * 64, r0 = blockIdx.y * 64;
#pragma unroll
  for (int rep = 0; rep < 16; ++rep) {
    int rr = q4 * 16 + rep;
    Ls[rr][l] = f2bf(in[(size_t)(r0 + rr) * C + c0 + l]);
  }
  __syncthreads();
#pragma unroll
  for (int rep = 0; rep < 16; ++rep) {
    int cc = q4 * 16 + rep;
    out[(size_t)(c0 + cc) * R + r0 + l] = Ls[l][cc];
  }
}

// ---------------- RMSNorm (fp32 in -> bf16 out) ----------------
__global__ __launch_bounds__(256) void rmsnorm_kernel(
    const float* __restrict__ x, const float* __restrict__ g,
    short* __restrict__ out, int D) {
  const int row = blockIdx.x;
  const int tid = threadIdx.x;
  const float4 xv = *(const float4*)&x[(size_t)row * D + tid * 4];
  float ss = xv.x * xv.x + xv.y * xv.y + xv.z * xv.z + xv.w * xv.w;
#pragma unroll
  for (int off = 32; off; off >>= 1) ss += __shfl_xor(ss, off);
  __shared__ float red[4];
  if ((tid & 63) == 0) red[tid >> 6] = ss;
  __syncthreads();
  float tot = red[0] + red[1] + red[2] + red[3];
  float scale = rsqrtf(tot / (float)D + 1e-6f);
  const float4 gv = *(const float4*)&g[tid * 4];
  s16x4 o;
  o[0] = f2bf(xv.x * scale * gv.x);
  o[1] = f2bf(xv.y * scale * gv.y);
  o[2] = f2bf(xv.z * scale * gv.z);
  o[3] = f2bf(xv.w * scale * gv.w);
  *(s16x4*)&out[(size_t)row * D + tid * 4] = o;
}

// ---------------- 128x128 GEMM (m97 structure): C = A[M,K] x BT[N,K]^T ----------------
template <int EPI>
__global__ __launch_bounds__(256) void gemm_bt_kernel(
    const short* __restrict__ A, const short* __restrict__ BT,
    int M, int N, int K,
    short* __restrict__ outB, float* __restrict__ outF,
    const float* __restrict__ bias, const float* __restrict__ addend) {
  __shared__ short As[128 * 32];
  __shared__ short Bs[128 * 32];
  const int tid = threadIdx.x;
  const int lane = tid & 63;
  const int wid = tid >> 6;
  const int lrow = lane & 15;
  const int kk = lane >> 4;
  const int row0 = blockIdx.y * 128;
  const int col0 = blockIdx.x * 128;
  const int wm = wid >> 1, wn = wid & 1;

  f32x4 acc[4][4] = {};

  for (int k0 = 0; k0 < K; k0 += 32) {
    __syncthreads();
#pragma unroll
    for (int it = 0; it < 2; ++it) {
      int c = it * 256 + tid;
      int r = c >> 2, c8 = (c & 3) * 8;
      const short* ga = A + (size_t)(row0 + r) * K + k0 + c8;
      const short* gb = BT + (size_t)(col0 + r) * K + k0 + c8;
      short* la = &As[(size_t)(it * 256 + wid * 64) * 8];
      short* lb = &Bs[(size_t)(it * 256 + wid * 64) * 8];
      __builtin_amdgcn_global_load_lds(GLOBAL_AS(ga), LDS_AS(la), 16, 0, 0);
      __builtin_amdgcn_global_load_lds(GLOBAL_AS(gb), LDS_AS(lb), 16, 0, 0);
    }
    __syncthreads();

    bf16x8 a[4], b[4];
#pragma unroll
    for (int i = 0; i < 4; ++i)
      a[i] = *(const bf16x8*)&As[(wm * 64 + i * 16 + lrow) * 32 + kk * 8];
#pragma unroll
    for (int i = 0; i < 4; ++i)
      b[i] = *(const bf16x8*)&Bs[(wn * 64 + i * 16 + lrow) * 32 + kk * 8];
#pragma unroll
    for (int i = 0; i < 4; ++i)
#pragma unroll
      for (int j = 0; j < 4; ++j)
        acc[i][j] = __builtin_amdgcn_mfma_f32_16x16x32_bf16(a[i], b[j], acc[i][j], 0, 0, 0);
  }

#pragma unroll
  for (int i = 0; i < 4; ++i) {
    int row = row0 + wm * 64 + i * 16 + kk * 4;
#pragma unroll
    for (int j = 0; j < 4; ++j) {
      int col = col0 + wn * 64 + j * 16 + lrow;
#pragma unroll
      for (int r = 0; r < 4; ++r) {
        float v = acc[i][j][r];
        size_t o = (size_t)(row + r) * N + col;
        if (EPI == 0) {
          outB[o] = f2bf(v);
        } else if (EPI == 1) {
          outF[o] = v + addend[o];
        } else if (EPI == 2) {
          v += bias[col];
          outB[o] = f2bf(v > 0.f ? v : 0.f);
        } else {
          outF[o] = v + bias[col] + addend[o];
        }
      }
    }
  }
}

// ---------------- 256x256 8-phase GEMM (T2+T3+T4+T5), bf16 out ----------------
#define READ_A(buf, mh)                                                      \
  _Pragma("unroll") for (int m4 = 0; m4 < 4; ++m4) {                         \
    int row_ = wm * 128 + ((mh)*4 + m4) * 16 + lrow;                         \
    _Pragma("unroll") for (int k_ = 0; k_ < 2; ++k_) {                       \
      int sl_ = (k_ * 4 + kk) ^ (row_ & 7);                                  \
      aA[m4][k_] = *(const bf16x8*)&lds[buf][0][row_ * 64 + sl_ * 8];        \
    }                                                                        \
  }
#define READ_B2(buf, pr)                                                     \
  _Pragma("unroll") for (int nn = 0; nn < 2; ++nn) {                         \
    int n_ = (pr)*2 + nn;                                                    \
    int row_ = wn * 64 + n_ * 16 + lrow;                                     \
    _Pragma("unroll") for (int k_ = 0; k_ < 2; ++k_) {                       \
      int sl_ = (k_ * 4 + kk) ^ (row_ & 7);                                  \
      bB[n_][k_] = *(const bf16x8*)&lds[buf][1][row_ * 64 + sl_ * 8];        \
    }                                                                        \
  }
#define MFMA16(mh, nh)                                                       \
  _Pragma("unroll") for (int m4 = 0; m4 < 4; ++m4)                           \
  _Pragma("unroll") for (int n2 = 0; n2 < 2; ++n2)                           \
  _Pragma("unroll") for (int k_ = 0; k_ < 2; ++k_)                           \
    acc[(mh)*4 + m4][(nh)*2 + n2] = __builtin_amdgcn_mfma_f32_16x16x32_bf16( \
        aA[m4][k_], bB[(nh)*2 + n2][k_], acc[(mh)*4 + m4][(nh)*2 + n2], 0, 0, 0);
#define STAGE_HALF(buf, mat, half, kt)                                       \
  {                                                                          \
    const short* g_ = ((mat) ? Bb : Ab) + (size_t)((half)*128) * K + (kt)*64;\
    short* l_ = &lds[buf][mat][(half)*8192];                                 \
    _Pragma("unroll") for (int it_ = 0; it_ < 2; ++it_) {                    \
      int ci_ = it_ * 512 + tid;                                             \
      int r_ = ci_ >> 3, sl_ = (ci_ & 7) ^ (r_ & 7);                         \
      __builtin_amdgcn_global_load_lds(GLOBAL_AS(g_ + (size_t)r_ * K + sl_ * 8), \
                                       LDS_AS(l_ + ci_ * 8), 16, 0, 0);      \
    }                                                                        \
  }
#define PH_SYNC1()                                                           \
  __builtin_amdgcn_s_barrier();                                              \
  asm volatile("s_waitcnt lgkmcnt(0)" ::: "memory");                         \
  __builtin_amdgcn_sched_barrier(0);                                         \
  __builtin_amdgcn_s_setprio(1)
#define PH_SYNC2()                                                           \
  __builtin_amdgcn_s_setprio(0);                                             \
  __builtin_amdgcn_s_barrier()
#define PH_SYNC2_VM(n)                                                       \
  __builtin_amdgcn_s_setprio(0);                                             \
  asm volatile("s_waitcnt vmcnt(" #n ")" ::: "memory");                      \
  __builtin_amdgcn_s_barrier()

template <int EPI>
__global__ __launch_bounds__(512, 2) void gemm256_kernel(
    const short* __restrict__ A, const short* __restrict__ BT,
    int N, int K, int kslice, size_t pstride,
    short* __restrict__ outB, const float* __restrict__ bias) {
  __shared__ short lds[2][2][16384];   // [buf][A/B][256 rows x 64 k], 128 KiB
  const int tid = threadIdx.x;
  const int lane = tid & 63, wid = tid >> 6;
  const int lrow = lane & 15, kk = lane >> 4;
  const int wm = wid >> 2, wn = wid & 3;
  const int row0 = blockIdx.y * 256, col0 = blockIdx.x * 256;
  const int kbase = blockIdx.z * kslice;
  const int NT = kslice >> 6;

  const short* Ab = A + (size_t)row0 * K + kbase;
  const short* Bb = BT + (size_t)col0 * K + kbase;

  f32x4 acc[8][4] = {};
  bf16x8 aA[4][2], bB[4][2];

  STAGE_HALF(0, 1, 0, 0); STAGE_HALF(0, 0, 0, 0);
  STAGE_HALF(0, 1, 1, 0); STAGE_HALF(0, 0, 1, 0);
  STAGE_HALF(1, 1, 0, 1); STAGE_HALF(1, 0, 0, 1); STAGE_HALF(1, 0, 1, 1);
  asm volatile("s_waitcnt vmcnt(6)" ::: "memory");
  __builtin_amdgcn_s_barrier();

  const int iters = NT >> 1;
  for (int i = 0; i < iters; ++i) {
    const int t1 = 2 * i + 1;
    int kt2 = 2 * i + 2; if (kt2 >= NT) kt2 -= NT;
    int kt3 = 2 * i + 3; if (kt3 >= NT) kt3 -= NT;
    READ_A(0, 0); READ_B2(0, 0); STAGE_HALF(1, 1, 1, t1);
    PH_SYNC1(); MFMA16(0, 0); PH_SYNC2();
    READ_B2(0, 1);
    PH_SYNC1(); MFMA16(0, 1); PH_SYNC2();
    READ_A(0, 1); STAGE_HALF(0, 1, 0, kt2);
    PH_SYNC1(); MFMA16(1, 0); PH_SYNC2();
    STAGE_HALF(0, 0, 0, kt2);
    PH_SYNC1(); MFMA16(1, 1); PH_SYNC2_VM(4);
    READ_A(1, 0); READ_B2(1, 0); STAGE_HALF(0, 1, 1, kt2);
    PH_SYNC1(); MFMA16(0, 0); PH_SYNC2();
    READ_B2(1, 1); STAGE_HALF(0, 0, 1, kt2);
    PH_SYNC1(); MFMA16(0, 1); PH_SYNC2();
    READ_A(1, 1); STAGE_HALF(1, 1, 0, kt3);
    PH_SYNC1(); MFMA16(1, 0); PH_SYNC2();
    STAGE_HALF(1, 0, 0, kt3); STAGE_HALF(1, 0, 1, kt3);
    PH_SYNC1(); MFMA16(1, 1); PH_SYNC2_VM(6);
  }

  short* ob = outB + (size_t)blockIdx.z * pstride;
#pragma unroll
  for (int m = 0; m < 8; ++m) {
    int row = row0 + wm * 128 + m * 16 + kk * 4;
#pragma unroll
    for (int n = 0; n < 4; ++n) {
      int col = col0 + wn * 64 + n * 16 + lrow;
#pragma unroll
      for (int r = 0; r < 4; ++r) {
        float v = acc[m][n][r];
        size_t o = (size_t)(row + r) * N + col;
        if (EPI == 0) {
          ob[o] = f2bf(v);
        } else {
          v += bias[col];
          ob[o] = f2bf(v > 0.f ? v : 0.f);
        }
      }
    }
  }
}

// out[i] = sum_{s<4} part[s][i] + bias[i % 1024] + addend[i]   (W2 split-K reduce)
__global__ __launch_bounds__(256) void reduce4_kernel(
    const short* __restrict__ part, const float* __restrict__ bias,
    const float* __restrict__ addend, float* __restrict__ out) {
  const size_t MN = (size_t)4096 * 1024;
  size_t i8 = ((size_t)blockIdx.x * 256 + threadIdx.x) * 8;
  bf16x8 p0 = *(const bf16x8*)&part[i8];
  bf16x8 p1 = *(const bf16x8*)&part[MN + i8];
  bf16x8 p2 = *(const bf16x8*)&part[2 * MN + i8];
  bf16x8 p3 = *(const bf16x8*)&part[3 * MN + i8];
  int col = (int)(i8 & 1023);
#pragma unroll
  for (int j = 0; j < 8; ++j) {
    float v = (bf2f(p0[j]) + bf2f(p1[j])) + (bf2f(p2[j]) + bf2f(p3[j]));
    out[i8 + j] = v + bias[col + j] + addend[i8 + j];
  }
}

// out[i] = bf16(part[0][i] + part[1][i])   (QK split-K2 reduce, bf16 out)
__global__ __launch_bounds__(256) void reduce2_bf16_kernel(
    const short* __restrict__ part, short* __restrict__ out, size_t MN) {
  size_t i8 = ((size_t)blockIdx.x * 256 + threadIdx.x) * 8;
  bf16x8 p0 = *(const bf16x8*)&part[i8];
  bf16x8 p1 = *(const bf16x8*)&part[MN + i8];
  bf16x8 o;
#pragma unroll
  for (int j = 0; j < 8; ++j) o[j] = f2bf(bf2f(p0[j]) + bf2f(p1[j]));
  *(bf16x8*)&out[i8] = o;
}

// ---------------- flash attention v7 (causal, no-max softmax, KVBLK=128, balanced) ----------------
// Per-CU load balance: with 512 blocks on 256 CUs, block bid co-resides with
// bid+256. Map bid<256 -> qtile 31-(bid>>4), bid>=256 -> qtile (bid-256)>>4:
// each CU's pair sums to exactly 33 rounds (was 18..48 -> max-bound).
__global__ __launch_bounds__(256) void attn_kernel(
    const short* __restrict__ QK, const short* __restrict__ VT,
    short* __restrict__ O) {
  const int S = 4096;
  __shared__ short Ks[2][128 * 64];
  __shared__ short Vs[2][64 * 128];
  __shared__ short Ps[4][32 * 64];

  const int tid = threadIdx.x;
  const int lane = tid & 63;
  const int w = tid >> 6;
  const int lrow = lane & 15;
  const int kk = lane >> 4;
  const int bid = blockIdx.x;
  const int h = bid & 15;
  const int idx = (bid >> 4) & 15;
  const int qtile = (bid >> 8) ? idx : 31 - idx;  // pair q with 31-q per CU
  const int q0 = qtile * 128;
  const int qw = q0 + w * 32;
  const int nt = qtile + 1;                       // 128-key rounds

  auto stage = [&](int buf, int t) {
    const int kv0 = t * 128;
#pragma unroll
    for (int it = 0; it < 4; ++it) {
      int ci = it * 256 + tid;                    // 16B chunks, 1024 per matrix
      int krow = ci >> 3;                         // 128 K rows x 8 slots
      int ksl = (ci & 7) ^ (krow & 7);
      int vrow = ci >> 4;                         // 64 V rows x 16 slots
      int vsl = (ci & 15) ^ (vrow & 15);
      const short* gk = QK + (size_t)(kv0 + krow) * 2048 + 1024 + h * 64 + ksl * 8;
      const short* gv = VT + (size_t)(h * 64 + vrow) * S + kv0 + vsl * 8;
      __builtin_amdgcn_global_load_lds(GLOBAL_AS(gk),
                                       LDS_AS(&Ks[buf][(it * 256 + w * 64) * 8]), 16, 0, 0);
      __builtin_amdgcn_global_load_lds(GLOBAL_AS(gv),
                                       LDS_AS(&Vs[buf][(it * 256 + w * 64) * 8]), 16, 0, 0);
    }
  };

  bf16x8 qf[2][2];
#pragma unroll
  for (int i = 0; i < 2; ++i)
#pragma unroll
    for (int half = 0; half < 2; ++half)
      qf[i][half] = *(const bf16x8*)&QK[(size_t)(qw + i * 16 + lrow) * 2048 +
                                        h * 64 + half * 32 + kk * 8];

  float rs_acc[2][4] = {};
  f32x4 o_acc[2][4] = {};

  stage(0, 0);
  __syncthreads();
  int cur = 0;

  for (int t = 0; t < nt; ++t) {
    if (t + 1 < nt) stage(cur ^ 1, t + 1);        // prefetch next 128-key tile

#pragma unroll
    for (int h2 = 0; h2 < 2; ++h2) {
      const int kvc = t * 128 + h2 * 64;
      if (kvc > qw + 31) continue;                // chunk fully masked for wave

      // ---- QK^T over this 64-key chunk ----
      bf16x8 kf[4][2];
#pragma unroll
      for (int c = 0; c < 4; ++c)
#pragma unroll
        for (int half = 0; half < 2; ++half) {
          int krow = h2 * 64 + c * 16 + lrow;
          kf[c][half] = *(const bf16x8*)&Ks[cur][krow * 64 + (((half * 4 + kk) ^ (lrow & 7)) * 8)];
        }
      f32x4 sc[2][4];
      __builtin_amdgcn_s_setprio(1);
#pragma unroll
      for (int i = 0; i < 2; ++i)
#pragma unroll
        for (int c = 0; c < 4; ++c) {
          f32x4 z = {};
          z = __builtin_amdgcn_mfma_f32_16x16x32_bf16(qf[i][0], kf[c][0], z, 0, 0, 0);
          z = __builtin_amdgcn_mfma_f32_16x16x32_bf16(qf[i][1], kf[c][1], z, 0, 0, 0);
          sc[i][c] = z;
        }
      __builtin_amdgcn_s_setprio(0);

      // ---- softmax numerator (scores pre-scaled via WQ) ----
      if (kvc + 63 <= qw) {
#pragma unroll
        for (int i = 0; i < 2; ++i)
#pragma unroll
          for (int r = 0; r < 4; ++r) {
            const int qrow = i * 16 + kk * 4 + r;
            float ps[4];
#pragma unroll
            for (int c = 0; c < 4; ++c) {
              float p = __expf(sc[i][c][r]);
              ps[c] = p;
              int col = c * 16 + lrow;
              Ps[w][qrow * 64 + (((col >> 3) ^ (qrow & 7)) * 8) + (col & 7)] = f2bf(p);
            }
            rs_acc[i][r] += (ps[0] + ps[1]) + (ps[2] + ps[3]);
          }
      } else {
#pragma unroll
        for (int i = 0; i < 2; ++i)
#pragma unroll
          for (int r = 0; r < 4; ++r) {
            const int qrow = i * 16 + kk * 4 + r;
            const int q = qw + qrow;
            float ps[4];
#pragma unroll
            for (int c = 0; c < 4; ++c) {
              float p = __expf(sc[i][c][r]);
              if (kvc + c * 16 + lrow > q) p = 0.f;
              ps[c] = p;
              int col = c * 16 + lrow;
              Ps[w][qrow * 64 + (((col >> 3) ^ (qrow & 7)) * 8) + (col & 7)] = f2bf(p);
            }
            rs_acc[i][r] += (ps[0] + ps[1]) + (ps[2] + ps[3]);
          }
      }

      // ---- PV over this chunk ----
#pragma unroll
      for (int ks = 0; ks < 2; ++ks) {
        bf16x8 pf2[2], vf[4];
#pragma unroll
        for (int i = 0; i < 2; ++i) {
          int qrow = i * 16 + lrow;
          pf2[i] = *(const bf16x8*)&Ps[w][qrow * 64 + (((ks * 4 + kk) ^ (qrow & 7)) * 8)];
        }
#pragma unroll
        for (int g = 0; g < 4; ++g) {
          int erow = g * 16 + lrow;
          vf[g] = *(const bf16x8*)&Vs[cur][erow * 128 + (((h2 * 8 + ks * 4 + kk) ^ (lrow & 15)) * 8)];
        }
        __builtin_amdgcn_s_setprio(1);
#pragma unroll
        for (int i = 0; i < 2; ++i)
#pragma unroll
          for (int g = 0; g < 4; ++g)
            o_acc[i][g] = __builtin_amdgcn_mfma_f32_16x16x32_bf16(pf2[i], vf[g], o_acc[i][g], 0, 0, 0);
        __builtin_amdgcn_s_setprio(0);
      }
    }

    __syncthreads();                              // drain prefetch + swap
    cur ^= 1;
  }

  float inv[2][4];
#pragma unroll
  for (int i = 0; i < 2; ++i)
#pragma unroll
    for (int r = 0; r < 4; ++r) {
      float l = rs_acc[i][r];
      l += __shfl_xor(l, 1);
      l += __shfl_xor(l, 2);
      l += __shfl_xor(l, 4);
      l += __shfl_xor(l, 8);
      inv[i][r] = 1.f / l;
    }
#pragma unroll
  for (int i = 0; i < 2; ++i)
#pragma unroll
    for (int g = 0; g < 4; ++g)
#pragma unroll
      for (int r = 0; r < 4; ++r) {
        int s_idx = qw + i * 16 + kk * 4 + r;
        O[(size_t)s_idx * 1024 + h * 64 + g * 16 + lrow] =
            f2bf(o_acc[i][g][r] * inv[i][r]);
      }
}

// ---------------- launch ----------------
extern "C" void kernel_launch(void* const* d_in, const int* in_sizes, int n_in,
                              void* d_out, int out_size, void* d_ws, size_t ws_size,
                              hipStream_t stream) {
  const float* x  = (const float*)d_in[0];
  const float* g1 = (const float*)d_in[2];
  const float* WQ = (const float*)d_in[3];
  const float* WK = (const float*)d_in[4];
  const float* WV = (const float*)d_in[5];
  const float* WO = (const float*)d_in[6];
  const float* g2 = (const float*)d_in[7];
  const float* W1 = (const float*)d_in[8];
  const float* B1 = (const float*)d_in[9];
  const float* W2 = (const float*)d_in[10];
  const float* B2 = (const float*)d_in[11];
  float* out = (float*)d_out;

  const int S = 4096, D = 1024, H = 16;

  char* ws = (char*)d_ws;
  size_t off = 0;
  auto alloc = [&](size_t bytes) -> void* {
    void* p = ws + off;
    off += (bytes + 255) & ~(size_t)255;
    return p;
  };
  short* h1     = (short*)alloc((size_t)S * D * 2);
  short* wqkv_t = (short*)alloc((size_t)3072 * 1024 * 2);
  short* qk     = (short*)alloc((size_t)S * 2048 * 2);
  short* vt     = (short*)alloc((size_t)1024 * S * 2);
  short* attn_o = (short*)alloc((size_t)S * D * 2);
  short* wo_t   = (short*)alloc((size_t)1024 * 1024 * 2);
  float* x2     = (float*)alloc((size_t)S * D * 4);
  short* h2     = (short*)alloc((size_t)S * D * 2);
  short* w1_t   = (short*)alloc((size_t)4096 * 1024 * 2);
  short* m1     = (short*)alloc((size_t)S * 4096 * 2);
  short* w2_t   = (short*)alloc((size_t)1024 * 4096 * 2);
  short* partW2 = qk;   // W2 split-K partials alias qk+vt+attn_o (dead by then)
  short* partQK = m1;   // QK split-K2 partials alias m1 (2 x 4096x2048 bf16 = m1 size; m1 dead until W1)

  // weight prep
  pack_qkv_kernel<<<dim3(D / 64, 48), 256, 0, stream>>>(WQ, WK, WV, wqkv_t);
  transpose_bf16_kernel<<<dim3(1024 / 64, 1024 / 64), 256, 0, stream>>>(WO, wo_t, 1024, 1024);
  transpose_bf16_kernel<<<dim3(4096 / 64, 1024 / 64), 256, 0, stream>>>(W1, w1_t, 1024, 4096);
  transpose_bf16_kernel<<<dim3(1024 / 64, 4096 / 64), 256, 0, stream>>>(W2, w2_t, 4096, 1024);

  // attention sub-block
  rmsnorm_kernel<<<S, 256, 0, stream>>>(x, g1, h1, D);
  // QK projection via 256^2 8-phase split-K2 -> bf16 partials in m1, reduce to qk
  gemm256_kernel<0><<<dim3(2048 / 256, S / 256, 2), 512, 0, stream>>>(
      h1, wqkv_t, 2048, 1024, 512, (size_t)S * 2048, partQK, nullptr);
  reduce2_bf16_kernel<<<(S * 2048 / 8) / 256, 256, 0, stream>>>(
      partQK, qk, (size_t)S * 2048);
  gemm_bt_kernel<0><<<dim3(S / 128, 1024 / 128), 256, 0, stream>>>(
      wqkv_t + (size_t)2048 * 1024, h1, 1024, S, 1024, vt, nullptr, nullptr, nullptr);
  attn_kernel<<<dim3(512), 256, 0, stream>>>(qk, vt, attn_o);
  gemm_bt_kernel<1><<<dim3(1024 / 128, S / 128), 256, 0, stream>>>(
      attn_o, wo_t, S, 1024, 1024, nullptr, x2, nullptr, x);

  // MLP sub-block
  rmsnorm_kernel<<<S, 256, 0, stream>>>(x2, g2, h2, D);
  gemm256_kernel<2><<<dim3(4096 / 256, 4096 / 256, 1), 512, 0, stream>>>(
      h2, w1_t, 4096, 1024, 1024, 0, m1, B1);
  gemm256_kernel<0><<<dim3(1024 / 256, 4096 / 256, 4), 512, 0, stream>>>(
      m1, w2_t, 1024, 4096, 1024, (size_t)4096 * 1024, partW2, nullptr);
  reduce4_kernel<<<2048, 256, 0, stream>>>(partW2, B2, x2, out);
}

// Round 9
// 276.830 us; speedup vs baseline: 1.0221x; 1.0221x over previous
//
#include <hip/hip_runtime.h>
#include <hip/hip_bf16.h>

typedef __attribute__((ext_vector_type(8))) short bf16x8;
typedef __attribute__((ext_vector_type(4))) float f32x4;
typedef __attribute__((ext_vector_type(4))) short s16x4;

#define GLOBAL_AS(p) ((const __attribute__((address_space(1))) void*)(p))
#define LDS_AS(p)    ((__attribute__((address_space(3))) void*)(p))

__device__ __forceinline__ short f2bf(float f) {
  return __builtin_bit_cast(short, __float2bfloat16(f));   // HW RNE cvt
}
__device__ __forceinline__ float bf2f(short s) {
  return __bfloat162float(__builtin_bit_cast(__hip_bfloat16, s));
}

// ---------------- weight prep (LDS-tiled, coalesced both sides) ----------------
// Q-projection weights pre-scaled by 1/sqrt(dh)=0.125 (exact in bf16).
__global__ __launch_bounds__(256) void pack_qkv_kernel(
    const float* __restrict__ WQ, const float* __restrict__ WK,
    const float* __restrict__ WV, short* __restrict__ out) {
  __shared__ short Ls[64][66];
  const int tid = threadIdx.x;
  const int l = tid & 63, q4 = tid >> 6;
  const int hh = blockIdx.y & 15, proj = blockIdx.y >> 4;
  const float* W = (proj == 0) ? WQ : ((proj == 1) ? WK : WV);
  const float scl = (proj == 0) ? 0.125f : 1.f;
  const int d0 = blockIdx.x * 64;
#pragma unroll
  for (int rep = 0; rep < 16; ++rep) {
    int dd = q4 * 16 + rep;
    Ls[dd][l] = f2bf(W[(size_t)hh * 65536 + (size_t)(d0 + dd) * 64 + l] * scl);
  }
  __syncthreads();
#pragma unroll
  for (int rep = 0; rep < 16; ++rep) {
    int ee = q4 * 16 + rep;
    out[(size_t)(proj * 1024 + hh * 64 + ee) * 1024 + d0 + l] = Ls[l][ee];
  }
}

__global__ __launch_bounds__(256) void transpose_bf16_kernel(
    const float* __restrict__ in, short* __restrict__ out, int R, int C) {
  __shared__ short Ls[64][66];
  const int tid = threadIdx.x;
  const int l = tid & 63, q4 = tid >> 6;
  const int c0 = blockIdx.x * 64, r0 = blockIdx.y * 64;
#pragma unroll
  for (int rep = 0; rep < 16; ++rep) {
    int rr = q4 * 16 + rep;
    Ls[rr][l] = f2bf(in[(size_t)(r0 + rr) * C + c0 + l]);
  }
  __syncthreads();
#pragma unroll
  for (int rep = 0; rep < 16; ++rep) {
    int cc = q4 * 16 + rep;
    out[(size_t)(c0 + cc) * R + r0 + l] = Ls[l][cc];
  }
}

// ---------------- RMSNorm (fp32 in -> bf16 out) ----------------
__global__ __launch_bounds__(256) void rmsnorm_kernel(
    const float* __restrict__ x, const float* __restrict__ g,
    short* __restrict__ out, int D) {
  const int row = blockIdx.x;
  const int tid = threadIdx.x;
  const float4 xv = *(const float4*)&x[(size_t)row * D + tid * 4];
  float ss = xv.x * xv.x + xv.y * xv.y + xv.z * xv.z + xv.w * xv.w;
#pragma unroll
  for (int off = 32; off; off >>= 1) ss += __shfl_xor(ss, off);
  __shared__ float red[4];
  if ((tid & 63) == 0) red[tid >> 6] = ss;
  __syncthreads();
  float tot = red[0] + red[1] + red[2] + red[3];
  float scale = rsqrtf(tot / (float)D + 1e-6f);
  const float4 gv = *(const float4*)&g[tid * 4];
  s16x4 o;
  o[0] = f2bf(xv.x * scale * gv.x);
  o[1] = f2bf(xv.y * scale * gv.y);
  o[2] = f2bf(xv.z * scale * gv.z);
  o[3] = f2bf(xv.w * scale * gv.w);
  *(s16x4*)&out[(size_t)row * D + tid * 4] = o;
}

// ---------------- 128x128 GEMM (m97 structure): C = A[M,K] x BT[N,K]^T ----------------
template <int EPI>
__global__ __launch_bounds__(256) void gemm_bt_kernel(
    const short* __restrict__ A, const short* __restrict__ BT,
    int M, int N, int K,
    short* __restrict__ outB, float* __restrict__ outF,
    const float* __restrict__ bias, const float* __restrict__ addend) {
  __shared__ short As[128 * 32];
  __shared__ short Bs[128 * 32];
  const int tid = threadIdx.x;
  const int lane = tid & 63;
  const int wid = tid >> 6;
  const int lrow = lane & 15;
  const int kk = lane >> 4;
  const int row0 = blockIdx.y * 128;
  const int col0 = blockIdx.x * 128;
  const int wm = wid >> 1, wn = wid & 1;

  f32x4 acc[4][4] = {};

  for (int k0 = 0; k0 < K; k0 += 32) {
    __syncthreads();
#pragma unroll
    for (int it = 0; it < 2; ++it) {
      int c = it * 256 + tid;
      int r = c >> 2, c8 = (c & 3) * 8;
      const short* ga = A + (size_t)(row0 + r) * K + k0 + c8;
      const short* gb = BT + (size_t)(col0 + r) * K + k0 + c8;
      short* la = &As[(size_t)(it * 256 + wid * 64) * 8];
      short* lb = &Bs[(size_t)(it * 256 + wid * 64) * 8];
      __builtin_amdgcn_global_load_lds(GLOBAL_AS(ga), LDS_AS(la), 16, 0, 0);
      __builtin_amdgcn_global_load_lds(GLOBAL_AS(gb), LDS_AS(lb), 16, 0, 0);
    }
    __syncthreads();

    bf16x8 a[4], b[4];
#pragma unroll
    for (int i = 0; i < 4; ++i)
      a[i] = *(const bf16x8*)&As[(wm * 64 + i * 16 + lrow) * 32 + kk * 8];
#pragma unroll
    for (int i = 0; i < 4; ++i)
      b[i] = *(const bf16x8*)&Bs[(wn * 64 + i * 16 + lrow) * 32 + kk * 8];
#pragma unroll
    for (int i = 0; i < 4; ++i)
#pragma unroll
      for (int j = 0; j < 4; ++j)
        acc[i][j] = __builtin_amdgcn_mfma_f32_16x16x32_bf16(a[i], b[j], acc[i][j], 0, 0, 0);
  }

#pragma unroll
  for (int i = 0; i < 4; ++i) {
    int row = row0 + wm * 64 + i * 16 + kk * 4;
#pragma unroll
    for (int j = 0; j < 4; ++j) {
      int col = col0 + wn * 64 + j * 16 + lrow;
#pragma unroll
      for (int r = 0; r < 4; ++r) {
        float v = acc[i][j][r];
        size_t o = (size_t)(row + r) * N + col;
        if (EPI == 0) {
          outB[o] = f2bf(v);
        } else if (EPI == 1) {
          outF[o] = v + addend[o];
        } else if (EPI == 2) {
          v += bias[col];
          outB[o] = f2bf(v > 0.f ? v : 0.f);
        } else {
          outF[o] = v + bias[col] + addend[o];
        }
      }
    }
  }
}

// ---------------- 256x256 8-phase GEMM (T2+T3+T4+T5), bf16 out ----------------
#define READ_A(buf, mh)                                                      \
  _Pragma("unroll") for (int m4 = 0; m4 < 4; ++m4) {                         \
    int row_ = wm * 128 + ((mh)*4 + m4) * 16 + lrow;                         \
    _Pragma("unroll") for (int k_ = 0; k_ < 2; ++k_) {                       \
      int sl_ = (k_ * 4 + kk) ^ (row_ & 7);                                  \
      aA[m4][k_] = *(const bf16x8*)&lds[buf][0][row_ * 64 + sl_ * 8];        \
    }                                                                        \
  }
#define READ_B2(buf, pr)                                                     \
  _Pragma("unroll") for (int nn = 0; nn < 2; ++nn) {                         \
    int n_ = (pr)*2 + nn;                                                    \
    int row_ = wn * 64 + n_ * 16 + lrow;                                     \
    _Pragma("unroll") for (int k_ = 0; k_ < 2; ++k_) {                       \
      int sl_ = (k_ * 4 + kk) ^ (row_ & 7);                                  \
      bB[n_][k_] = *(const bf16x8*)&lds[buf][1][row_ * 64 + sl_ * 8];        \
    }                                                                        \
  }
#define MFMA16(mh, nh)                                                       \
  _Pragma("unroll") for (int m4 = 0; m4 < 4; ++m4)                           \
  _Pragma("unroll") for (int n2 = 0; n2 < 2; ++n2)                           \
  _Pragma("unroll") for (int k_ = 0; k_ < 2; ++k_)                           \
    acc[(mh)*4 + m4][(nh)*2 + n2] = __builtin_amdgcn_mfma_f32_16x16x32_bf16( \
        aA[m4][k_], bB[(nh)*2 + n2][k_], acc[(mh)*4 + m4][(nh)*2 + n2], 0, 0, 0);
#define STAGE_HALF(buf, mat, half, kt)                                       \
  {                                                                          \
    const short* g_ = ((mat) ? Bb : Ab) + (size_t)((half)*128) * K + (kt)*64;\
    short* l_ = &lds[buf][mat][(half)*8192];                                 \
    _Pragma("unroll") for (int it_ = 0; it_ < 2; ++it_) {                    \
      int ci_ = it_ * 512 + tid;                                             \
      int r_ = ci_ >> 3, sl_ = (ci_ & 7) ^ (r_ & 7);                         \
      __builtin_amdgcn_global_load_lds(GLOBAL_AS(g_ + (size_t)r_ * K + sl_ * 8), \
                                       LDS_AS(l_ + ci_ * 8), 16, 0, 0);      \
    }                                                                        \
  }
#define PH_SYNC1()                                                           \
  __builtin_amdgcn_s_barrier();                                              \
  asm volatile("s_waitcnt lgkmcnt(0)" ::: "memory");                         \
  __builtin_amdgcn_sched_barrier(0);                                         \
  __builtin_amdgcn_s_setprio(1)
#define PH_SYNC2()                                                           \
  __builtin_amdgcn_s_setprio(0);                                             \
  __builtin_amdgcn_s_barrier()
#define PH_SYNC2_VM(n)                                                       \
  __builtin_amdgcn_s_setprio(0);                                             \
  asm volatile("s_waitcnt vmcnt(" #n ")" ::: "memory");                      \
  __builtin_amdgcn_s_barrier()

template <int EPI>
__global__ __launch_bounds__(512, 2) void gemm256_kernel(
    const short* __restrict__ A, const short* __restrict__ BT,
    int N, int K, int kslice, size_t pstride,
    short* __restrict__ outB, const float* __restrict__ bias) {
  __shared__ short lds[2][2][16384];   // [buf][A/B][256 rows x 64 k], 128 KiB
  const int tid = threadIdx.x;
  const int lane = tid & 63, wid = tid >> 6;
  const int lrow = lane & 15, kk = lane >> 4;
  const int wm = wid >> 2, wn = wid & 3;
  const int row0 = blockIdx.y * 256, col0 = blockIdx.x * 256;
  const int kbase = blockIdx.z * kslice;
  const int NT = kslice >> 6;

  const short* Ab = A + (size_t)row0 * K + kbase;
  const short* Bb = BT + (size_t)col0 * K + kbase;

  f32x4 acc[8][4] = {};
  bf16x8 aA[4][2], bB[4][2];

  STAGE_HALF(0, 1, 0, 0); STAGE_HALF(0, 0, 0, 0);
  STAGE_HALF(0, 1, 1, 0); STAGE_HALF(0, 0, 1, 0);
  STAGE_HALF(1, 1, 0, 1); STAGE_HALF(1, 0, 0, 1); STAGE_HALF(1, 0, 1, 1);
  asm volatile("s_waitcnt vmcnt(6)" ::: "memory");
  __builtin_amdgcn_s_barrier();

  const int iters = NT >> 1;
  for (int i = 0; i < iters; ++i) {
    const int t1 = 2 * i + 1;
    int kt2 = 2 * i + 2; if (kt2 >= NT) kt2 -= NT;
    int kt3 = 2 * i + 3; if (kt3 >= NT) kt3 -= NT;
    READ_A(0, 0); READ_B2(0, 0); STAGE_HALF(1, 1, 1, t1);
    PH_SYNC1(); MFMA16(0, 0); PH_SYNC2();
    READ_B2(0, 1);
    PH_SYNC1(); MFMA16(0, 1); PH_SYNC2();
    READ_A(0, 1); STAGE_HALF(0, 1, 0, kt2);
    PH_SYNC1(); MFMA16(1, 0); PH_SYNC2();
    STAGE_HALF(0, 0, 0, kt2);
    PH_SYNC1(); MFMA16(1, 1); PH_SYNC2_VM(4);
    READ_A(1, 0); READ_B2(1, 0); STAGE_HALF(0, 1, 1, kt2);
    PH_SYNC1(); MFMA16(0, 0); PH_SYNC2();
    READ_B2(1, 1); STAGE_HALF(0, 0, 1, kt2);
    PH_SYNC1(); MFMA16(0, 1); PH_SYNC2();
    READ_A(1, 1); STAGE_HALF(1, 1, 0, kt3);
    PH_SYNC1(); MFMA16(1, 0); PH_SYNC2();
    STAGE_HALF(1, 0, 0, kt3); STAGE_HALF(1, 0, 1, kt3);
    PH_SYNC1(); MFMA16(1, 1); PH_SYNC2_VM(6);
  }

  short* ob = outB + (size_t)blockIdx.z * pstride;
#pragma unroll
  for (int m = 0; m < 8; ++m) {
    int row = row0 + wm * 128 + m * 16 + kk * 4;
#pragma unroll
    for (int n = 0; n < 4; ++n) {
      int col = col0 + wn * 64 + n * 16 + lrow;
#pragma unroll
      for (int r = 0; r < 4; ++r) {
        float v = acc[m][n][r];
        size_t o = (size_t)(row + r) * N + col;
        if (EPI == 0) {
          ob[o] = f2bf(v);
        } else {
          v += bias[col];
          ob[o] = f2bf(v > 0.f ? v : 0.f);
        }
      }
    }
  }
}

// out[i] = sum_{s<4} part[s][i] + bias[i % 1024] + addend[i]   (W2 split-K reduce)
__global__ __launch_bounds__(256) void reduce4_kernel(
    const short* __restrict__ part, const float* __restrict__ bias,
    const float* __restrict__ addend, float* __restrict__ out) {
  const size_t MN = (size_t)4096 * 1024;
  size_t i8 = ((size_t)blockIdx.x * 256 + threadIdx.x) * 8;
  bf16x8 p0 = *(const bf16x8*)&part[i8];
  bf16x8 p1 = *(const bf16x8*)&part[MN + i8];
  bf16x8 p2 = *(const bf16x8*)&part[2 * MN + i8];
  bf16x8 p3 = *(const bf16x8*)&part[3 * MN + i8];
  int col = (int)(i8 & 1023);
#pragma unroll
  for (int j = 0; j < 8; ++j) {
    float v = (bf2f(p0[j]) + bf2f(p1[j])) + (bf2f(p2[j]) + bf2f(p3[j]));
    out[i8 + j] = v + bias[col + j] + addend[i8 + j];
  }
}

// ---------------- flash attention v8: KV-split (flash-decoding) ----------------
// No-max softmax => partials combine by plain addition: o = sum o_s, l = sum l_s.
// qtiles 16..31 split their KV range in 2 blocks; 0..15 single. 768 blocks,
// max 16 rounds each (halves the serial critical path), longest-first via
// static 48-slot schedule. Blocks write fp32 o-partials + l-partials; a
// combine kernel normalizes. opart aliases m1 (dead until W1), lpart aliases h1.
__device__ const unsigned char QT_SLOT[48] = {
    31, 31, 30, 15, 30, 29, 29, 28, 14, 28, 27, 27, 26, 13, 26, 25,
    25, 24, 12, 24, 23, 23, 22, 11, 22, 21, 21, 20, 10, 20, 19, 19,
    18,  9, 18, 17, 17, 16,  8, 16,  7,  6,  5,  4,  3,  2,  1,  0};
__device__ const unsigned char SP_SLOT[48] = {
    0, 1, 0, 0, 1, 0, 1, 0, 0, 1, 0, 1, 0, 0, 1, 0,
    1, 0, 0, 1, 0, 1, 0, 0, 1, 0, 1, 0, 0, 1, 0, 1,
    0, 0, 1, 0, 1, 0, 0, 1, 0, 0, 0, 0, 0, 0, 0, 0};

__global__ __launch_bounds__(256) void attn_kernel(
    const short* __restrict__ QK, const short* __restrict__ VT,
    float* __restrict__ opart, float* __restrict__ lpart) {
  const int S = 4096;
  __shared__ short Ks[2][128 * 64];
  __shared__ short Vs[2][64 * 128];
  __shared__ short Ps[4][32 * 64];

  const int tid = threadIdx.x;
  const int lane = tid & 63;
  const int w = tid >> 6;
  const int lrow = lane & 15;
  const int kk = lane >> 4;
  const int bid = blockIdx.x;
  const int h = bid & 15;
  const int slot = bid >> 4;
  const int qtile = QT_SLOT[slot];
  const int sp = SP_SLOT[slot];
  const int T = qtile + 1;                    // total 128-key tiles for this qtile
  const bool split = (qtile >= 16);
  const int half = (T + 1) >> 1;
  const int t0 = (split && sp) ? half : 0;
  const int t1 = (split && !sp) ? half : T;
  const int q0 = qtile * 128;
  const int qw = q0 + w * 32;

  auto stage = [&](int buf, int t) {
    const int kv0 = t * 128;
#pragma unroll
    for (int it = 0; it < 4; ++it) {
      int ci = it * 256 + tid;                // 16B chunks, 1024 per matrix
      int krow = ci >> 3;                     // 128 K rows x 8 slots
      int ksl = (ci & 7) ^ (krow & 7);
      int vrow = ci >> 4;                     // 64 V rows x 16 slots
      int vsl = (ci & 15) ^ (vrow & 15);
      const short* gk = QK + (size_t)(kv0 + krow) * 2048 + 1024 + h * 64 + ksl * 8;
      const short* gv = VT + (size_t)(h * 64 + vrow) * S + kv0 + vsl * 8;
      __builtin_amdgcn_global_load_lds(GLOBAL_AS(gk),
                                       LDS_AS(&Ks[buf][(it * 256 + w * 64) * 8]), 16, 0, 0);
      __builtin_amdgcn_global_load_lds(GLOBAL_AS(gv),
                                       LDS_AS(&Vs[buf][(it * 256 + w * 64) * 8]), 16, 0, 0);
    }
  };

  bf16x8 qf[2][2];
#pragma unroll
  for (int i = 0; i < 2; ++i)
#pragma unroll
    for (int half2 = 0; half2 < 2; ++half2)
      qf[i][half2] = *(const bf16x8*)&QK[(size_t)(qw + i * 16 + lrow) * 2048 +
                                         h * 64 + half2 * 32 + kk * 8];

  float rs_acc[2][4] = {};
  f32x4 o_acc[2][4] = {};

  stage(0, t0);
  __syncthreads();
  int cur = 0;

  for (int t = t0; t < t1; ++t) {
    if (t + 1 < t1) stage(cur ^ 1, t + 1);    // prefetch next 128-key tile

#pragma unroll
    for (int h2 = 0; h2 < 2; ++h2) {
      const int kvc = t * 128 + h2 * 64;
      if (kvc > qw + 31) continue;            // chunk fully masked for wave

      // ---- QK^T over this 64-key chunk ----
      bf16x8 kf[4][2];
#pragma unroll
      for (int c = 0; c < 4; ++c)
#pragma unroll
        for (int half2 = 0; half2 < 2; ++half2) {
          int krow = h2 * 64 + c * 16 + lrow;
          kf[c][half2] = *(const bf16x8*)&Ks[cur][krow * 64 + (((half2 * 4 + kk) ^ (lrow & 7)) * 8)];
        }
      f32x4 sc[2][4];
      __builtin_amdgcn_s_setprio(1);
#pragma unroll
      for (int i = 0; i < 2; ++i)
#pragma unroll
        for (int c = 0; c < 4; ++c) {
          f32x4 z = {};
          z = __builtin_amdgcn_mfma_f32_16x16x32_bf16(qf[i][0], kf[c][0], z, 0, 0, 0);
          z = __builtin_amdgcn_mfma_f32_16x16x32_bf16(qf[i][1], kf[c][1], z, 0, 0, 0);
          sc[i][c] = z;
        }
      __builtin_amdgcn_s_setprio(0);

      // ---- softmax numerator (scores pre-scaled via WQ) ----
      if (kvc + 63 <= qw) {
#pragma unroll
        for (int i = 0; i < 2; ++i)
#pragma unroll
          for (int r = 0; r < 4; ++r) {
            const int qrow = i * 16 + kk * 4 + r;
            float ps[4];
#pragma unroll
            for (int c = 0; c < 4; ++c) {
              float p = __expf(sc[i][c][r]);
              ps[c] = p;
              int col = c * 16 + lrow;
              Ps[w][qrow * 64 + (((col >> 3) ^ (qrow & 7)) * 8) + (col & 7)] = f2bf(p);
            }
            rs_acc[i][r] += (ps[0] + ps[1]) + (ps[2] + ps[3]);
          }
      } else {
#pragma unroll
        for (int i = 0; i < 2; ++i)
#pragma unroll
          for (int r = 0; r < 4; ++r) {
            const int qrow = i * 16 + kk * 4 + r;
            const int q = qw + qrow;
            float ps[4];
#pragma unroll
            for (int c = 0; c < 4; ++c) {
              float p = __expf(sc[i][c][r]);
              if (kvc + c * 16 + lrow > q) p = 0.f;
              ps[c] = p;
              int col = c * 16 + lrow;
              Ps[w][qrow * 64 + (((col >> 3) ^ (qrow & 7)) * 8) + (col & 7)] = f2bf(p);
            }
            rs_acc[i][r] += (ps[0] + ps[1]) + (ps[2] + ps[3]);
          }
      }

      // ---- PV over this chunk ----
#pragma unroll
      for (int ks = 0; ks < 2; ++ks) {
        bf16x8 pf2[2], vf[4];
#pragma unroll
        for (int i = 0; i < 2; ++i) {
          int qrow = i * 16 + lrow;
          pf2[i] = *(const bf16x8*)&Ps[w][qrow * 64 + (((ks * 4 + kk) ^ (qrow & 7)) * 8)];
        }
#pragma unroll
        for (int g = 0; g < 4; ++g) {
          int erow = g * 16 + lrow;
          vf[g] = *(const bf16x8*)&Vs[cur][erow * 128 + (((h2 * 8 + ks * 4 + kk) ^ (lrow & 15)) * 8)];
        }
        __builtin_amdgcn_s_setprio(1);
#pragma unroll
        for (int i = 0; i < 2; ++i)
#pragma unroll
          for (int g = 0; g < 4; ++g)
            o_acc[i][g] = __builtin_amdgcn_mfma_f32_16x16x32_bf16(pf2[i], vf[g], o_acc[i][g], 0, 0, 0);
        __builtin_amdgcn_s_setprio(0);
      }
    }

    __syncthreads();                          // drain prefetch + swap
    cur ^= 1;
  }

  // ---- epilogue: write fp32 partials (o unnormalized, l row-sum) ----
  const int pidx = (h * 32 + qtile) * 2 + sp;
  float* op = opart + (size_t)pidx * 8192;    // [128 q][64 d]
  float* lp = lpart + pidx * 128;
#pragma unroll
  for (int i = 0; i < 2; ++i)
#pragma unroll
    for (int r = 0; r < 4; ++r) {
      float l = rs_acc[i][r];
      l += __shfl_xor(l, 1);
      l += __shfl_xor(l, 2);
      l += __shfl_xor(l, 4);
      l += __shfl_xor(l, 8);
      if (lrow == 0) lp[w * 32 + i * 16 + kk * 4 + r] = l;
    }
#pragma unroll
  for (int i = 0; i < 2; ++i)
#pragma unroll
    for (int g = 0; g < 4; ++g)
#pragma unroll
      for (int r = 0; r < 4; ++r)
        op[(w * 32 + i * 16 + kk * 4 + r) * 64 + g * 16 + lrow] = o_acc[i][g][r];
}

// combine: attn_o[srow][col] = bf16( sum_s o_s / sum_s l_s )
__global__ __launch_bounds__(256) void attn_combine_kernel(
    const float* __restrict__ opart, const float* __restrict__ lpart,
    short* __restrict__ O) {
  size_t e8 = ((size_t)blockIdx.x * 256 + threadIdx.x) * 8;   // into [4096][1024]
  const int srow = (int)(e8 >> 10);
  const int col = (int)(e8 & 1023);
  const int h = col >> 6, d = col & 63;
  const int qtile = srow >> 7, qr = srow & 127;
  const int pb = (h * 32 + qtile) * 2;
  const float* o0 = opart + (size_t)pb * 8192 + qr * 64 + d;
  float l = lpart[pb * 128 + qr];
  float4 a0 = *(const float4*)o0;
  float4 a1 = *(const float4*)(o0 + 4);
  if (qtile >= 16) {
    const float* o1 = opart + (size_t)(pb + 1) * 8192 + qr * 64 + d;
    float4 b0 = *(const float4*)o1;
    float4 b1 = *(const float4*)(o1 + 4);
    a0.x += b0.x; a0.y += b0.y; a0.z += b0.z; a0.w += b0.w;
    a1.x += b1.x; a1.y += b1.y; a1.z += b1.z; a1.w += b1.w;
    l += lpart[(pb + 1) * 128 + qr];
  }
  float inv = 1.f / l;
  bf16x8 o;
  o[0] = f2bf(a0.x * inv); o[1] = f2bf(a0.y * inv);
  o[2] = f2bf(a0.z * inv); o[3] = f2bf(a0.w * inv);
  o[4] = f2bf(a1.x * inv); o[5] = f2bf(a1.y * inv);
  o[6] = f2bf(a1.z * inv); o[7] = f2bf(a1.w * inv);
  *(bf16x8*)&O[e8] = o;
}

// ---------------- launch ----------------
extern "C" void kernel_launch(void* const* d_in, const int* in_sizes, int n_in,
                              void* d_out, int out_size, void* d_ws, size_t ws_size,
                              hipStream_t stream) {
  const float* x  = (const float*)d_in[0];
  const float* g1 = (const float*)d_in[2];
  const float* WQ = (const float*)d_in[3];
  const float* WK = (const float*)d_in[4];
  const float* WV = (const float*)d_in[5];
  const float* WO = (const float*)d_in[6];
  const float* g2 = (const float*)d_in[7];
  const float* W1 = (const float*)d_in[8];
  const float* B1 = (const float*)d_in[9];
  const float* W2 = (const float*)d_in[10];
  const float* B2 = (const float*)d_in[11];
  float* out = (float*)d_out;

  const int S = 4096, D = 1024, H = 16;

  char* ws = (char*)d_ws;
  size_t off = 0;
  auto alloc = [&](size_t bytes) -> void* {
    void* p = ws + off;
    off += (bytes + 255) & ~(size_t)255;
    return p;
  };
  short* h1     = (short*)alloc((size_t)S * D * 2);
  short* wqkv_t = (short*)alloc((size_t)3072 * 1024 * 2);
  short* qk     = (short*)alloc((size_t)S * 2048 * 2);
  short* vt     = (short*)alloc((size_t)1024 * S * 2);
  short* attn_o = (short*)alloc((size_t)S * D * 2);
  short* wo_t   = (short*)alloc((size_t)1024 * 1024 * 2);
  float* x2     = (float*)alloc((size_t)S * D * 4);
  short* h2     = (short*)alloc((size_t)S * D * 2);
  short* w1_t   = (short*)alloc((size_t)4096 * 1024 * 2);
  short* m1     = (short*)alloc((size_t)S * 4096 * 2);
  short* w2_t   = (short*)alloc((size_t)1024 * 4096 * 2);
  short* partW2 = qk;          // W2 split-K partials alias qk+vt+attn_o (dead by then)
  float* opart  = (float*)m1;  // attn o-partials: 16*32*2*128*64*4B = 33.55MB = m1 (dead until W1)
  float* lpart  = (float*)h1;  // attn l-partials: 512KB (h1 dead after qk/vt GEMMs)

  // weight prep
  pack_qkv_kernel<<<dim3(D / 64, 48), 256, 0, stream>>>(WQ, WK, WV, wqkv_t);
  transpose_bf16_kernel<<<dim3(1024 / 64, 1024 / 64), 256, 0, stream>>>(WO, wo_t, 1024, 1024);
  transpose_bf16_kernel<<<dim3(4096 / 64, 1024 / 64), 256, 0, stream>>>(W1, w1_t, 1024, 4096);
  transpose_bf16_kernel<<<dim3(1024 / 64, 4096 / 64), 256, 0, stream>>>(W2, w2_t, 4096, 1024);

  // attention sub-block
  rmsnorm_kernel<<<S, 256, 0, stream>>>(x, g1, h1, D);
  gemm_bt_kernel<0><<<dim3(2048 / 128, S / 128), 256, 0, stream>>>(
      h1, wqkv_t, S, 2048, 1024, qk, nullptr, nullptr, nullptr);
  gemm_bt_kernel<0><<<dim3(S / 128, 1024 / 128), 256, 0, stream>>>(
      wqkv_t + (size_t)2048 * 1024, h1, 1024, S, 1024, vt, nullptr, nullptr, nullptr);
  attn_kernel<<<dim3(768), 256, 0, stream>>>(qk, vt, opart, lpart);
  attn_combine_kernel<<<dim3((S * 1024 / 8) / 256), 256, 0, stream>>>(opart, lpart, attn_o);
  gemm_bt_kernel<1><<<dim3(1024 / 128, S / 128), 256, 0, stream>>>(
      attn_o, wo_t, S, 1024, 1024, nullptr, x2, nullptr, x);

  // MLP sub-block
  rmsnorm_kernel<<<S, 256, 0, stream>>>(x2, g2, h2, D);
  gemm256_kernel<2><<<dim3(4096 / 256, 4096 / 256, 1), 512, 0, stream>>>(
      h2, w1_t, 4096, 1024, 1024, 0, m1, B1);
  gemm256_kernel<0><<<dim3(1024 / 256, 4096 / 256, 4), 512, 0, stream>>>(
      m1, w2_t, 1024, 4096, 1024, (size_t)4096 * 1024, partW2, nullptr);
  reduce4_kernel<<<2048, 256, 0, stream>>>(partW2, B2, x2, out);
}

// Round 10
// 266.259 us; speedup vs baseline: 1.0627x; 1.0397x over previous
//
#include <hip/hip_runtime.h>
#include <hip/hip_bf16.h>

typedef __attribute__((ext_vector_type(8))) short bf16x8;
typedef __attribute__((ext_vector_type(4))) float f32x4;
typedef __attribute__((ext_vector_type(4))) short s16x4;

#define GLOBAL_AS(p) ((const __attribute__((address_space(1))) void*)(p))
#define LDS_AS(p)    ((__attribute__((address_space(3))) void*)(p))

__device__ __forceinline__ short f2bf(float f) {
  return __builtin_bit_cast(short, __float2bfloat16(f));   // HW RNE cvt
}
__device__ __forceinline__ float bf2f(short s) {
  return __bfloat162float(__builtin_bit_cast(__hip_bfloat16, s));
}

// ---------------- weight prep (LDS-tiled, coalesced both sides) ----------------
// Q-projection weights pre-scaled by 1/sqrt(dh)=0.125 (exact in bf16).
__global__ __launch_bounds__(256) void pack_qkv_kernel(
    const float* __restrict__ WQ, const float* __restrict__ WK,
    const float* __restrict__ WV, short* __restrict__ out) {
  __shared__ short Ls[64][66];
  const int tid = threadIdx.x;
  const int l = tid & 63, q4 = tid >> 6;
  const int hh = blockIdx.y & 15, proj = blockIdx.y >> 4;
  const float* W = (proj == 0) ? WQ : ((proj == 1) ? WK : WV);
  const float scl = (proj == 0) ? 0.125f : 1.f;
  const int d0 = blockIdx.x * 64;
#pragma unroll
  for (int rep = 0; rep < 16; ++rep) {
    int dd = q4 * 16 + rep;
    Ls[dd][l] = f2bf(W[(size_t)hh * 65536 + (size_t)(d0 + dd) * 64 + l] * scl);
  }
  __syncthreads();
#pragma unroll
  for (int rep = 0; rep < 16; ++rep) {
    int ee = q4 * 16 + rep;
    out[(size_t)(proj * 1024 + hh * 64 + ee) * 1024 + d0 + l] = Ls[l][ee];
  }
}

__global__ __launch_bounds__(256) void transpose_bf16_kernel(
    const float* __restrict__ in, short* __restrict__ out, int R, int C) {
  __shared__ short Ls[64][66];
  const int tid = threadIdx.x;
  const int l = tid & 63, q4 = tid >> 6;
  const int c0 = blockIdx.x * 64, r0 = blockIdx.y * 64;
#pragma unroll
  for (int rep = 0; rep < 16; ++rep) {
    int rr = q4 * 16 + rep;
    Ls[rr][l] = f2bf(in[(size_t)(r0 + rr) * C + c0 + l]);
  }
  __syncthreads();
#pragma unroll
  for (int rep = 0; rep < 16; ++rep) {
    int cc = q4 * 16 + rep;
    out[(size_t)(c0 + cc) * R + r0 + l] = Ls[l][cc];
  }
}

// ---------------- RMSNorm (fp32 in -> bf16 out) ----------------
__global__ __launch_bounds__(256) void rmsnorm_kernel(
    const float* __restrict__ x, const float* __restrict__ g,
    short* __restrict__ out, int D) {
  const int row = blockIdx.x;
  const int tid = threadIdx.x;
  const float4 xv = *(const float4*)&x[(size_t)row * D + tid * 4];
  float ss = xv.x * xv.x + xv.y * xv.y + xv.z * xv.z + xv.w * xv.w;
#pragma unroll
  for (int off = 32; off; off >>= 1) ss += __shfl_xor(ss, off);
  __shared__ float red[4];
  if ((tid & 63) == 0) red[tid >> 6] = ss;
  __syncthreads();
  float tot = red[0] + red[1] + red[2] + red[3];
  float scale = rsqrtf(tot / (float)D + 1e-6f);
  const float4 gv = *(const float4*)&g[tid * 4];
  s16x4 o;
  o[0] = f2bf(xv.x * scale * gv.x);
  o[1] = f2bf(xv.y * scale * gv.y);
  o[2] = f2bf(xv.z * scale * gv.z);
  o[3] = f2bf(xv.w * scale * gv.w);
  *(s16x4*)&out[(size_t)row * D + tid * 4] = o;
}

// ---------------- 128x128 GEMM (m97 structure): C = A[M,K] x BT[N,K]^T ----------------
template <int EPI>
__global__ __launch_bounds__(256) void gemm_bt_kernel(
    const short* __restrict__ A, const short* __restrict__ BT,
    int M, int N, int K,
    short* __restrict__ outB, float* __restrict__ outF,
    const float* __restrict__ bias, const float* __restrict__ addend) {
  __shared__ short As[128 * 32];
  __shared__ short Bs[128 * 32];
  const int tid = threadIdx.x;
  const int lane = tid & 63;
  const int wid = tid >> 6;
  const int lrow = lane & 15;
  const int kk = lane >> 4;
  const int row0 = blockIdx.y * 128;
  const int col0 = blockIdx.x * 128;
  const int wm = wid >> 1, wn = wid & 1;

  f32x4 acc[4][4] = {};

  for (int k0 = 0; k0 < K; k0 += 32) {
    __syncthreads();
#pragma unroll
    for (int it = 0; it < 2; ++it) {
      int c = it * 256 + tid;
      int r = c >> 2, c8 = (c & 3) * 8;
      const short* ga = A + (size_t)(row0 + r) * K + k0 + c8;
      const short* gb = BT + (size_t)(col0 + r) * K + k0 + c8;
      short* la = &As[(size_t)(it * 256 + wid * 64) * 8];
      short* lb = &Bs[(size_t)(it * 256 + wid * 64) * 8];
      __builtin_amdgcn_global_load_lds(GLOBAL_AS(ga), LDS_AS(la), 16, 0, 0);
      __builtin_amdgcn_global_load_lds(GLOBAL_AS(gb), LDS_AS(lb), 16, 0, 0);
    }
    __syncthreads();

    bf16x8 a[4], b[4];
#pragma unroll
    for (int i = 0; i < 4; ++i)
      a[i] = *(const bf16x8*)&As[(wm * 64 + i * 16 + lrow) * 32 + kk * 8];
#pragma unroll
    for (int i = 0; i < 4; ++i)
      b[i] = *(const bf16x8*)&Bs[(wn * 64 + i * 16 + lrow) * 32 + kk * 8];
#pragma unroll
    for (int i = 0; i < 4; ++i)
#pragma unroll
      for (int j = 0; j < 4; ++j)
        acc[i][j] = __builtin_amdgcn_mfma_f32_16x16x32_bf16(a[i], b[j], acc[i][j], 0, 0, 0);
  }

#pragma unroll
  for (int i = 0; i < 4; ++i) {
    int row = row0 + wm * 64 + i * 16 + kk * 4;
#pragma unroll
    for (int j = 0; j < 4; ++j) {
      int col = col0 + wn * 64 + j * 16 + lrow;
#pragma unroll
      for (int r = 0; r < 4; ++r) {
        float v = acc[i][j][r];
        size_t o = (size_t)(row + r) * N + col;
        if (EPI == 0) {
          outB[o] = f2bf(v);
        } else if (EPI == 1) {
          outF[o] = v + addend[o];
        } else if (EPI == 2) {
          v += bias[col];
          outB[o] = f2bf(v > 0.f ? v : 0.f);
        } else {
          outF[o] = v + bias[col] + addend[o];
        }
      }
    }
  }
}

// ---------------- 256x256 8-phase GEMM (T2+T3+T4+T5), bf16 out ----------------
#define READ_A(buf, mh)                                                      \
  _Pragma("unroll") for (int m4 = 0; m4 < 4; ++m4) {                         \
    int row_ = wm * 128 + ((mh)*4 + m4) * 16 + lrow;                         \
    _Pragma("unroll") for (int k_ = 0; k_ < 2; ++k_) {                       \
      int sl_ = (k_ * 4 + kk) ^ (row_ & 7);                                  \
      aA[m4][k_] = *(const bf16x8*)&lds[buf][0][row_ * 64 + sl_ * 8];        \
    }                                                                        \
  }
#define READ_B2(buf, pr)                                                     \
  _Pragma("unroll") for (int nn = 0; nn < 2; ++nn) {                         \
    int n_ = (pr)*2 + nn;                                                    \
    int row_ = wn * 64 + n_ * 16 + lrow;                                     \
    _Pragma("unroll") for (int k_ = 0; k_ < 2; ++k_) {                       \
      int sl_ = (k_ * 4 + kk) ^ (row_ & 7);                                  \
      bB[n_][k_] = *(const bf16x8*)&lds[buf][1][row_ * 64 + sl_ * 8];        \
    }                                                                        \
  }
#define MFMA16(mh, nh)                                                       \
  _Pragma("unroll") for (int m4 = 0; m4 < 4; ++m4)                           \
  _Pragma("unroll") for (int n2 = 0; n2 < 2; ++n2)                           \
  _Pragma("unroll") for (int k_ = 0; k_ < 2; ++k_)                           \
    acc[(mh)*4 + m4][(nh)*2 + n2] = __builtin_amdgcn_mfma_f32_16x16x32_bf16( \
        aA[m4][k_], bB[(nh)*2 + n2][k_], acc[(mh)*4 + m4][(nh)*2 + n2], 0, 0, 0);
#define STAGE_HALF(buf, mat, half, kt)                                       \
  {                                                                          \
    const short* g_ = ((mat) ? Bb : Ab) + (size_t)((half)*128) * K + (kt)*64;\
    short* l_ = &lds[buf][mat][(half)*8192];                                 \
    _Pragma("unroll") for (int it_ = 0; it_ < 2; ++it_) {                    \
      int ci_ = it_ * 512 + tid;                                             \
      int r_ = ci_ >> 3, sl_ = (ci_ & 7) ^ (r_ & 7);                         \
      __builtin_amdgcn_global_load_lds(GLOBAL_AS(g_ + (size_t)r_ * K + sl_ * 8), \
                                       LDS_AS(l_ + ci_ * 8), 16, 0, 0);      \
    }                                                                        \
  }
#define PH_SYNC1()                                                           \
  __builtin_amdgcn_s_barrier();                                              \
  asm volatile("s_waitcnt lgkmcnt(0)" ::: "memory");                         \
  __builtin_amdgcn_sched_barrier(0);                                         \
  __builtin_amdgcn_s_setprio(1)
#define PH_SYNC2()                                                           \
  __builtin_amdgcn_s_setprio(0);                                             \
  __builtin_amdgcn_s_barrier()
#define PH_SYNC2_VM(n)                                                       \
  __builtin_amdgcn_s_setprio(0);                                             \
  asm volatile("s_waitcnt vmcnt(" #n ")" ::: "memory");                      \
  __builtin_amdgcn_s_barrier()

template <int EPI>
__global__ __launch_bounds__(512, 2) void gemm256_kernel(
    const short* __restrict__ A, const short* __restrict__ BT,
    int N, int K, int kslice, size_t pstride,
    short* __restrict__ outB, const float* __restrict__ bias) {
  __shared__ short lds[2][2][16384];   // [buf][A/B][256 rows x 64 k], 128 KiB
  const int tid = threadIdx.x;
  const int lane = tid & 63, wid = tid >> 6;
  const int lrow = lane & 15, kk = lane >> 4;
  const int wm = wid >> 2, wn = wid & 3;
  const int row0 = blockIdx.y * 256, col0 = blockIdx.x * 256;
  const int kbase = blockIdx.z * kslice;
  const int NT = kslice >> 6;

  const short* Ab = A + (size_t)row0 * K + kbase;
  const short* Bb = BT + (size_t)col0 * K + kbase;

  f32x4 acc[8][4] = {};
  bf16x8 aA[4][2], bB[4][2];

  STAGE_HALF(0, 1, 0, 0); STAGE_HALF(0, 0, 0, 0);
  STAGE_HALF(0, 1, 1, 0); STAGE_HALF(0, 0, 1, 0);
  STAGE_HALF(1, 1, 0, 1); STAGE_HALF(1, 0, 0, 1); STAGE_HALF(1, 0, 1, 1);
  asm volatile("s_waitcnt vmcnt(6)" ::: "memory");
  __builtin_amdgcn_s_barrier();

  const int iters = NT >> 1;
  for (int i = 0; i < iters; ++i) {
    const int t1 = 2 * i + 1;
    int kt2 = 2 * i + 2; if (kt2 >= NT) kt2 -= NT;
    int kt3 = 2 * i + 3; if (kt3 >= NT) kt3 -= NT;
    READ_A(0, 0); READ_B2(0, 0); STAGE_HALF(1, 1, 1, t1);
    PH_SYNC1(); MFMA16(0, 0); PH_SYNC2();
    READ_B2(0, 1);
    PH_SYNC1(); MFMA16(0, 1); PH_SYNC2();
    READ_A(0, 1); STAGE_HALF(0, 1, 0, kt2);
    PH_SYNC1(); MFMA16(1, 0); PH_SYNC2();
    STAGE_HALF(0, 0, 0, kt2);
    PH_SYNC1(); MFMA16(1, 1); PH_SYNC2_VM(4);
    READ_A(1, 0); READ_B2(1, 0); STAGE_HALF(0, 1, 1, kt2);
    PH_SYNC1(); MFMA16(0, 0); PH_SYNC2();
    READ_B2(1, 1); STAGE_HALF(0, 0, 1, kt2);
    PH_SYNC1(); MFMA16(0, 1); PH_SYNC2();
    READ_A(1, 1); STAGE_HALF(1, 1, 0, kt3);
    PH_SYNC1(); MFMA16(1, 0); PH_SYNC2();
    STAGE_HALF(1, 0, 0, kt3); STAGE_HALF(1, 0, 1, kt3);
    PH_SYNC1(); MFMA16(1, 1); PH_SYNC2_VM(6);
  }

  short* ob = outB + (size_t)blockIdx.z * pstride;
#pragma unroll
  for (int m = 0; m < 8; ++m) {
    int row = row0 + wm * 128 + m * 16 + kk * 4;
#pragma unroll
    for (int n = 0; n < 4; ++n) {
      int col = col0 + wn * 64 + n * 16 + lrow;
#pragma unroll
      for (int r = 0; r < 4; ++r) {
        float v = acc[m][n][r];
        size_t o = (size_t)(row + r) * N + col;
        if (EPI == 0) {
          ob[o] = f2bf(v);
        } else {
          v += bias[col];
          ob[o] = f2bf(v > 0.f ? v : 0.f);
        }
      }
    }
  }
}

// out[i] = sum_{s<4} part[s][i] + bias[i % 1024] + addend[i]   (W2 split-K reduce)
__global__ __launch_bounds__(256) void reduce4_kernel(
    const short* __restrict__ part, const float* __restrict__ bias,
    const float* __restrict__ addend, float* __restrict__ out) {
  const size_t MN = (size_t)4096 * 1024;
  size_t i8 = ((size_t)blockIdx.x * 256 + threadIdx.x) * 8;
  bf16x8 p0 = *(const bf16x8*)&part[i8];
  bf16x8 p1 = *(const bf16x8*)&part[MN + i8];
  bf16x8 p2 = *(const bf16x8*)&part[2 * MN + i8];
  bf16x8 p3 = *(const bf16x8*)&part[3 * MN + i8];
  int col = (int)(i8 & 1023);
#pragma unroll
  for (int j = 0; j < 8; ++j) {
    float v = (bf2f(p0[j]) + bf2f(p1[j])) + (bf2f(p2[j]) + bf2f(p3[j]));
    out[i8 + j] = v + bias[col + j] + addend[i8 + j];
  }
}

// ---------------- flash attention v9: KV-split, 8-wave blocks ----------------
// Same tiles/swizzles/schedule as v8, but 512-thread blocks: 8 waves x 16
// q-rows (was 4 x 32). LDS per block unchanged (80KB, K/V shared by 8 waves)
// -> 2 blocks/CU = 16 waves/CU = 4/SIMD (2x the latency-hiding pool); per-wave
// serial chain halves. __launch_bounds__(512,4) pins VGPR <= 128.
__device__ const unsigned char QT_SLOT[48] = {
    31, 31, 30, 15, 30, 29, 29, 28, 14, 28, 27, 27, 26, 13, 26, 25,
    25, 24, 12, 24, 23, 23, 22, 11, 22, 21, 21, 20, 10, 20, 19, 19,
    18,  9, 18, 17, 17, 16,  8, 16,  7,  6,  5,  4,  3,  2,  1,  0};
__device__ const unsigned char SP_SLOT[48] = {
    0, 1, 0, 0, 1, 0, 1, 0, 0, 1, 0, 1, 0, 0, 1, 0,
    1, 0, 0, 1, 0, 1, 0, 0, 1, 0, 1, 0, 0, 1, 0, 1,
    0, 0, 1, 0, 1, 0, 0, 1, 0, 0, 0, 0, 0, 0, 0, 0};

__global__ __launch_bounds__(512, 4) void attn_kernel(
    const short* __restrict__ QK, const short* __restrict__ VT,
    float* __restrict__ opart, float* __restrict__ lpart) {
  const int S = 4096;
  __shared__ short Ks[2][128 * 64];
  __shared__ short Vs[2][64 * 128];
  __shared__ short Ps[8][16 * 64];

  const int tid = threadIdx.x;
  const int lane = tid & 63;
  const int w = tid >> 6;                     // 0..7
  const int lrow = lane & 15;
  const int kk = lane >> 4;
  const int bid = blockIdx.x;
  const int h = bid & 15;
  const int slot = bid >> 4;
  const int qtile = QT_SLOT[slot];
  const int sp = SP_SLOT[slot];
  const int T = qtile + 1;                    // total 128-key tiles for this qtile
  const bool split = (qtile >= 16);
  const int half = (T + 1) >> 1;
  const int t0 = (split && sp) ? half : 0;
  const int t1 = (split && !sp) ? half : T;
  const int q0 = qtile * 128;
  const int qw = q0 + w * 16;                 // 16 q-rows per wave

  auto stage = [&](int buf, int t) {
    const int kv0 = t * 128;
#pragma unroll
    for (int it = 0; it < 2; ++it) {
      int ci = it * 512 + tid;                // 16B chunks, 1024 per matrix
      int krow = ci >> 3;                     // 128 K rows x 8 slots
      int ksl = (ci & 7) ^ (krow & 7);
      int vrow = ci >> 4;                     // 64 V rows x 16 slots
      int vsl = (ci & 15) ^ (vrow & 15);
      const short* gk = QK + (size_t)(kv0 + krow) * 2048 + 1024 + h * 64 + ksl * 8;
      const short* gv = VT + (size_t)(h * 64 + vrow) * S + kv0 + vsl * 8;
      __builtin_amdgcn_global_load_lds(GLOBAL_AS(gk),
                                       LDS_AS(&Ks[buf][(it * 512 + w * 64) * 8]), 16, 0, 0);
      __builtin_amdgcn_global_load_lds(GLOBAL_AS(gv),
                                       LDS_AS(&Vs[buf][(it * 512 + w * 64) * 8]), 16, 0, 0);
    }
  };

  bf16x8 qf[2];
#pragma unroll
  for (int half2 = 0; half2 < 2; ++half2)
    qf[half2] = *(const bf16x8*)&QK[(size_t)(qw + lrow) * 2048 +
                                    h * 64 + half2 * 32 + kk * 8];

  float rs_acc[4] = {};
  f32x4 o_acc[4] = {};

  stage(0, t0);
  __syncthreads();
  int cur = 0;

  for (int t = t0; t < t1; ++t) {
    if (t + 1 < t1) stage(cur ^ 1, t + 1);    // prefetch next 128-key tile

#pragma unroll
    for (int h2 = 0; h2 < 2; ++h2) {
      const int kvc = t * 128 + h2 * 64;
      if (kvc > qw + 15) continue;            // chunk fully masked for wave

      // ---- QK^T over this 64-key chunk (8 MFMA) ----
      bf16x8 kf[4][2];
#pragma unroll
      for (int c = 0; c < 4; ++c)
#pragma unroll
        for (int half2 = 0; half2 < 2; ++half2) {
          int krow = h2 * 64 + c * 16 + lrow;
          kf[c][half2] = *(const bf16x8*)&Ks[cur][krow * 64 + (((half2 * 4 + kk) ^ (lrow & 7)) * 8)];
        }
      f32x4 sc[4];
      __builtin_amdgcn_s_setprio(1);
#pragma unroll
      for (int c = 0; c < 4; ++c) {
        f32x4 z = {};
        z = __builtin_amdgcn_mfma_f32_16x16x32_bf16(qf[0], kf[c][0], z, 0, 0, 0);
        z = __builtin_amdgcn_mfma_f32_16x16x32_bf16(qf[1], kf[c][1], z, 0, 0, 0);
        sc[c] = z;
      }
      __builtin_amdgcn_s_setprio(0);

      // ---- softmax numerator (scores pre-scaled via WQ) ----
      if (kvc + 63 <= qw) {
#pragma unroll
        for (int r = 0; r < 4; ++r) {
          const int qrow = kk * 4 + r;
          float ps[4];
#pragma unroll
          for (int c = 0; c < 4; ++c) {
            float p = __expf(sc[c][r]);
            ps[c] = p;
            int col = c * 16 + lrow;
            Ps[w][qrow * 64 + (((col >> 3) ^ (qrow & 7)) * 8) + (col & 7)] = f2bf(p);
          }
          rs_acc[r] += (ps[0] + ps[1]) + (ps[2] + ps[3]);
        }
      } else {
#pragma unroll
        for (int r = 0; r < 4; ++r) {
          const int qrow = kk * 4 + r;
          const int q = qw + qrow;
          float ps[4];
#pragma unroll
          for (int c = 0; c < 4; ++c) {
            float p = __expf(sc[c][r]);
            if (kvc + c * 16 + lrow > q) p = 0.f;
            ps[c] = p;
            int col = c * 16 + lrow;
            Ps[w][qrow * 64 + (((col >> 3) ^ (qrow & 7)) * 8) + (col & 7)] = f2bf(p);
          }
          rs_acc[r] += (ps[0] + ps[1]) + (ps[2] + ps[3]);
        }
      }

      // ---- PV over this chunk (8 MFMA) ----
#pragma unroll
      for (int ks = 0; ks < 2; ++ks) {
        bf16x8 pf2, vf[4];
        {
          int qrow = lrow;
          pf2 = *(const bf16x8*)&Ps[w][qrow * 64 + (((ks * 4 + kk) ^ (qrow & 7)) * 8)];
        }
#pragma unroll
        for (int g = 0; g < 4; ++g) {
          int erow = g * 16 + lrow;
          vf[g] = *(const bf16x8*)&Vs[cur][erow * 128 + (((h2 * 8 + ks * 4 + kk) ^ (lrow & 15)) * 8)];
        }
        __builtin_amdgcn_s_setprio(1);
#pragma unroll
        for (int g = 0; g < 4; ++g)
          o_acc[g] = __builtin_amdgcn_mfma_f32_16x16x32_bf16(pf2, vf[g], o_acc[g], 0, 0, 0);
        __builtin_amdgcn_s_setprio(0);
      }
    }

    __syncthreads();                          // drain prefetch + swap
    cur ^= 1;
  }

  // ---- epilogue: write fp32 partials (o unnormalized, l row-sum) ----
  const int pidx = (h * 32 + qtile) * 2 + sp;
  float* op = opart + (size_t)pidx * 8192;    // [128 q][64 d]
  float* lp = lpart + pidx * 128;
#pragma unroll
  for (int r = 0; r < 4; ++r) {
    float l = rs_acc[r];
    l += __shfl_xor(l, 1);
    l += __shfl_xor(l, 2);
    l += __shfl_xor(l, 4);
    l += __shfl_xor(l, 8);
    if (lrow == 0) lp[w * 16 + kk * 4 + r] = l;
  }
#pragma unroll
  for (int g = 0; g < 4; ++g)
#pragma unroll
    for (int r = 0; r < 4; ++r)
      op[(w * 16 + kk * 4 + r) * 64 + g * 16 + lrow] = o_acc[g][r];
}

// combine: attn_o[srow][col] = bf16( sum_s o_s / sum_s l_s )
__global__ __launch_bounds__(256) void attn_combine_kernel(
    const float* __restrict__ opart, const float* __restrict__ lpart,
    short* __restrict__ O) {
  size_t e8 = ((size_t)blockIdx.x * 256 + threadIdx.x) * 8;   // into [4096][1024]
  const int srow = (int)(e8 >> 10);
  const int col = (int)(e8 & 1023);
  const int h = col >> 6, d = col & 63;
  const int qtile = srow >> 7, qr = srow & 127;
  const int pb = (h * 32 + qtile) * 2;
  const float* o0 = opart + (size_t)pb * 8192 + qr * 64 + d;
  float l = lpart[pb * 128 + qr];
  float4 a0 = *(const float4*)o0;
  float4 a1 = *(const float4*)(o0 + 4);
  if (qtile >= 16) {
    const float* o1 = opart + (size_t)(pb + 1) * 8192 + qr * 64 + d;
    float4 b0 = *(const float4*)o1;
    float4 b1 = *(const float4*)(o1 + 4);
    a0.x += b0.x; a0.y += b0.y; a0.z += b0.z; a0.w += b0.w;
    a1.x += b1.x; a1.y += b1.y; a1.z += b1.z; a1.w += b1.w;
    l += lpart[(pb + 1) * 128 + qr];
  }
  float inv = 1.f / l;
  bf16x8 o;
  o[0] = f2bf(a0.x * inv); o[1] = f2bf(a0.y * inv);
  o[2] = f2bf(a0.z * inv); o[3] = f2bf(a0.w * inv);
  o[4] = f2bf(a1.x * inv); o[5] = f2bf(a1.y * inv);
  o[6] = f2bf(a1.z * inv); o[7] = f2bf(a1.w * inv);
  *(bf16x8*)&O[e8] = o;
}

// ---------------- launch ----------------
extern "C" void kernel_launch(void* const* d_in, const int* in_sizes, int n_in,
                              void* d_out, int out_size, void* d_ws, size_t ws_size,
                              hipStream_t stream) {
  const float* x  = (const float*)d_in[0];
  const float* g1 = (const float*)d_in[2];
  const float* WQ = (const float*)d_in[3];
  const float* WK = (const float*)d_in[4];
  const float* WV = (const float*)d_in[5];
  const float* WO = (const float*)d_in[6];
  const float* g2 = (const float*)d_in[7];
  const float* W1 = (const float*)d_in[8];
  const float* B1 = (const float*)d_in[9];
  const float* W2 = (const float*)d_in[10];
  const float* B2 = (const float*)d_in[11];
  float* out = (float*)d_out;

  const int S = 4096, D = 1024, H = 16;

  char* ws = (char*)d_ws;
  size_t off = 0;
  auto alloc = [&](size_t bytes) -> void* {
    void* p = ws + off;
    off += (bytes + 255) & ~(size_t)255;
    return p;
  };
  short* h1     = (short*)alloc((size_t)S * D * 2);
  short* wqkv_t = (short*)alloc((size_t)3072 * 1024 * 2);
  short* qk     = (short*)alloc((size_t)S * 2048 * 2);
  short* vt     = (short*)alloc((size_t)1024 * S * 2);
  short* attn_o = (short*)alloc((size_t)S * D * 2);
  short* wo_t   = (short*)alloc((size_t)1024 * 1024 * 2);
  float* x2     = (float*)alloc((size_t)S * D * 4);
  short* h2     = (short*)alloc((size_t)S * D * 2);
  short* w1_t   = (short*)alloc((size_t)4096 * 1024 * 2);
  short* m1     = (short*)alloc((size_t)S * 4096 * 2);
  short* w2_t   = (short*)alloc((size_t)1024 * 4096 * 2);
  short* partW2 = qk;          // W2 split-K partials alias qk+vt+attn_o (dead by then)
  float* opart  = (float*)m1;  // attn o-partials: 33.55MB = m1 (dead until W1)
  float* lpart  = (float*)h1;  // attn l-partials: 512KB (h1 dead after qk/vt GEMMs)

  // weight prep
  pack_qkv_kernel<<<dim3(D / 64, 48), 256, 0, stream>>>(WQ, WK, WV, wqkv_t);
  transpose_bf16_kernel<<<dim3(1024 / 64, 1024 / 64), 256, 0, stream>>>(WO, wo_t, 1024, 1024);
  transpose_bf16_kernel<<<dim3(4096 / 64, 1024 / 64), 256, 0, stream>>>(W1, w1_t, 1024, 4096);
  transpose_bf16_kernel<<<dim3(1024 / 64, 4096 / 64), 256, 0, stream>>>(W2, w2_t, 4096, 1024);

  // attention sub-block
  rmsnorm_kernel<<<S, 256, 0, stream>>>(x, g1, h1, D);
  gemm_bt_kernel<0><<<dim3(2048 / 128, S / 128), 256, 0, stream>>>(
      h1, wqkv_t, S, 2048, 1024, qk, nullptr, nullptr, nullptr);
  gemm_bt_kernel<0><<<dim3(S / 128, 1024 / 128), 256, 0, stream>>>(
      wqkv_t + (size_t)2048 * 1024, h1, 1024, S, 1024, vt, nullptr, nullptr, nullptr);
  attn_kernel<<<dim3(768), 512, 0, stream>>>(qk, vt, opart, lpart);
  attn_combine_kernel<<<dim3((S * 1024 / 8) / 256), 256, 0, stream>>>(opart, lpart, attn_o);
  gemm_bt_kernel<1><<<dim3(1024 / 128, S / 128), 256, 0, stream>>>(
      attn_o, wo_t, S, 1024, 1024, nullptr, x2, nullptr, x);

  // MLP sub-block
  rmsnorm_kernel<<<S, 256, 0, stream>>>(x2, g2, h2, D);
  gemm256_kernel<2><<<dim3(4096 / 256, 4096 / 256, 1), 512, 0, stream>>>(
      h2, w1_t, 4096, 1024, 1024, 0, m1, B1);
  gemm256_kernel<0><<<dim3(1024 / 256, 4096 / 256, 4), 512, 0, stream>>>(
      m1, w2_t, 1024, 4096, 1024, (size_t)4096 * 1024, partW2, nullptr);
  reduce4_kernel<<<2048, 256, 0, stream>>>(partW2, B2, x2, out);
}

// Round 11
// 249.524 us; speedup vs baseline: 1.1339x; 1.0671x over previous
//
#include <hip/hip_runtime.h>
#include <hip/hip_bf16.h>

typedef __attribute__((ext_vector_type(8))) short bf16x8;
typedef __attribute__((ext_vector_type(4))) float f32x4;
typedef __attribute__((ext_vector_type(4))) short s16x4;

#define GLOBAL_AS(p) ((const __attribute__((address_space(1))) void*)(p))
#define LDS_AS(p)    ((__attribute__((address_space(3))) void*)(p))

__device__ __forceinline__ short f2bf(float f) {
  return __builtin_bit_cast(short, __float2bfloat16(f));   // HW RNE cvt
}
__device__ __forceinline__ float bf2f(short s) {
  return __bfloat162float(__builtin_bit_cast(__hip_bfloat16, s));
}

// ---------------- weight prep (LDS-tiled, coalesced both sides) ----------------
// Q-projection weights pre-scaled by 1/sqrt(dh)=0.125 (exact in bf16).
__global__ __launch_bounds__(256) void pack_qkv_kernel(
    const float* __restrict__ WQ, const float* __restrict__ WK,
    const float* __restrict__ WV, short* __restrict__ out) {
  __shared__ short Ls[64][66];
  const int tid = threadIdx.x;
  const int l = tid & 63, q4 = tid >> 6;
  const int hh = blockIdx.y & 15, proj = blockIdx.y >> 4;
  const float* W = (proj == 0) ? WQ : ((proj == 1) ? WK : WV);
  const float scl = (proj == 0) ? 0.125f : 1.f;
  const int d0 = blockIdx.x * 64;
#pragma unroll
  for (int rep = 0; rep < 16; ++rep) {
    int dd = q4 * 16 + rep;
    Ls[dd][l] = f2bf(W[(size_t)hh * 65536 + (size_t)(d0 + dd) * 64 + l] * scl);
  }
  __syncthreads();
#pragma unroll
  for (int rep = 0; rep < 16; ++rep) {
    int ee = q4 * 16 + rep;
    out[(size_t)(proj * 1024 + hh * 64 + ee) * 1024 + d0 + l] = Ls[l][ee];
  }
}

__global__ __launch_bounds__(256) void transpose_bf16_kernel(
    const float* __restrict__ in, short* __restrict__ out, int R, int C) {
  __shared__ short Ls[64][66];
  const int tid = threadIdx.x;
  const int l = tid & 63, q4 = tid >> 6;
  const int c0 = blockIdx.x * 64, r0 = blockIdx.y * 64;
#pragma unroll
  for (int rep = 0; rep < 16; ++rep) {
    int rr = q4 * 16 + rep;
    Ls[rr][l] = f2bf(in[(size_t)(r0 + rr) * C + c0 + l]);
  }
  __syncthreads();
#pragma unroll
  for (int rep = 0; rep < 16; ++rep) {
    int cc = q4 * 16 + rep;
    out[(size_t)(c0 + cc) * R + r0 + l] = Ls[l][cc];
  }
}

// V columns of qkv [S][3072] (cols 2048..3071) -> vt [1024][S], bf16->bf16
__global__ __launch_bounds__(256) void transpose_v_kernel(
    const short* __restrict__ qkv, short* __restrict__ vt, int S) {
  __shared__ short Ls[64][66];
  const int tid = threadIdx.x;
  const int l = tid & 63, q4 = tid >> 6;
  const int s0 = blockIdx.x * 64, e0 = blockIdx.y * 64;
#pragma unroll
  for (int rep = 0; rep < 16; ++rep) {
    int rr = q4 * 16 + rep;
    Ls[rr][l] = qkv[(size_t)(s0 + rr) * 3072 + 2048 + e0 + l];
  }
  __syncthreads();
#pragma unroll
  for (int rep = 0; rep < 16; ++rep) {
    int ee = q4 * 16 + rep;
    vt[(size_t)(e0 + ee) * S + s0 + l] = Ls[l][ee];
  }
}

// ---------------- RMSNorm (fp32 in -> bf16 out) ----------------
__global__ __launch_bounds__(256) void rmsnorm_kernel(
    const float* __restrict__ x, const float* __restrict__ g,
    short* __restrict__ out, int D) {
  const int row = blockIdx.x;
  const int tid = threadIdx.x;
  const float4 xv = *(const float4*)&x[(size_t)row * D + tid * 4];
  float ss = xv.x * xv.x + xv.y * xv.y + xv.z * xv.z + xv.w * xv.w;
#pragma unroll
  for (int off = 32; off; off >>= 1) ss += __shfl_xor(ss, off);
  __shared__ float red[4];
  if ((tid & 63) == 0) red[tid >> 6] = ss;
  __syncthreads();
  float tot = red[0] + red[1] + red[2] + red[3];
  float scale = rsqrtf(tot / (float)D + 1e-6f);
  const float4 gv = *(const float4*)&g[tid * 4];
  s16x4 o;
  o[0] = f2bf(xv.x * scale * gv.x);
  o[1] = f2bf(xv.y * scale * gv.y);
  o[2] = f2bf(xv.z * scale * gv.z);
  o[3] = f2bf(xv.w * scale * gv.w);
  *(s16x4*)&out[(size_t)row * D + tid * 4] = o;
}

// ---------------- 128x128 GEMM (m97 structure): C = A[M,K] x BT[N,K]^T ----------------
template <int EPI>
__global__ __launch_bounds__(256) void gemm_bt_kernel(
    const short* __restrict__ A, const short* __restrict__ BT,
    int M, int N, int K,
    short* __restrict__ outB, float* __restrict__ outF,
    const float* __restrict__ bias, const float* __restrict__ addend) {
  __shared__ short As[128 * 32];
  __shared__ short Bs[128 * 32];
  const int tid = threadIdx.x;
  const int lane = tid & 63;
  const int wid = tid >> 6;
  const int lrow = lane & 15;
  const int kk = lane >> 4;
  const int row0 = blockIdx.y * 128;
  const int col0 = blockIdx.x * 128;
  const int wm = wid >> 1, wn = wid & 1;

  f32x4 acc[4][4] = {};

  for (int k0 = 0; k0 < K; k0 += 32) {
    __syncthreads();
#pragma unroll
    for (int it = 0; it < 2; ++it) {
      int c = it * 256 + tid;
      int r = c >> 2, c8 = (c & 3) * 8;
      const short* ga = A + (size_t)(row0 + r) * K + k0 + c8;
      const short* gb = BT + (size_t)(col0 + r) * K + k0 + c8;
      short* la = &As[(size_t)(it * 256 + wid * 64) * 8];
      short* lb = &Bs[(size_t)(it * 256 + wid * 64) * 8];
      __builtin_amdgcn_global_load_lds(GLOBAL_AS(ga), LDS_AS(la), 16, 0, 0);
      __builtin_amdgcn_global_load_lds(GLOBAL_AS(gb), LDS_AS(lb), 16, 0, 0);
    }
    __syncthreads();

    bf16x8 a[4], b[4];
#pragma unroll
    for (int i = 0; i < 4; ++i)
      a[i] = *(const bf16x8*)&As[(wm * 64 + i * 16 + lrow) * 32 + kk * 8];
#pragma unroll
    for (int i = 0; i < 4; ++i)
      b[i] = *(const bf16x8*)&Bs[(wn * 64 + i * 16 + lrow) * 32 + kk * 8];
#pragma unroll
    for (int i = 0; i < 4; ++i)
#pragma unroll
      for (int j = 0; j < 4; ++j)
        acc[i][j] = __builtin_amdgcn_mfma_f32_16x16x32_bf16(a[i], b[j], acc[i][j], 0, 0, 0);
  }

#pragma unroll
  for (int i = 0; i < 4; ++i) {
    int row = row0 + wm * 64 + i * 16 + kk * 4;
#pragma unroll
    for (int j = 0; j < 4; ++j) {
      int col = col0 + wn * 64 + j * 16 + lrow;
#pragma unroll
      for (int r = 0; r < 4; ++r) {
        float v = acc[i][j][r];
        size_t o = (size_t)(row + r) * N + col;
        if (EPI == 0) {
          outB[o] = f2bf(v);
        } else if (EPI == 1) {
          outF[o] = v + addend[o];
        } else if (EPI == 2) {
          v += bias[col];
          outB[o] = f2bf(v > 0.f ? v : 0.f);
        } else {
          outF[o] = v + bias[col] + addend[o];
        }
      }
    }
  }
}

// ---------------- 256x256 8-phase GEMM (T2+T3+T4+T5), bf16 out ----------------
#define READ_A(buf, mh)                                                      \
  _Pragma("unroll") for (int m4 = 0; m4 < 4; ++m4) {                         \
    int row_ = wm * 128 + ((mh)*4 + m4) * 16 + lrow;                         \
    _Pragma("unroll") for (int k_ = 0; k_ < 2; ++k_) {                       \
      int sl_ = (k_ * 4 + kk) ^ (row_ & 7);                                  \
      aA[m4][k_] = *(const bf16x8*)&lds[buf][0][row_ * 64 + sl_ * 8];        \
    }                                                                        \
  }
#define READ_B2(buf, pr)                                                     \
  _Pragma("unroll") for (int nn = 0; nn < 2; ++nn) {                         \
    int n_ = (pr)*2 + nn;                                                    \
    int row_ = wn * 64 + n_ * 16 + lrow;                                     \
    _Pragma("unroll") for (int k_ = 0; k_ < 2; ++k_) {                       \
      int sl_ = (k_ * 4 + kk) ^ (row_ & 7);                                  \
      bB[n_][k_] = *(const bf16x8*)&lds[buf][1][row_ * 64 + sl_ * 8];        \
    }                                                                        \
  }
#define MFMA16(mh, nh)                                                       \
  _Pragma("unroll") for (int m4 = 0; m4 < 4; ++m4)                           \
  _Pragma("unroll") for (int n2 = 0; n2 < 2; ++n2)                           \
  _Pragma("unroll") for (int k_ = 0; k_ < 2; ++k_)                           \
    acc[(mh)*4 + m4][(nh)*2 + n2] = __builtin_amdgcn_mfma_f32_16x16x32_bf16( \
        aA[m4][k_], bB[(nh)*2 + n2][k_], acc[(mh)*4 + m4][(nh)*2 + n2], 0, 0, 0);
#define STAGE_HALF(buf, mat, half, kt)                                       \
  {                                                                          \
    const short* g_ = ((mat) ? Bb : Ab) + (size_t)((half)*128) * K + (kt)*64;\
    short* l_ = &lds[buf][mat][(half)*8192];                                 \
    _Pragma("unroll") for (int it_ = 0; it_ < 2; ++it_) {                    \
      int ci_ = it_ * 512 + tid;                                             \
      int r_ = ci_ >> 3, sl_ = (ci_ & 7) ^ (r_ & 7);                         \
      __builtin_amdgcn_global_load_lds(GLOBAL_AS(g_ + (size_t)r_ * K + sl_ * 8), \
                                       LDS_AS(l_ + ci_ * 8), 16, 0, 0);      \
    }                                                                        \
  }
#define PH_SYNC1()                                                           \
  __builtin_amdgcn_s_barrier();                                              \
  asm volatile("s_waitcnt lgkmcnt(0)" ::: "memory");                         \
  __builtin_amdgcn_sched_barrier(0);                                         \
  __builtin_amdgcn_s_setprio(1)
#define PH_SYNC2()                                                           \
  __builtin_amdgcn_s_setprio(0);                                             \
  __builtin_amdgcn_s_barrier()
#define PH_SYNC2_VM(n)                                                       \
  __builtin_amdgcn_s_setprio(0);                                             \
  asm volatile("s_waitcnt vmcnt(" #n ")" ::: "memory");                      \
  __builtin_amdgcn_s_barrier()

template <int EPI>
__global__ __launch_bounds__(512, 2) void gemm256_kernel(
    const short* __restrict__ A, const short* __restrict__ BT,
    int N, int K, int kslice, size_t pstride,
    short* __restrict__ outB, const float* __restrict__ bias) {
  __shared__ short lds[2][2][16384];   // [buf][A/B][256 rows x 64 k], 128 KiB
  const int tid = threadIdx.x;
  const int lane = tid & 63, wid = tid >> 6;
  const int lrow = lane & 15, kk = lane >> 4;
  const int wm = wid >> 2, wn = wid & 3;
  const int row0 = blockIdx.y * 256, col0 = blockIdx.x * 256;
  const int kbase = blockIdx.z * kslice;
  const int NT = kslice >> 6;

  const short* Ab = A + (size_t)row0 * K + kbase;
  const short* Bb = BT + (size_t)col0 * K + kbase;

  f32x4 acc[8][4] = {};
  bf16x8 aA[4][2], bB[4][2];

  STAGE_HALF(0, 1, 0, 0); STAGE_HALF(0, 0, 0, 0);
  STAGE_HALF(0, 1, 1, 0); STAGE_HALF(0, 0, 1, 0);
  STAGE_HALF(1, 1, 0, 1); STAGE_HALF(1, 0, 0, 1); STAGE_HALF(1, 0, 1, 1);
  asm volatile("s_waitcnt vmcnt(6)" ::: "memory");
  __builtin_amdgcn_s_barrier();

  const int iters = NT >> 1;
  for (int i = 0; i < iters; ++i) {
    const int t1 = 2 * i + 1;
    int kt2 = 2 * i + 2; if (kt2 >= NT) kt2 -= NT;
    int kt3 = 2 * i + 3; if (kt3 >= NT) kt3 -= NT;
    READ_A(0, 0); READ_B2(0, 0); STAGE_HALF(1, 1, 1, t1);
    PH_SYNC1(); MFMA16(0, 0); PH_SYNC2();
    READ_B2(0, 1);
    PH_SYNC1(); MFMA16(0, 1); PH_SYNC2();
    READ_A(0, 1); STAGE_HALF(0, 1, 0, kt2);
    PH_SYNC1(); MFMA16(1, 0); PH_SYNC2();
    STAGE_HALF(0, 0, 0, kt2);
    PH_SYNC1(); MFMA16(1, 1); PH_SYNC2_VM(4);
    READ_A(1, 0); READ_B2(1, 0); STAGE_HALF(0, 1, 1, kt2);
    PH_SYNC1(); MFMA16(0, 0); PH_SYNC2();
    READ_B2(1, 1); STAGE_HALF(0, 0, 1, kt2);
    PH_SYNC1(); MFMA16(0, 1); PH_SYNC2();
    READ_A(1, 1); STAGE_HALF(1, 1, 0, kt3);
    PH_SYNC1(); MFMA16(1, 0); PH_SYNC2();
    STAGE_HALF(1, 0, 0, kt3); STAGE_HALF(1, 0, 1, kt3);
    PH_SYNC1(); MFMA16(1, 1); PH_SYNC2_VM(6);
  }

  short* ob = outB + (size_t)blockIdx.z * pstride;
#pragma unroll
  for (int m = 0; m < 8; ++m) {
    int row = row0 + wm * 128 + m * 16 + kk * 4;
#pragma unroll
    for (int n = 0; n < 4; ++n) {
      int col = col0 + wn * 64 + n * 16 + lrow;
#pragma unroll
      for (int r = 0; r < 4; ++r) {
        float v = acc[m][n][r];
        size_t o = (size_t)(row + r) * N + col;
        if (EPI == 0) {
          ob[o] = f2bf(v);
        } else {
          v += bias[col];
          ob[o] = f2bf(v > 0.f ? v : 0.f);
        }
      }
    }
  }
}

// out[i] = sum_{s<4} part[s][i] + bias[i % 1024] + addend[i]   (W2 split-K reduce)
__global__ __launch_bounds__(256) void reduce4_kernel(
    const short* __restrict__ part, const float* __restrict__ bias,
    const float* __restrict__ addend, float* __restrict__ out) {
  const size_t MN = (size_t)4096 * 1024;
  size_t i8 = ((size_t)blockIdx.x * 256 + threadIdx.x) * 8;
  bf16x8 p0 = *(const bf16x8*)&part[i8];
  bf16x8 p1 = *(const bf16x8*)&part[MN + i8];
  bf16x8 p2 = *(const bf16x8*)&part[2 * MN + i8];
  bf16x8 p3 = *(const bf16x8*)&part[3 * MN + i8];
  int col = (int)(i8 & 1023);
#pragma unroll
  for (int j = 0; j < 8; ++j) {
    float v = (bf2f(p0[j]) + bf2f(p1[j])) + (bf2f(p2[j]) + bf2f(p3[j]));
    out[i8 + j] = v + bias[col + j] + addend[i8 + j];
  }
}

// ---------------- flash attention v10: KV-split, 8-wave blocks, fused QKV input ----------------
// QKV: [S][3072] bf16 (Q at h*64, K at 1024+h*64); VT: [1024][S].
__device__ const unsigned char QT_SLOT[48] = {
    31, 31, 30, 15, 30, 29, 29, 28, 14, 28, 27, 27, 26, 13, 26, 25,
    25, 24, 12, 24, 23, 23, 22, 11, 22, 21, 21, 20, 10, 20, 19, 19,
    18,  9, 18, 17, 17, 16,  8, 16,  7,  6,  5,  4,  3,  2,  1,  0};
__device__ const unsigned char SP_SLOT[48] = {
    0, 1, 0, 0, 1, 0, 1, 0, 0, 1, 0, 1, 0, 0, 1, 0,
    1, 0, 0, 1, 0, 1, 0, 0, 1, 0, 1, 0, 0, 1, 0, 1,
    0, 0, 1, 0, 1, 0, 0, 1, 0, 0, 0, 0, 0, 0, 0, 0};

__global__ __launch_bounds__(512, 4) void attn_kernel(
    const short* __restrict__ QKV, const short* __restrict__ VT,
    float* __restrict__ opart, float* __restrict__ lpart) {
  const int S = 4096;
  __shared__ short Ks[2][128 * 64];
  __shared__ short Vs[2][64 * 128];
  __shared__ short Ps[8][16 * 64];

  const int tid = threadIdx.x;
  const int lane = tid & 63;
  const int w = tid >> 6;                     // 0..7
  const int lrow = lane & 15;
  const int kk = lane >> 4;
  const int bid = blockIdx.x;
  const int h = bid & 15;
  const int slot = bid >> 4;
  const int qtile = QT_SLOT[slot];
  const int sp = SP_SLOT[slot];
  const int T = qtile + 1;                    // total 128-key tiles for this qtile
  const bool split = (qtile >= 16);
  const int half = (T + 1) >> 1;
  const int t0 = (split && sp) ? half : 0;
  const int t1 = (split && !sp) ? half : T;
  const int q0 = qtile * 128;
  const int qw = q0 + w * 16;                 // 16 q-rows per wave

  auto stage = [&](int buf, int t) {
    const int kv0 = t * 128;
#pragma unroll
    for (int it = 0; it < 2; ++it) {
      int ci = it * 512 + tid;                // 16B chunks, 1024 per matrix
      int krow = ci >> 3;                     // 128 K rows x 8 slots
      int ksl = (ci & 7) ^ (krow & 7);
      int vrow = ci >> 4;                     // 64 V rows x 16 slots
      int vsl = (ci & 15) ^ (vrow & 15);
      const short* gk = QKV + (size_t)(kv0 + krow) * 3072 + 1024 + h * 64 + ksl * 8;
      const short* gv = VT + (size_t)(h * 64 + vrow) * S + kv0 + vsl * 8;
      __builtin_amdgcn_global_load_lds(GLOBAL_AS(gk),
                                       LDS_AS(&Ks[buf][(it * 512 + w * 64) * 8]), 16, 0, 0);
      __builtin_amdgcn_global_load_lds(GLOBAL_AS(gv),
                                       LDS_AS(&Vs[buf][(it * 512 + w * 64) * 8]), 16, 0, 0);
    }
  };

  bf16x8 qf[2];
#pragma unroll
  for (int half2 = 0; half2 < 2; ++half2)
    qf[half2] = *(const bf16x8*)&QKV[(size_t)(qw + lrow) * 3072 +
                                     h * 64 + half2 * 32 + kk * 8];

  float rs_acc[4] = {};
  f32x4 o_acc[4] = {};

  stage(0, t0);
  __syncthreads();
  int cur = 0;

  for (int t = t0; t < t1; ++t) {
    if (t + 1 < t1) stage(cur ^ 1, t + 1);    // prefetch next 128-key tile

#pragma unroll
    for (int h2 = 0; h2 < 2; ++h2) {
      const int kvc = t * 128 + h2 * 64;
      if (kvc > qw + 15) continue;            // chunk fully masked for wave

      // ---- QK^T over this 64-key chunk (8 MFMA) ----
      bf16x8 kf[4][2];
#pragma unroll
      for (int c = 0; c < 4; ++c)
#pragma unroll
        for (int half2 = 0; half2 < 2; ++half2) {
          int krow = h2 * 64 + c * 16 + lrow;
          kf[c][half2] = *(const bf16x8*)&Ks[cur][krow * 64 + (((half2 * 4 + kk) ^ (lrow & 7)) * 8)];
        }
      f32x4 sc[4];
      __builtin_amdgcn_s_setprio(1);
#pragma unroll
      for (int c = 0; c < 4; ++c) {
        f32x4 z = {};
        z = __builtin_amdgcn_mfma_f32_16x16x32_bf16(qf[0], kf[c][0], z, 0, 0, 0);
        z = __builtin_amdgcn_mfma_f32_16x16x32_bf16(qf[1], kf[c][1], z, 0, 0, 0);
        sc[c] = z;
      }
      __builtin_amdgcn_s_setprio(0);

      // ---- softmax numerator (scores pre-scaled via WQ) ----
      if (kvc + 63 <= qw) {
#pragma unroll
        for (int r = 0; r < 4; ++r) {
          const int qrow = kk * 4 + r;
          float ps[4];
#pragma unroll
          for (int c = 0; c < 4; ++c) {
            float p = __expf(sc[c][r]);
            ps[c] = p;
            int col = c * 16 + lrow;
            Ps[w][qrow * 64 + (((col >> 3) ^ (qrow & 7)) * 8) + (col & 7)] = f2bf(p);
          }
          rs_acc[r] += (ps[0] + ps[1]) + (ps[2] + ps[3]);
        }
      } else {
#pragma unroll
        for (int r = 0; r < 4; ++r) {
          const int qrow = kk * 4 + r;
          const int q = qw + qrow;
          float ps[4];
#pragma unroll
          for (int c = 0; c < 4; ++c) {
            float p = __expf(sc[c][r]);
            if (kvc + c * 16 + lrow > q) p = 0.f;
            ps[c] = p;
            int col = c * 16 + lrow;
            Ps[w][qrow * 64 + (((col >> 3) ^ (qrow & 7)) * 8) + (col & 7)] = f2bf(p);
          }
          rs_acc[r] += (ps[0] + ps[1]) + (ps[2] + ps[3]);
        }
      }

      // ---- PV over this chunk (8 MFMA) ----
#pragma unroll
      for (int ks = 0; ks < 2; ++ks) {
        bf16x8 pf2, vf[4];
        {
          int qrow = lrow;
          pf2 = *(const bf16x8*)&Ps[w][qrow * 64 + (((ks * 4 + kk) ^ (qrow & 7)) * 8)];
        }
#pragma unroll
        for (int g = 0; g < 4; ++g) {
          int erow = g * 16 + lrow;
          vf[g] = *(const bf16x8*)&Vs[cur][erow * 128 + (((h2 * 8 + ks * 4 + kk) ^ (lrow & 15)) * 8)];
        }
        __builtin_amdgcn_s_setprio(1);
#pragma unroll
        for (int g = 0; g < 4; ++g)
          o_acc[g] = __builtin_amdgcn_mfma_f32_16x16x32_bf16(pf2, vf[g], o_acc[g], 0, 0, 0);
        __builtin_amdgcn_s_setprio(0);
      }
    }

    __syncthreads();                          // drain prefetch + swap
    cur ^= 1;
  }

  // ---- epilogue: write fp32 partials (o unnormalized, l row-sum) ----
  const int pidx = (h * 32 + qtile) * 2 + sp;
  float* op = opart + (size_t)pidx * 8192;    // [128 q][64 d]
  float* lp = lpart + pidx * 128;
#pragma unroll
  for (int r = 0; r < 4; ++r) {
    float l = rs_acc[r];
    l += __shfl_xor(l, 1);
    l += __shfl_xor(l, 2);
    l += __shfl_xor(l, 4);
    l += __shfl_xor(l, 8);
    if (lrow == 0) lp[w * 16 + kk * 4 + r] = l;
  }
#pragma unroll
  for (int g = 0; g < 4; ++g)
#pragma unroll
    for (int r = 0; r < 4; ++r)
      op[(w * 16 + kk * 4 + r) * 64 + g * 16 + lrow] = o_acc[g][r];
}

// combine: attn_o[srow][col] = bf16( sum_s o_s / sum_s l_s )
__global__ __launch_bounds__(256) void attn_combine_kernel(
    const float* __restrict__ opart, const float* __restrict__ lpart,
    short* __restrict__ O) {
  size_t e8 = ((size_t)blockIdx.x * 256 + threadIdx.x) * 8;   // into [4096][1024]
  const int srow = (int)(e8 >> 10);
  const int col = (int)(e8 & 1023);
  const int h = col >> 6, d = col & 63;
  const int qtile = srow >> 7, qr = srow & 127;
  const int pb = (h * 32 + qtile) * 2;
  const float* o0 = opart + (size_t)pb * 8192 + qr * 64 + d;
  float l = lpart[pb * 128 + qr];
  float4 a0 = *(const float4*)o0;
  float4 a1 = *(const float4*)(o0 + 4);
  if (qtile >= 16) {
    const float* o1 = opart + (size_t)(pb + 1) * 8192 + qr * 64 + d;
    float4 b0 = *(const float4*)o1;
    float4 b1 = *(const float4*)(o1 + 4);
    a0.x += b0.x; a0.y += b0.y; a0.z += b0.z; a0.w += b0.w;
    a1.x += b1.x; a1.y += b1.y; a1.z += b1.z; a1.w += b1.w;
    l += lpart[(pb + 1) * 128 + qr];
  }
  float inv = 1.f / l;
  bf16x8 o;
  o[0] = f2bf(a0.x * inv); o[1] = f2bf(a0.y * inv);
  o[2] = f2bf(a0.z * inv); o[3] = f2bf(a0.w * inv);
  o[4] = f2bf(a1.x * inv); o[5] = f2bf(a1.y * inv);
  o[6] = f2bf(a1.z * inv); o[7] = f2bf(a1.w * inv);
  *(bf16x8*)&O[e8] = o;
}

// ---------------- launch ----------------
extern "C" void kernel_launch(void* const* d_in, const int* in_sizes, int n_in,
                              void* d_out, int out_size, void* d_ws, size_t ws_size,
                              hipStream_t stream) {
  const float* x  = (const float*)d_in[0];
  const float* g1 = (const float*)d_in[2];
  const float* WQ = (const float*)d_in[3];
  const float* WK = (const float*)d_in[4];
  const float* WV = (const float*)d_in[5];
  const float* WO = (const float*)d_in[6];
  const float* g2 = (const float*)d_in[7];
  const float* W1 = (const float*)d_in[8];
  const float* B1 = (const float*)d_in[9];
  const float* W2 = (const float*)d_in[10];
  const float* B2 = (const float*)d_in[11];
  float* out = (float*)d_out;

  const int S = 4096, D = 1024, H = 16;

  char* ws = (char*)d_ws;
  size_t off = 0;
  auto alloc = [&](size_t bytes) -> void* {
    void* p = ws + off;
    off += (bytes + 255) & ~(size_t)255;
    return p;
  };
  short* h1     = (short*)alloc((size_t)S * D * 2);
  short* wqkv_t = (short*)alloc((size_t)3072 * 1024 * 2);
  short* qkv    = (short*)alloc((size_t)S * 3072 * 2);   // fused QKV output
  short* vt     = (short*)alloc((size_t)1024 * S * 2);
  short* attn_o = (short*)alloc((size_t)S * D * 2);
  short* wo_t   = (short*)alloc((size_t)1024 * 1024 * 2);
  float* x2     = (float*)alloc((size_t)S * D * 4);
  short* h2     = (short*)alloc((size_t)S * D * 2);
  short* w1_t   = (short*)alloc((size_t)4096 * 1024 * 2);
  short* m1     = (short*)alloc((size_t)S * 4096 * 2);
  short* w2_t   = (short*)alloc((size_t)1024 * 4096 * 2);
  short* partW2 = qkv;         // W2 split-K partials (33.55MB) alias qkv(25.2)+vt(8.4) (dead by then)
  float* opart  = (float*)m1;  // attn o-partials: 33.55MB = m1 (dead until W1)
  float* lpart  = (float*)h1;  // attn l-partials: 512KB (h1 dead after QKV gemm)

  // weight prep
  pack_qkv_kernel<<<dim3(D / 64, 48), 256, 0, stream>>>(WQ, WK, WV, wqkv_t);
  transpose_bf16_kernel<<<dim3(1024 / 64, 1024 / 64), 256, 0, stream>>>(WO, wo_t, 1024, 1024);
  transpose_bf16_kernel<<<dim3(4096 / 64, 1024 / 64), 256, 0, stream>>>(W1, w1_t, 1024, 4096);
  transpose_bf16_kernel<<<dim3(1024 / 64, 4096 / 64), 256, 0, stream>>>(W2, w2_t, 4096, 1024);

  // attention sub-block
  rmsnorm_kernel<<<S, 256, 0, stream>>>(x, g1, h1, D);
  // fused QKV projection: one 256^2 8-phase GEMM, [S][3072]
  gemm256_kernel<0><<<dim3(3072 / 256, S / 256, 1), 512, 0, stream>>>(
      h1, wqkv_t, 3072, 1024, 1024, 0, qkv, nullptr);
  // V^T from qkv V-columns
  transpose_v_kernel<<<dim3(S / 64, 1024 / 64), 256, 0, stream>>>(qkv, vt, S);
  attn_kernel<<<dim3(768), 512, 0, stream>>>(qkv, vt, opart, lpart);
  attn_combine_kernel<<<dim3((S * 1024 / 8) / 256), 256, 0, stream>>>(opart, lpart, attn_o);
  gemm_bt_kernel<1><<<dim3(1024 / 128, S / 128), 256, 0, stream>>>(
      attn_o, wo_t, S, 1024, 1024, nullptr, x2, nullptr, x);

  // MLP sub-block
  rmsnorm_kernel<<<S, 256, 0, stream>>>(x2, g2, h2, D);
  gemm256_kernel<2><<<dim3(4096 / 256, 4096 / 256, 1), 512, 0, stream>>>(
      h2, w1_t, 4096, 1024, 1024, 0, m1, B1);
  gemm256_kernel<0><<<dim3(1024 / 256, 4096 / 256, 4), 512, 0, stream>>>(
      m1, w2_t, 1024, 4096, 1024, (size_t)4096 * 1024, partW2, nullptr);
  reduce4_kernel<<<2048, 256, 0, stream>>>(partW2, B2, x2, out);
}

// Round 12
// 244.277 us; speedup vs baseline: 1.1583x; 1.0215x over previous
//
#include <hip/hip_runtime.h>
#include <hip/hip_bf16.h>

typedef __attribute__((ext_vector_type(8))) short bf16x8;
typedef __attribute__((ext_vector_type(4))) float f32x4;
typedef __attribute__((ext_vector_type(4))) short s16x4;

#define GLOBAL_AS(p) ((const __attribute__((address_space(1))) void*)(p))
#define LDS_AS(p)    ((__attribute__((address_space(3))) void*)(p))

__device__ __forceinline__ short f2bf(float f) {
  return __builtin_bit_cast(short, __float2bfloat16(f));   // HW RNE cvt
}
__device__ __forceinline__ float bf2f(short s) {
  return __bfloat162float(__builtin_bit_cast(__hip_bfloat16, s));
}

// ---------------- weight prep (LDS-tiled, coalesced both sides) ----------------
// Q-projection weights pre-scaled by 1/sqrt(dh)=0.125 (exact in bf16).
__global__ __launch_bounds__(256) void pack_qkv_kernel(
    const float* __restrict__ WQ, const float* __restrict__ WK,
    const float* __restrict__ WV, short* __restrict__ out) {
  __shared__ short Ls[64][66];
  const int tid = threadIdx.x;
  const int l = tid & 63, q4 = tid >> 6;
  const int hh = blockIdx.y & 15, proj = blockIdx.y >> 4;
  const float* W = (proj == 0) ? WQ : ((proj == 1) ? WK : WV);
  const float scl = (proj == 0) ? 0.125f : 1.f;
  const int d0 = blockIdx.x * 64;
#pragma unroll
  for (int rep = 0; rep < 16; ++rep) {
    int dd = q4 * 16 + rep;
    Ls[dd][l] = f2bf(W[(size_t)hh * 65536 + (size_t)(d0 + dd) * 64 + l] * scl);
  }
  __syncthreads();
#pragma unroll
  for (int rep = 0; rep < 16; ++rep) {
    int ee = q4 * 16 + rep;
    out[(size_t)(proj * 1024 + hh * 64 + ee) * 1024 + d0 + l] = Ls[l][ee];
  }
}

__global__ __launch_bounds__(256) void transpose_bf16_kernel(
    const float* __restrict__ in, short* __restrict__ out, int R, int C) {
  __shared__ short Ls[64][66];
  const int tid = threadIdx.x;
  const int l = tid & 63, q4 = tid >> 6;
  const int c0 = blockIdx.x * 64, r0 = blockIdx.y * 64;
#pragma unroll
  for (int rep = 0; rep < 16; ++rep) {
    int rr = q4 * 16 + rep;
    Ls[rr][l] = f2bf(in[(size_t)(r0 + rr) * C + c0 + l]);
  }
  __syncthreads();
#pragma unroll
  for (int rep = 0; rep < 16; ++rep) {
    int cc = q4 * 16 + rep;
    out[(size_t)(c0 + cc) * R + r0 + l] = Ls[l][cc];
  }
}

// V columns of qkv [S][3072] (cols 2048..3071) -> vt [1024][S], bf16->bf16
__global__ __launch_bounds__(256) void transpose_v_kernel(
    const short* __restrict__ qkv, short* __restrict__ vt, int S) {
  __shared__ short Ls[64][66];
  const int tid = threadIdx.x;
  const int l = tid & 63, q4 = tid >> 6;
  const int s0 = blockIdx.x * 64, e0 = blockIdx.y * 64;
#pragma unroll
  for (int rep = 0; rep < 16; ++rep) {
    int rr = q4 * 16 + rep;
    Ls[rr][l] = qkv[(size_t)(s0 + rr) * 3072 + 2048 + e0 + l];
  }
  __syncthreads();
#pragma unroll
  for (int rep = 0; rep < 16; ++rep) {
    int ee = q4 * 16 + rep;
    vt[(size_t)(e0 + ee) * S + s0 + l] = Ls[l][ee];
  }
}

// ---------------- RMSNorm (fp32 in -> bf16 out) ----------------
__global__ __launch_bounds__(256) void rmsnorm_kernel(
    const float* __restrict__ x, const float* __restrict__ g,
    short* __restrict__ out, int D) {
  const int row = blockIdx.x;
  const int tid = threadIdx.x;
  const float4 xv = *(const float4*)&x[(size_t)row * D + tid * 4];
  float ss = xv.x * xv.x + xv.y * xv.y + xv.z * xv.z + xv.w * xv.w;
#pragma unroll
  for (int off = 32; off; off >>= 1) ss += __shfl_xor(ss, off);
  __shared__ float red[4];
  if ((tid & 63) == 0) red[tid >> 6] = ss;
  __syncthreads();
  float tot = red[0] + red[1] + red[2] + red[3];
  float scale = rsqrtf(tot / (float)D + 1e-6f);
  const float4 gv = *(const float4*)&g[tid * 4];
  s16x4 o;
  o[0] = f2bf(xv.x * scale * gv.x);
  o[1] = f2bf(xv.y * scale * gv.y);
  o[2] = f2bf(xv.z * scale * gv.z);
  o[3] = f2bf(xv.w * scale * gv.w);
  *(s16x4*)&out[(size_t)row * D + tid * 4] = o;
}

// ---------------- 128x128 GEMM (m97 structure): C = A[M,K] x BT[N,K]^T ----------------
template <int EPI>
__global__ __launch_bounds__(256) void gemm_bt_kernel(
    const short* __restrict__ A, const short* __restrict__ BT,
    int M, int N, int K,
    short* __restrict__ outB, float* __restrict__ outF,
    const float* __restrict__ bias, const float* __restrict__ addend) {
  __shared__ short As[128 * 32];
  __shared__ short Bs[128 * 32];
  const int tid = threadIdx.x;
  const int lane = tid & 63;
  const int wid = tid >> 6;
  const int lrow = lane & 15;
  const int kk = lane >> 4;
  const int row0 = blockIdx.y * 128;
  const int col0 = blockIdx.x * 128;
  const int wm = wid >> 1, wn = wid & 1;

  f32x4 acc[4][4] = {};

  for (int k0 = 0; k0 < K; k0 += 32) {
    __syncthreads();
#pragma unroll
    for (int it = 0; it < 2; ++it) {
      int c = it * 256 + tid;
      int r = c >> 2, c8 = (c & 3) * 8;
      const short* ga = A + (size_t)(row0 + r) * K + k0 + c8;
      const short* gb = BT + (size_t)(col0 + r) * K + k0 + c8;
      short* la = &As[(size_t)(it * 256 + wid * 64) * 8];
      short* lb = &Bs[(size_t)(it * 256 + wid * 64) * 8];
      __builtin_amdgcn_global_load_lds(GLOBAL_AS(ga), LDS_AS(la), 16, 0, 0);
      __builtin_amdgcn_global_load_lds(GLOBAL_AS(gb), LDS_AS(lb), 16, 0, 0);
    }
    __syncthreads();

    bf16x8 a[4], b[4];
#pragma unroll
    for (int i = 0; i < 4; ++i)
      a[i] = *(const bf16x8*)&As[(wm * 64 + i * 16 + lrow) * 32 + kk * 8];
#pragma unroll
    for (int i = 0; i < 4; ++i)
      b[i] = *(const bf16x8*)&Bs[(wn * 64 + i * 16 + lrow) * 32 + kk * 8];
#pragma unroll
    for (int i = 0; i < 4; ++i)
#pragma unroll
      for (int j = 0; j < 4; ++j)
        acc[i][j] = __builtin_amdgcn_mfma_f32_16x16x32_bf16(a[i], b[j], acc[i][j], 0, 0, 0);
  }

#pragma unroll
  for (int i = 0; i < 4; ++i) {
    int row = row0 + wm * 64 + i * 16 + kk * 4;
#pragma unroll
    for (int j = 0; j < 4; ++j) {
      int col = col0 + wn * 64 + j * 16 + lrow;
#pragma unroll
      for (int r = 0; r < 4; ++r) {
        float v = acc[i][j][r];
        size_t o = (size_t)(row + r) * N + col;
        if (EPI == 0) {
          outB[o] = f2bf(v);
        } else if (EPI == 1) {
          outF[o] = v + addend[o];
        } else if (EPI == 2) {
          v += bias[col];
          outB[o] = f2bf(v > 0.f ? v : 0.f);
        } else {
          outF[o] = v + bias[col] + addend[o];
        }
      }
    }
  }
}

// ---------------- 256x256 8-phase GEMM (T2+T3+T4+T5), bf16 out ----------------
#define READ_A(buf, mh)                                                      \
  _Pragma("unroll") for (int m4 = 0; m4 < 4; ++m4) {                         \
    int row_ = wm * 128 + ((mh)*4 + m4) * 16 + lrow;                         \
    _Pragma("unroll") for (int k_ = 0; k_ < 2; ++k_) {                       \
      int sl_ = (k_ * 4 + kk) ^ (row_ & 7);                                  \
      aA[m4][k_] = *(const bf16x8*)&lds[buf][0][row_ * 64 + sl_ * 8];        \
    }                                                                        \
  }
#define READ_B2(buf, pr)                                                     \
  _Pragma("unroll") for (int nn = 0; nn < 2; ++nn) {                         \
    int n_ = (pr)*2 + nn;                                                    \
    int row_ = wn * 64 + n_ * 16 + lrow;                                     \
    _Pragma("unroll") for (int k_ = 0; k_ < 2; ++k_) {                       \
      int sl_ = (k_ * 4 + kk) ^ (row_ & 7);                                  \
      bB[n_][k_] = *(const bf16x8*)&lds[buf][1][row_ * 64 + sl_ * 8];        \
    }                                                                        \
  }
#define MFMA16(mh, nh)                                                       \
  _Pragma("unroll") for (int m4 = 0; m4 < 4; ++m4)                           \
  _Pragma("unroll") for (int n2 = 0; n2 < 2; ++n2)                           \
  _Pragma("unroll") for (int k_ = 0; k_ < 2; ++k_)                           \
    acc[(mh)*4 + m4][(nh)*2 + n2] = __builtin_amdgcn_mfma_f32_16x16x32_bf16( \
        aA[m4][k_], bB[(nh)*2 + n2][k_], acc[(mh)*4 + m4][(nh)*2 + n2], 0, 0, 0);
#define STAGE_HALF(buf, mat, half, kt)                                       \
  {                                                                          \
    const short* g_ = ((mat) ? Bb : Ab) + (size_t)((half)*128) * K + (kt)*64;\
    short* l_ = &lds[buf][mat][(half)*8192];                                 \
    _Pragma("unroll") for (int it_ = 0; it_ < 2; ++it_) {                    \
      int ci_ = it_ * 512 + tid;                                             \
      int r_ = ci_ >> 3, sl_ = (ci_ & 7) ^ (r_ & 7);                         \
      __builtin_amdgcn_global_load_lds(GLOBAL_AS(g_ + (size_t)r_ * K + sl_ * 8), \
                                       LDS_AS(l_ + ci_ * 8), 16, 0, 0);      \
    }                                                                        \
  }
#define PH_SYNC1()                                                           \
  __builtin_amdgcn_s_barrier();                                              \
  asm volatile("s_waitcnt lgkmcnt(0)" ::: "memory");                         \
  __builtin_amdgcn_sched_barrier(0);                                         \
  __builtin_amdgcn_s_setprio(1)
#define PH_SYNC2()                                                           \
  __builtin_amdgcn_s_setprio(0);                                             \
  __builtin_amdgcn_s_barrier()
#define PH_SYNC2_VM(n)                                                       \
  __builtin_amdgcn_s_setprio(0);                                             \
  asm volatile("s_waitcnt vmcnt(" #n ")" ::: "memory");                      \
  __builtin_amdgcn_s_barrier()

template <int EPI>
__global__ __launch_bounds__(512, 2) void gemm256_kernel(
    const short* __restrict__ A, const short* __restrict__ BT,
    int N, int K, int kslice, size_t pstride,
    short* __restrict__ outB, const float* __restrict__ bias) {
  __shared__ short lds[2][2][16384];   // [buf][A/B][256 rows x 64 k], 128 KiB
  const int tid = threadIdx.x;
  const int lane = tid & 63, wid = tid >> 6;
  const int lrow = lane & 15, kk = lane >> 4;
  const int wm = wid >> 2, wn = wid & 3;
  const int row0 = blockIdx.y * 256, col0 = blockIdx.x * 256;
  const int kbase = blockIdx.z * kslice;
  const int NT = kslice >> 6;

  const short* Ab = A + (size_t)row0 * K + kbase;
  const short* Bb = BT + (size_t)col0 * K + kbase;

  f32x4 acc[8][4] = {};
  bf16x8 aA[4][2], bB[4][2];

  STAGE_HALF(0, 1, 0, 0); STAGE_HALF(0, 0, 0, 0);
  STAGE_HALF(0, 1, 1, 0); STAGE_HALF(0, 0, 1, 0);
  STAGE_HALF(1, 1, 0, 1); STAGE_HALF(1, 0, 0, 1); STAGE_HALF(1, 0, 1, 1);
  asm volatile("s_waitcnt vmcnt(6)" ::: "memory");
  __builtin_amdgcn_s_barrier();

  const int iters = NT >> 1;
  for (int i = 0; i < iters; ++i) {
    const int t1 = 2 * i + 1;
    int kt2 = 2 * i + 2; if (kt2 >= NT) kt2 -= NT;
    int kt3 = 2 * i + 3; if (kt3 >= NT) kt3 -= NT;
    READ_A(0, 0); READ_B2(0, 0); STAGE_HALF(1, 1, 1, t1);
    PH_SYNC1(); MFMA16(0, 0); PH_SYNC2();
    READ_B2(0, 1);
    PH_SYNC1(); MFMA16(0, 1); PH_SYNC2();
    READ_A(0, 1); STAGE_HALF(0, 1, 0, kt2);
    PH_SYNC1(); MFMA16(1, 0); PH_SYNC2();
    STAGE_HALF(0, 0, 0, kt2);
    PH_SYNC1(); MFMA16(1, 1); PH_SYNC2_VM(4);
    READ_A(1, 0); READ_B2(1, 0); STAGE_HALF(0, 1, 1, kt2);
    PH_SYNC1(); MFMA16(0, 0); PH_SYNC2();
    READ_B2(1, 1); STAGE_HALF(0, 0, 1, kt2);
    PH_SYNC1(); MFMA16(0, 1); PH_SYNC2();
    READ_A(1, 1); STAGE_HALF(1, 1, 0, kt3);
    PH_SYNC1(); MFMA16(1, 0); PH_SYNC2();
    STAGE_HALF(1, 0, 0, kt3); STAGE_HALF(1, 0, 1, kt3);
    PH_SYNC1(); MFMA16(1, 1); PH_SYNC2_VM(6);
  }

  short* ob = outB + (size_t)blockIdx.z * pstride;
#pragma unroll
  for (int m = 0; m < 8; ++m) {
    int row = row0 + wm * 128 + m * 16 + kk * 4;
#pragma unroll
    for (int n = 0; n < 4; ++n) {
      int col = col0 + wn * 64 + n * 16 + lrow;
#pragma unroll
      for (int r = 0; r < 4; ++r) {
        float v = acc[m][n][r];
        size_t o = (size_t)(row + r) * N + col;
        if (EPI == 0) {
          ob[o] = f2bf(v);
        } else {
          v += bias[col];
          ob[o] = f2bf(v > 0.f ? v : 0.f);
        }
      }
    }
  }
}

// out[i] = sum_{s<4} part[s][i] + bias[i % 1024] + addend[i]   (W2 split-K reduce)
__global__ __launch_bounds__(256) void reduce4_kernel(
    const short* __restrict__ part, const float* __restrict__ bias,
    const float* __restrict__ addend, float* __restrict__ out) {
  const size_t MN = (size_t)4096 * 1024;
  size_t i8 = ((size_t)blockIdx.x * 256 + threadIdx.x) * 8;
  bf16x8 p0 = *(const bf16x8*)&part[i8];
  bf16x8 p1 = *(const bf16x8*)&part[MN + i8];
  bf16x8 p2 = *(const bf16x8*)&part[2 * MN + i8];
  bf16x8 p3 = *(const bf16x8*)&part[3 * MN + i8];
  int col = (int)(i8 & 1023);
#pragma unroll
  for (int j = 0; j < 8; ++j) {
    float v = (bf2f(p0[j]) + bf2f(p1[j])) + (bf2f(p2[j]) + bf2f(p3[j]));
    out[i8 + j] = v + bias[col + j] + addend[i8 + j];
  }
}

// ---------------- flash attention v11: swapped QK^T, packed P, split-only combine ----------------
// sc = mfma(K_frag, Q_frag): output row = key (kk*4+r), col = q (lrow). Each
// lane holds 4 CONSECUTIVE keys for one q-row -> P store is 4x ds_write_b64
// (was 16x ds_write_b16); rs is a single per-lane scalar (2-shuffle reduce).
// Non-split blocks (qtile<16) normalize in-kernel and write attn_o directly;
// only split blocks (qtile>=16) write opart/lpart for the combine kernel.
__device__ const unsigned char QT_SLOT[48] = {
    31, 31, 30, 15, 30, 29, 29, 28, 14, 28, 27, 27, 26, 13, 26, 25,
    25, 24, 12, 24, 23, 23, 22, 11, 22, 21, 21, 20, 10, 20, 19, 19,
    18,  9, 18, 17, 17, 16,  8, 16,  7,  6,  5,  4,  3,  2,  1,  0};
__device__ const unsigned char SP_SLOT[48] = {
    0, 1, 0, 0, 1, 0, 1, 0, 0, 1, 0, 1, 0, 0, 1, 0,
    1, 0, 0, 1, 0, 1, 0, 0, 1, 0, 1, 0, 0, 1, 0, 1,
    0, 0, 1, 0, 1, 0, 0, 1, 0, 0, 0, 0, 0, 0, 0, 0};

__global__ __launch_bounds__(512, 4) void attn_kernel(
    const short* __restrict__ QKV, const short* __restrict__ VT,
    float* __restrict__ opart, float* __restrict__ lpart,
    short* __restrict__ O) {
  const int S = 4096;
  __shared__ short Ks[2][128 * 64];
  __shared__ short Vs[2][64 * 128];
  __shared__ short Ps[8][16 * 64];

  const int tid = threadIdx.x;
  const int lane = tid & 63;
  const int w = tid >> 6;                     // 0..7
  const int lrow = lane & 15;
  const int kk = lane >> 4;
  const int bid = blockIdx.x;
  const int h = bid & 15;
  const int slot = bid >> 4;
  const int qtile = QT_SLOT[slot];
  const int sp = SP_SLOT[slot];
  const int T = qtile + 1;                    // total 128-key tiles for this qtile
  const bool split = (qtile >= 16);
  const int half = (T + 1) >> 1;
  const int t0 = (split && sp) ? half : 0;
  const int t1 = (split && !sp) ? half : T;
  const int q0 = qtile * 128;
  const int qw = q0 + w * 16;                 // 16 q-rows per wave
  const int myq = qw + lrow;                  // this lane's q row (swapped layout)

  auto stage = [&](int buf, int t) {
    const int kv0 = t * 128;
#pragma unroll
    for (int it = 0; it < 2; ++it) {
      int ci = it * 512 + tid;                // 16B chunks, 1024 per matrix
      int krow = ci >> 3;                     // 128 K rows x 8 slots
      int ksl = (ci & 7) ^ (krow & 7);
      int vrow = ci >> 4;                     // 64 V rows x 16 slots
      int vsl = (ci & 15) ^ (vrow & 15);
      const short* gk = QKV + (size_t)(kv0 + krow) * 3072 + 1024 + h * 64 + ksl * 8;
      const short* gv = VT + (size_t)(h * 64 + vrow) * S + kv0 + vsl * 8;
      __builtin_amdgcn_global_load_lds(GLOBAL_AS(gk),
                                       LDS_AS(&Ks[buf][(it * 512 + w * 64) * 8]), 16, 0, 0);
      __builtin_amdgcn_global_load_lds(GLOBAL_AS(gv),
                                       LDS_AS(&Vs[buf][(it * 512 + w * 64) * 8]), 16, 0, 0);
    }
  };

  bf16x8 qf[2];
#pragma unroll
  for (int half2 = 0; half2 < 2; ++half2)
    qf[half2] = *(const bf16x8*)&QKV[(size_t)(qw + lrow) * 3072 +
                                     h * 64 + half2 * 32 + kk * 8];

  float rs_acc = 0.f;
  f32x4 o_acc[4] = {};

  stage(0, t0);
  __syncthreads();
  int cur = 0;

  for (int t = t0; t < t1; ++t) {
    if (t + 1 < t1) stage(cur ^ 1, t + 1);    // prefetch next 128-key tile

#pragma unroll
    for (int h2 = 0; h2 < 2; ++h2) {
      const int kvc = t * 128 + h2 * 64;
      if (kvc > qw + 15) continue;            // chunk fully masked for wave

      // ---- QK^T (swapped): sc[c] row=key(kk*4+r), col=q(lrow) ----
      bf16x8 kf[4][2];
#pragma unroll
      for (int c = 0; c < 4; ++c)
#pragma unroll
        for (int half2 = 0; half2 < 2; ++half2) {
          int krow = h2 * 64 + c * 16 + lrow;
          kf[c][half2] = *(const bf16x8*)&Ks[cur][krow * 64 + (((half2 * 4 + kk) ^ (lrow & 7)) * 8)];
        }
      f32x4 sc[4];
      __builtin_amdgcn_s_setprio(1);
#pragma unroll
      for (int c = 0; c < 4; ++c) {
        f32x4 z = {};
        z = __builtin_amdgcn_mfma_f32_16x16x32_bf16(kf[c][0], qf[0], z, 0, 0, 0);
        z = __builtin_amdgcn_mfma_f32_16x16x32_bf16(kf[c][1], qf[1], z, 0, 0, 0);
        sc[c] = z;
      }
      __builtin_amdgcn_s_setprio(0);

      // ---- softmax numerator: lane holds 4 consecutive keys for q=myq ----
      if (kvc + 63 <= qw) {
        // interior: no masking
#pragma unroll
        for (int c = 0; c < 4; ++c) {
          float p0 = __expf(sc[c][0]), p1 = __expf(sc[c][1]);
          float p2 = __expf(sc[c][2]), p3 = __expf(sc[c][3]);
          rs_acc += (p0 + p1) + (p2 + p3);
          s16x4 pk;
          pk[0] = f2bf(p0); pk[1] = f2bf(p1); pk[2] = f2bf(p2); pk[3] = f2bf(p3);
          int slot8 = c * 2 + (kk >> 1);
          *(s16x4*)&Ps[w][lrow * 64 + ((slot8 ^ (lrow & 7)) * 8) + (kk & 1) * 4] = pk;
        }
      } else {
        // boundary: zero keys > myq
#pragma unroll
        for (int c = 0; c < 4; ++c) {
          const int keyb = kvc + c * 16 + kk * 4;
          float pv[4];
#pragma unroll
          for (int r = 0; r < 4; ++r) {
            float p = __expf(sc[c][r]);
            if (keyb + r > myq) p = 0.f;
            pv[r] = p;
          }
          rs_acc += (pv[0] + pv[1]) + (pv[2] + pv[3]);
          s16x4 pk;
          pk[0] = f2bf(pv[0]); pk[1] = f2bf(pv[1]); pk[2] = f2bf(pv[2]); pk[3] = f2bf(pv[3]);
          int slot8 = c * 2 + (kk >> 1);
          *(s16x4*)&Ps[w][lrow * 64 + ((slot8 ^ (lrow & 7)) * 8) + (kk & 1) * 4] = pk;
        }
      }

      // ---- PV over this chunk (8 MFMA) ----
#pragma unroll
      for (int ks = 0; ks < 2; ++ks) {
        bf16x8 pf2, vf[4];
        {
          int qrow = lrow;
          pf2 = *(const bf16x8*)&Ps[w][qrow * 64 + (((ks * 4 + kk) ^ (qrow & 7)) * 8)];
        }
#pragma unroll
        for (int g = 0; g < 4; ++g) {
          int erow = g * 16 + lrow;
          vf[g] = *(const bf16x8*)&Vs[cur][erow * 128 + (((h2 * 8 + ks * 4 + kk) ^ (lrow & 15)) * 8)];
        }
        __builtin_amdgcn_s_setprio(1);
#pragma unroll
        for (int g = 0; g < 4; ++g)
          o_acc[g] = __builtin_amdgcn_mfma_f32_16x16x32_bf16(pf2, vf[g], o_acc[g], 0, 0, 0);
        __builtin_amdgcn_s_setprio(0);
      }
    }

    __syncthreads();                          // drain prefetch + swap
    cur ^= 1;
  }

  // ---- epilogue: 2-shuffle l reduce (lanes with same lrow hold partials) ----
  float l = rs_acc;
  l += __shfl_xor(l, 16);
  l += __shfl_xor(l, 32);

  if (!split) {
    // normalize in-kernel, write attn_o directly
    float inv_[4];
#pragma unroll
    for (int r = 0; r < 4; ++r) inv_[r] = 1.f / __shfl(l, kk * 4 + r);
#pragma unroll
    for (int g = 0; g < 4; ++g)
#pragma unroll
      for (int r = 0; r < 4; ++r) {
        int s_idx = qw + kk * 4 + r;
        O[(size_t)s_idx * 1024 + h * 64 + g * 16 + lrow] =
            f2bf(o_acc[g][r] * inv_[r]);
      }
  } else {
    const int pidx = (h * 32 + qtile) * 2 + sp;
    float* op = opart + (size_t)pidx * 8192;  // [128 q][64 d]
    float* lp = lpart + pidx * 128;
    if (lane < 16) lp[w * 16 + lrow] = l;
#pragma unroll
    for (int g = 0; g < 4; ++g)
#pragma unroll
      for (int r = 0; r < 4; ++r)
        op[(w * 16 + kk * 4 + r) * 64 + g * 16 + lrow] = o_acc[g][r];
  }
}

// combine (split qtiles 16..31 only): attn_o[srow][col] = bf16( (o0+o1) / (l0+l1) )
__global__ __launch_bounds__(256) void attn_combine_kernel(
    const float* __restrict__ opart, const float* __restrict__ lpart,
    short* __restrict__ O) {
  size_t e8 = ((size_t)blockIdx.x * 256 + threadIdx.x) * 8 + (size_t)2048 * 1024;
  const int srow = (int)(e8 >> 10);
  const int col = (int)(e8 & 1023);
  const int h = col >> 6, d = col & 63;
  const int qtile = srow >> 7, qr = srow & 127;
  const int pb = (h * 32 + qtile) * 2;
  const float* o0 = opart + (size_t)pb * 8192 + qr * 64 + d;
  const float* o1 = opart + (size_t)(pb + 1) * 8192 + qr * 64 + d;
  float l = lpart[pb * 128 + qr] + lpart[(pb + 1) * 128 + qr];
  float4 a0 = *(const float4*)o0;
  float4 a1 = *(const float4*)(o0 + 4);
  float4 b0 = *(const float4*)o1;
  float4 b1 = *(const float4*)(o1 + 4);
  a0.x += b0.x; a0.y += b0.y; a0.z += b0.z; a0.w += b0.w;
  a1.x += b1.x; a1.y += b1.y; a1.z += b1.z; a1.w += b1.w;
  float inv = 1.f / l;
  bf16x8 o;
  o[0] = f2bf(a0.x * inv); o[1] = f2bf(a0.y * inv);
  o[2] = f2bf(a0.z * inv); o[3] = f2bf(a0.w * inv);
  o[4] = f2bf(a1.x * inv); o[5] = f2bf(a1.y * inv);
  o[6] = f2bf(a1.z * inv); o[7] = f2bf(a1.w * inv);
  *(bf16x8*)&O[e8] = o;
}

// ---------------- launch ----------------
extern "C" void kernel_launch(void* const* d_in, const int* in_sizes, int n_in,
                              void* d_out, int out_size, void* d_ws, size_t ws_size,
                              hipStream_t stream) {
  const float* x  = (const float*)d_in[0];
  const float* g1 = (const float*)d_in[2];
  const float* WQ = (const float*)d_in[3];
  const float* WK = (const float*)d_in[4];
  const float* WV = (const float*)d_in[5];
  const float* WO = (const float*)d_in[6];
  const float* g2 = (const float*)d_in[7];
  const float* W1 = (const float*)d_in[8];
  const float* B1 = (const float*)d_in[9];
  const float* W2 = (const float*)d_in[10];
  const float* B2 = (const float*)d_in[11];
  float* out = (float*)d_out;

  const int S = 4096, D = 1024, H = 16;

  char* ws = (char*)d_ws;
  size_t off = 0;
  auto alloc = [&](size_t bytes) -> void* {
    void* p = ws + off;
    off += (bytes + 255) & ~(size_t)255;
    return p;
  };
  short* h1     = (short*)alloc((size_t)S * D * 2);
  short* wqkv_t = (short*)alloc((size_t)3072 * 1024 * 2);
  short* qkv    = (short*)alloc((size_t)S * 3072 * 2);   // fused QKV output
  short* vt     = (short*)alloc((size_t)1024 * S * 2);
  short* attn_o = (short*)alloc((size_t)S * D * 2);
  short* wo_t   = (short*)alloc((size_t)1024 * 1024 * 2);
  float* x2     = (float*)alloc((size_t)S * D * 4);
  short* h2     = (short*)alloc((size_t)S * D * 2);
  short* w1_t   = (short*)alloc((size_t)4096 * 1024 * 2);
  short* m1     = (short*)alloc((size_t)S * 4096 * 2);
  short* w2_t   = (short*)alloc((size_t)1024 * 4096 * 2);
  short* partW2 = qkv;         // W2 split-K partials (33.55MB) alias qkv(25.2)+vt(8.4) (dead by then)
  float* opart  = (float*)m1;  // attn o-partials (split qtiles only): aliases m1 (dead until W1)
  float* lpart  = (float*)h1;  // attn l-partials: 512KB (h1 dead after QKV gemm)

  // weight prep
  pack_qkv_kernel<<<dim3(D / 64, 48), 256, 0, stream>>>(WQ, WK, WV, wqkv_t);
  transpose_bf16_kernel<<<dim3(1024 / 64, 1024 / 64), 256, 0, stream>>>(WO, wo_t, 1024, 1024);
  transpose_bf16_kernel<<<dim3(4096 / 64, 1024 / 64), 256, 0, stream>>>(W1, w1_t, 1024, 4096);
  transpose_bf16_kernel<<<dim3(1024 / 64, 4096 / 64), 256, 0, stream>>>(W2, w2_t, 4096, 1024);

  // attention sub-block
  rmsnorm_kernel<<<S, 256, 0, stream>>>(x, g1, h1, D);
  // fused QKV projection: one 256^2 8-phase GEMM, [S][3072]
  gemm256_kernel<0><<<dim3(3072 / 256, S / 256, 1), 512, 0, stream>>>(
      h1, wqkv_t, 3072, 1024, 1024, 0, qkv, nullptr);
  // V^T from qkv V-columns
  transpose_v_kernel<<<dim3(S / 64, 1024 / 64), 256, 0, stream>>>(qkv, vt, S);
  attn_kernel<<<dim3(768), 512, 0, stream>>>(qkv, vt, opart, lpart, attn_o);
  attn_combine_kernel<<<dim3((2048 * 1024 / 8) / 256), 256, 0, stream>>>(opart, lpart, attn_o);
  gemm_bt_kernel<1><<<dim3(1024 / 128, S / 128), 256, 0, stream>>>(
      attn_o, wo_t, S, 1024, 1024, nullptr, x2, nullptr, x);

  // MLP sub-block
  rmsnorm_kernel<<<S, 256, 0, stream>>>(x2, g2, h2, D);
  gemm256_kernel<2><<<dim3(4096 / 256, 4096 / 256, 1), 512, 0, stream>>>(
      h2, w1_t, 4096, 1024, 1024, 0, m1, B1);
  gemm256_kernel<0><<<dim3(1024 / 256, 4096 / 256, 4), 512, 0, stream>>>(
      m1, w2_t, 1024, 4096, 1024, (size_t)4096 * 1024, partW2, nullptr);
  reduce4_kernel<<<2048, 256, 0, stream>>>(partW2, B2, x2, out);
}

// Round 13
// 239.028 us; speedup vs baseline: 1.1837x; 1.0220x over previous
//
#include <hip/hip_runtime.h>
#include <hip/hip_bf16.h>

typedef __attribute__((ext_vector_type(8))) short bf16x8;
typedef __attribute__((ext_vector_type(4))) float f32x4;
typedef __attribute__((ext_vector_type(4))) short s16x4;

#define GLOBAL_AS(p) ((const __attribute__((address_space(1))) void*)(p))
#define LDS_AS(p)    ((__attribute__((address_space(3))) void*)(p))

__device__ __forceinline__ short f2bf(float f) {
  return __builtin_bit_cast(short, __float2bfloat16(f));   // HW RNE cvt
}
__device__ __forceinline__ float bf2f(short s) {
  return __bfloat162float(__builtin_bit_cast(__hip_bfloat16, s));
}

// ---------------- merged weight prep (one dispatch) ----------------
// bid 0..767: pack WQ/WK/WV -> wqkv_t [3072][1024] (Q rows pre-scaled 0.125)
// bid 768..1023: WO^T; 1024..2047: W1^T; 2048..3071: W2^T (fp32 -> bf16)
__global__ __launch_bounds__(256) void prep_kernel(
    const float* __restrict__ WQ, const float* __restrict__ WK,
    const float* __restrict__ WV, short* __restrict__ wqkv_t,
    const float* __restrict__ WO, short* __restrict__ wo_t,
    const float* __restrict__ W1, short* __restrict__ w1_t,
    const float* __restrict__ W2, short* __restrict__ w2_t) {
  __shared__ short Ls[64][66];
  const int tid = threadIdx.x;
  const int l = tid & 63, q4 = tid >> 6;
  const int bid = blockIdx.x;

  if (bid < 768) {
    const int x = bid & 15, y = bid >> 4;     // x: d-block, y: hh|proj
    const int hh = y & 15, proj = y >> 4;
    const float* W = (proj == 0) ? WQ : ((proj == 1) ? WK : WV);
    const float scl = (proj == 0) ? 0.125f : 1.f;
    const int d0 = x * 64;
#pragma unroll
    for (int rep = 0; rep < 16; ++rep) {
      int dd = q4 * 16 + rep;
      Ls[dd][l] = f2bf(W[(size_t)hh * 65536 + (size_t)(d0 + dd) * 64 + l] * scl);
    }
    __syncthreads();
#pragma unroll
    for (int rep = 0; rep < 16; ++rep) {
      int ee = q4 * 16 + rep;
      wqkv_t[(size_t)(proj * 1024 + hh * 64 + ee) * 1024 + d0 + l] = Ls[l][ee];
    }
  } else {
    const float* in; short* out; int R, C, bx, by;
    if (bid < 1024) {
      int idx = bid - 768;  in = WO; out = wo_t; R = 1024; C = 1024;
      bx = idx & 15; by = idx >> 4;
    } else if (bid < 2048) {
      int idx = bid - 1024; in = W1; out = w1_t; R = 1024; C = 4096;
      bx = idx & 63; by = idx >> 6;
    } else {
      int idx = bid - 2048; in = W2; out = w2_t; R = 4096; C = 1024;
      bx = idx & 15; by = idx >> 4;
    }
    const int c0 = bx * 64, r0 = by * 64;
#pragma unroll
    for (int rep = 0; rep < 16; ++rep) {
      int rr = q4 * 16 + rep;
      Ls[rr][l] = f2bf(in[(size_t)(r0 + rr) * C + c0 + l]);
    }
    __syncthreads();
#pragma unroll
    for (int rep = 0; rep < 16; ++rep) {
      int cc = q4 * 16 + rep;
      out[(size_t)(c0 + cc) * R + r0 + l] = Ls[l][cc];
    }
  }
}

// V columns of qkv [S][3072] (cols 2048..3071) -> vt [1024][S], bf16->bf16
__global__ __launch_bounds__(256) void transpose_v_kernel(
    const short* __restrict__ qkv, short* __restrict__ vt, int S) {
  __shared__ short Ls[64][66];
  const int tid = threadIdx.x;
  const int l = tid & 63, q4 = tid >> 6;
  const int s0 = blockIdx.x * 64, e0 = blockIdx.y * 64;
#pragma unroll
  for (int rep = 0; rep < 16; ++rep) {
    int rr = q4 * 16 + rep;
    Ls[rr][l] = qkv[(size_t)(s0 + rr) * 3072 + 2048 + e0 + l];
  }
  __syncthreads();
#pragma unroll
  for (int rep = 0; rep < 16; ++rep) {
    int ee = q4 * 16 + rep;
    vt[(size_t)(e0 + ee) * S + s0 + l] = Ls[l][ee];
  }
}

// ---------------- RMSNorm (fp32 in -> bf16 out) ----------------
__global__ __launch_bounds__(256) void rmsnorm_kernel(
    const float* __restrict__ x, const float* __restrict__ g,
    short* __restrict__ out, int D) {
  const int row = blockIdx.x;
  const int tid = threadIdx.x;
  const float4 xv = *(const float4*)&x[(size_t)row * D + tid * 4];
  float ss = xv.x * xv.x + xv.y * xv.y + xv.z * xv.z + xv.w * xv.w;
#pragma unroll
  for (int off = 32; off; off >>= 1) ss += __shfl_xor(ss, off);
  __shared__ float red[4];
  if ((tid & 63) == 0) red[tid >> 6] = ss;
  __syncthreads();
  float tot = red[0] + red[1] + red[2] + red[3];
  float scale = rsqrtf(tot / (float)D + 1e-6f);
  const float4 gv = *(const float4*)&g[tid * 4];
  s16x4 o;
  o[0] = f2bf(xv.x * scale * gv.x);
  o[1] = f2bf(xv.y * scale * gv.y);
  o[2] = f2bf(xv.z * scale * gv.z);
  o[3] = f2bf(xv.w * scale * gv.w);
  *(s16x4*)&out[(size_t)row * D + tid * 4] = o;
}

// ---------------- 128x64 GEMM (WO): C = A[M,K] x BT[N,K]^T, fp32 out + addend ----------------
// BN=64 so grid = (N/64)x(M/128) = 512 blocks -> 2 blocks/CU (the 128x128
// version capped at 1 block/CU = 1 wave/SIMD and ran latency-bound at 460 TF).
__global__ __launch_bounds__(256) void gemm_bt64_kernel(
    const short* __restrict__ A, const short* __restrict__ BT,
    int M, int N, int K,
    float* __restrict__ outF, const float* __restrict__ addend) {
  __shared__ short As[128 * 32];
  __shared__ short Bs[64 * 32];
  const int tid = threadIdx.x;
  const int lane = tid & 63;
  const int wid = tid >> 6;
  const int lrow = lane & 15;
  const int kk = lane >> 4;
  const int row0 = blockIdx.y * 128;
  const int col0 = blockIdx.x * 64;
  const int wm = wid >> 1, wn = wid & 1;

  f32x4 acc[4][2] = {};

  for (int k0 = 0; k0 < K; k0 += 32) {
    __syncthreads();
#pragma unroll
    for (int it = 0; it < 2; ++it) {
      int c = it * 256 + tid;
      int r = c >> 2, c8 = (c & 3) * 8;
      const short* ga = A + (size_t)(row0 + r) * K + k0 + c8;
      short* la = &As[(size_t)(it * 256 + wid * 64) * 8];
      __builtin_amdgcn_global_load_lds(GLOBAL_AS(ga), LDS_AS(la), 16, 0, 0);
    }
    {
      int r = tid >> 2, c8 = (tid & 3) * 8;
      const short* gb = BT + (size_t)(col0 + r) * K + k0 + c8;
      short* lb = &Bs[(size_t)(wid * 64) * 8];
      __builtin_amdgcn_global_load_lds(GLOBAL_AS(gb), LDS_AS(lb), 16, 0, 0);
    }
    __syncthreads();

    bf16x8 a[4], b[2];
#pragma unroll
    for (int i = 0; i < 4; ++i)
      a[i] = *(const bf16x8*)&As[(wm * 64 + i * 16 + lrow) * 32 + kk * 8];
#pragma unroll
    for (int j = 0; j < 2; ++j)
      b[j] = *(const bf16x8*)&Bs[(wn * 32 + j * 16 + lrow) * 32 + kk * 8];
#pragma unroll
    for (int i = 0; i < 4; ++i)
#pragma unroll
      for (int j = 0; j < 2; ++j)
        acc[i][j] = __builtin_amdgcn_mfma_f32_16x16x32_bf16(a[i], b[j], acc[i][j], 0, 0, 0);
  }

#pragma unroll
  for (int i = 0; i < 4; ++i) {
    int row = row0 + wm * 64 + i * 16 + kk * 4;
#pragma unroll
    for (int j = 0; j < 2; ++j) {
      int col = col0 + wn * 32 + j * 16 + lrow;
#pragma unroll
      for (int r = 0; r < 4; ++r) {
        size_t o = (size_t)(row + r) * N + col;
        outF[o] = acc[i][j][r] + addend[o];
      }
    }
  }
}

// ---------------- 256x256 8-phase GEMM (T2+T3+T4+T5), bf16 out ----------------
#define READ_A(buf, mh)                                                      \
  _Pragma("unroll") for (int m4 = 0; m4 < 4; ++m4) {                         \
    int row_ = wm * 128 + ((mh)*4 + m4) * 16 + lrow;                         \
    _Pragma("unroll") for (int k_ = 0; k_ < 2; ++k_) {                       \
      int sl_ = (k_ * 4 + kk) ^ (row_ & 7);                                  \
      aA[m4][k_] = *(const bf16x8*)&lds[buf][0][row_ * 64 + sl_ * 8];        \
    }                                                                        \
  }
#define READ_B2(buf, pr)                                                     \
  _Pragma("unroll") for (int nn = 0; nn < 2; ++nn) {                         \
    int n_ = (pr)*2 + nn;                                                    \
    int row_ = wn * 64 + n_ * 16 + lrow;                                     \
    _Pragma("unroll") for (int k_ = 0; k_ < 2; ++k_) {                       \
      int sl_ = (k_ * 4 + kk) ^ (row_ & 7);                                  \
      bB[n_][k_] = *(const bf16x8*)&lds[buf][1][row_ * 64 + sl_ * 8];        \
    }                                                                        \
  }
#define MFMA16(mh, nh)                                                       \
  _Pragma("unroll") for (int m4 = 0; m4 < 4; ++m4)                           \
  _Pragma("unroll") for (int n2 = 0; n2 < 2; ++n2)                           \
  _Pragma("unroll") for (int k_ = 0; k_ < 2; ++k_)                           \
    acc[(mh)*4 + m4][(nh)*2 + n2] = __builtin_amdgcn_mfma_f32_16x16x32_bf16( \
        aA[m4][k_], bB[(nh)*2 + n2][k_], acc[(mh)*4 + m4][(nh)*2 + n2], 0, 0, 0);
#define STAGE_HALF(buf, mat, half, kt)                                       \
  {                                                                          \
    const short* g_ = ((mat) ? Bb : Ab) + (size_t)((half)*128) * K + (kt)*64;\
    short* l_ = &lds[buf][mat][(half)*8192];                                 \
    _Pragma("unroll") for (int it_ = 0; it_ < 2; ++it_) {                    \
      int ci_ = it_ * 512 + tid;                                             \
      int r_ = ci_ >> 3, sl_ = (ci_ & 7) ^ (r_ & 7);                         \
      __builtin_amdgcn_global_load_lds(GLOBAL_AS(g_ + (size_t)r_ * K + sl_ * 8), \
                                       LDS_AS(l_ + ci_ * 8), 16, 0, 0);      \
    }                                                                        \
  }
#define PH_SYNC1()                                                           \
  __builtin_amdgcn_s_barrier();                                              \
  asm volatile("s_waitcnt lgkmcnt(0)" ::: "memory");                         \
  __builtin_amdgcn_sched_barrier(0);                                         \
  __builtin_amdgcn_s_setprio(1)
#define PH_SYNC2()                                                           \
  __builtin_amdgcn_s_setprio(0);                                             \
  __builtin_amdgcn_s_barrier()
#define PH_SYNC2_VM(n)                                                       \
  __builtin_amdgcn_s_setprio(0);                                             \
  asm volatile("s_waitcnt vmcnt(" #n ")" ::: "memory");                      \
  __builtin_amdgcn_s_barrier()

template <int EPI>
__global__ __launch_bounds__(512, 2) void gemm256_kernel(
    const short* __restrict__ A, const short* __restrict__ BT,
    int N, int K, int kslice, size_t pstride,
    short* __restrict__ outB, const float* __restrict__ bias) {
  __shared__ short lds[2][2][16384];   // [buf][A/B][256 rows x 64 k], 128 KiB
  const int tid = threadIdx.x;
  const int lane = tid & 63, wid = tid >> 6;
  const int lrow = lane & 15, kk = lane >> 4;
  const int wm = wid >> 2, wn = wid & 3;
  const int row0 = blockIdx.y * 256, col0 = blockIdx.x * 256;
  const int kbase = blockIdx.z * kslice;
  const int NT = kslice >> 6;

  const short* Ab = A + (size_t)row0 * K + kbase;
  const short* Bb = BT + (size_t)col0 * K + kbase;

  f32x4 acc[8][4] = {};
  bf16x8 aA[4][2], bB[4][2];

  STAGE_HALF(0, 1, 0, 0); STAGE_HALF(0, 0, 0, 0);
  STAGE_HALF(0, 1, 1, 0); STAGE_HALF(0, 0, 1, 0);
  STAGE_HALF(1, 1, 0, 1); STAGE_HALF(1, 0, 0, 1); STAGE_HALF(1, 0, 1, 1);
  asm volatile("s_waitcnt vmcnt(6)" ::: "memory");
  __builtin_amdgcn_s_barrier();

  const int iters = NT >> 1;
  for (int i = 0; i < iters; ++i) {
    const int t1 = 2 * i + 1;
    int kt2 = 2 * i + 2; if (kt2 >= NT) kt2 -= NT;
    int kt3 = 2 * i + 3; if (kt3 >= NT) kt3 -= NT;
    READ_A(0, 0); READ_B2(0, 0); STAGE_HALF(1, 1, 1, t1);
    PH_SYNC1(); MFMA16(0, 0); PH_SYNC2();
    READ_B2(0, 1);
    PH_SYNC1(); MFMA16(0, 1); PH_SYNC2();
    READ_A(0, 1); STAGE_HALF(0, 1, 0, kt2);
    PH_SYNC1(); MFMA16(1, 0); PH_SYNC2();
    STAGE_HALF(0, 0, 0, kt2);
    PH_SYNC1(); MFMA16(1, 1); PH_SYNC2_VM(4);
    READ_A(1, 0); READ_B2(1, 0); STAGE_HALF(0, 1, 1, kt2);
    PH_SYNC1(); MFMA16(0, 0); PH_SYNC2();
    READ_B2(1, 1); STAGE_HALF(0, 0, 1, kt2);
    PH_SYNC1(); MFMA16(0, 1); PH_SYNC2();
    READ_A(1, 1); STAGE_HALF(1, 1, 0, kt3);
    PH_SYNC1(); MFMA16(1, 0); PH_SYNC2();
    STAGE_HALF(1, 0, 0, kt3); STAGE_HALF(1, 0, 1, kt3);
    PH_SYNC1(); MFMA16(1, 1); PH_SYNC2_VM(6);
  }

  short* ob = outB + (size_t)blockIdx.z * pstride;
#pragma unroll
  for (int m = 0; m < 8; ++m) {
    int row = row0 + wm * 128 + m * 16 + kk * 4;
#pragma unroll
    for (int n = 0; n < 4; ++n) {
      int col = col0 + wn * 64 + n * 16 + lrow;
#pragma unroll
      for (int r = 0; r < 4; ++r) {
        float v = acc[m][n][r];
        size_t o = (size_t)(row + r) * N + col;
        if (EPI == 0) {
          ob[o] = f2bf(v);
        } else {
          v += bias[col];
          ob[o] = f2bf(v > 0.f ? v : 0.f);
        }
      }
    }
  }
}

// out[i] = sum_{s<4} part[s][i] + bias[i % 1024] + addend[i]   (W2 split-K reduce)
__global__ __launch_bounds__(256) void reduce4_kernel(
    const short* __restrict__ part, const float* __restrict__ bias,
    const float* __restrict__ addend, float* __restrict__ out) {
  const size_t MN = (size_t)4096 * 1024;
  size_t i8 = ((size_t)blockIdx.x * 256 + threadIdx.x) * 8;
  bf16x8 p0 = *(const bf16x8*)&part[i8];
  bf16x8 p1 = *(const bf16x8*)&part[MN + i8];
  bf16x8 p2 = *(const bf16x8*)&part[2 * MN + i8];
  bf16x8 p3 = *(const bf16x8*)&part[3 * MN + i8];
  int col = (int)(i8 & 1023);
#pragma unroll
  for (int j = 0; j < 8; ++j) {
    float v = (bf2f(p0[j]) + bf2f(p1[j])) + (bf2f(p2[j]) + bf2f(p3[j]));
    out[i8 + j] = v + bias[col + j] + addend[i8 + j];
  }
}

// ---------------- flash attention v11: swapped QK^T, packed P, split-only combine ----------------
__device__ const unsigned char QT_SLOT[48] = {
    31, 31, 30, 15, 30, 29, 29, 28, 14, 28, 27, 27, 26, 13, 26, 25,
    25, 24, 12, 24, 23, 23, 22, 11, 22, 21, 21, 20, 10, 20, 19, 19,
    18,  9, 18, 17, 17, 16,  8, 16,  7,  6,  5,  4,  3,  2,  1,  0};
__device__ const unsigned char SP_SLOT[48] = {
    0, 1, 0, 0, 1, 0, 1, 0, 0, 1, 0, 1, 0, 0, 1, 0,
    1, 0, 0, 1, 0, 1, 0, 0, 1, 0, 1, 0, 0, 1, 0, 1,
    0, 0, 1, 0, 1, 0, 0, 1, 0, 0, 0, 0, 0, 0, 0, 0};

__global__ __launch_bounds__(512, 4) void attn_kernel(
    const short* __restrict__ QKV, const short* __restrict__ VT,
    float* __restrict__ opart, float* __restrict__ lpart,
    short* __restrict__ O) {
  const int S = 4096;
  __shared__ short Ks[2][128 * 64];
  __shared__ short Vs[2][64 * 128];
  __shared__ short Ps[8][16 * 64];

  const int tid = threadIdx.x;
  const int lane = tid & 63;
  const int w = tid >> 6;                     // 0..7
  const int lrow = lane & 15;
  const int kk = lane >> 4;
  const int bid = blockIdx.x;
  const int h = bid & 15;
  const int slot = bid >> 4;
  const int qtile = QT_SLOT[slot];
  const int sp = SP_SLOT[slot];
  const int T = qtile + 1;                    // total 128-key tiles for this qtile
  const bool split = (qtile >= 16);
  const int half = (T + 1) >> 1;
  const int t0 = (split && sp) ? half : 0;
  const int t1 = (split && !sp) ? half : T;
  const int q0 = qtile * 128;
  const int qw = q0 + w * 16;                 // 16 q-rows per wave
  const int myq = qw + lrow;                  // this lane's q row (swapped layout)

  auto stage = [&](int buf, int t) {
    const int kv0 = t * 128;
#pragma unroll
    for (int it = 0; it < 2; ++it) {
      int ci = it * 512 + tid;                // 16B chunks, 1024 per matrix
      int krow = ci >> 3;                     // 128 K rows x 8 slots
      int ksl = (ci & 7) ^ (krow & 7);
      int vrow = ci >> 4;                     // 64 V rows x 16 slots
      int vsl = (ci & 15) ^ (vrow & 15);
      const short* gk = QKV + (size_t)(kv0 + krow) * 3072 + 1024 + h * 64 + ksl * 8;
      const short* gv = VT + (size_t)(h * 64 + vrow) * S + kv0 + vsl * 8;
      __builtin_amdgcn_global_load_lds(GLOBAL_AS(gk),
                                       LDS_AS(&Ks[buf][(it * 512 + w * 64) * 8]), 16, 0, 0);
      __builtin_amdgcn_global_load_lds(GLOBAL_AS(gv),
                                       LDS_AS(&Vs[buf][(it * 512 + w * 64) * 8]), 16, 0, 0);
    }
  };

  bf16x8 qf[2];
#pragma unroll
  for (int half2 = 0; half2 < 2; ++half2)
    qf[half2] = *(const bf16x8*)&QKV[(size_t)(qw + lrow) * 3072 +
                                     h * 64 + half2 * 32 + kk * 8];

  float rs_acc = 0.f;
  f32x4 o_acc[4] = {};

  stage(0, t0);
  __syncthreads();
  int cur = 0;

  for (int t = t0; t < t1; ++t) {
    if (t + 1 < t1) stage(cur ^ 1, t + 1);    // prefetch next 128-key tile

#pragma unroll
    for (int h2 = 0; h2 < 2; ++h2) {
      const int kvc = t * 128 + h2 * 64;
      if (kvc > qw + 15) continue;            // chunk fully masked for wave

      // ---- QK^T (swapped): sc[c] row=key(kk*4+r), col=q(lrow) ----
      bf16x8 kf[4][2];
#pragma unroll
      for (int c = 0; c < 4; ++c)
#pragma unroll
        for (int half2 = 0; half2 < 2; ++half2) {
          int krow = h2 * 64 + c * 16 + lrow;
          kf[c][half2] = *(const bf16x8*)&Ks[cur][krow * 64 + (((half2 * 4 + kk) ^ (lrow & 7)) * 8)];
        }
      f32x4 sc[4];
      __builtin_amdgcn_s_setprio(1);
#pragma unroll
      for (int c = 0; c < 4; ++c) {
        f32x4 z = {};
        z = __builtin_amdgcn_mfma_f32_16x16x32_bf16(kf[c][0], qf[0], z, 0, 0, 0);
        z = __builtin_amdgcn_mfma_f32_16x16x32_bf16(kf[c][1], qf[1], z, 0, 0, 0);
        sc[c] = z;
      }
      __builtin_amdgcn_s_setprio(0);

      // ---- softmax numerator: lane holds 4 consecutive keys for q=myq ----
      if (kvc + 63 <= qw) {
#pragma unroll
        for (int c = 0; c < 4; ++c) {
          float p0 = __expf(sc[c][0]), p1 = __expf(sc[c][1]);
          float p2 = __expf(sc[c][2]), p3 = __expf(sc[c][3]);
          rs_acc += (p0 + p1) + (p2 + p3);
          s16x4 pk;
          pk[0] = f2bf(p0); pk[1] = f2bf(p1); pk[2] = f2bf(p2); pk[3] = f2bf(p3);
          int slot8 = c * 2 + (kk >> 1);
          *(s16x4*)&Ps[w][lrow * 64 + ((slot8 ^ (lrow & 7)) * 8) + (kk & 1) * 4] = pk;
        }
      } else {
#pragma unroll
        for (int c = 0; c < 4; ++c) {
          const int keyb = kvc + c * 16 + kk * 4;
          float pv[4];
#pragma unroll
          for (int r = 0; r < 4; ++r) {
            float p = __expf(sc[c][r]);
            if (keyb + r > myq) p = 0.f;
            pv[r] = p;
          }
          rs_acc += (pv[0] + pv[1]) + (pv[2] + pv[3]);
          s16x4 pk;
          pk[0] = f2bf(pv[0]); pk[1] = f2bf(pv[1]); pk[2] = f2bf(pv[2]); pk[3] = f2bf(pv[3]);
          int slot8 = c * 2 + (kk >> 1);
          *(s16x4*)&Ps[w][lrow * 64 + ((slot8 ^ (lrow & 7)) * 8) + (kk & 1) * 4] = pk;
        }
      }

      // ---- PV over this chunk (8 MFMA) ----
#pragma unroll
      for (int ks = 0; ks < 2; ++ks) {
        bf16x8 pf2, vf[4];
        {
          int qrow = lrow;
          pf2 = *(const bf16x8*)&Ps[w][qrow * 64 + (((ks * 4 + kk) ^ (qrow & 7)) * 8)];
        }
#pragma unroll
        for (int g = 0; g < 4; ++g) {
          int erow = g * 16 + lrow;
          vf[g] = *(const bf16x8*)&Vs[cur][erow * 128 + (((h2 * 8 + ks * 4 + kk) ^ (lrow & 15)) * 8)];
        }
        __builtin_amdgcn_s_setprio(1);
#pragma unroll
        for (int g = 0; g < 4; ++g)
          o_acc[g] = __builtin_amdgcn_mfma_f32_16x16x32_bf16(pf2, vf[g], o_acc[g], 0, 0, 0);
        __builtin_amdgcn_s_setprio(0);
      }
    }

    __syncthreads();                          // drain prefetch + swap
    cur ^= 1;
  }

  // ---- epilogue: 2-shuffle l reduce (lanes with same lrow hold partials) ----
  float l = rs_acc;
  l += __shfl_xor(l, 16);
  l += __shfl_xor(l, 32);

  if (!split) {
    float inv_[4];
#pragma unroll
    for (int r = 0; r < 4; ++r) inv_[r] = 1.f / __shfl(l, kk * 4 + r);
#pragma unroll
    for (int g = 0; g < 4; ++g)
#pragma unroll
      for (int r = 0; r < 4; ++r) {
        int s_idx = qw + kk * 4 + r;
        O[(size_t)s_idx * 1024 + h * 64 + g * 16 + lrow] =
            f2bf(o_acc[g][r] * inv_[r]);
      }
  } else {
    const int pidx = (h * 32 + qtile) * 2 + sp;
    float* op = opart + (size_t)pidx * 8192;  // [128 q][64 d]
    float* lp = lpart + pidx * 128;
    if (lane < 16) lp[w * 16 + lrow] = l;
#pragma unroll
    for (int g = 0; g < 4; ++g)
#pragma unroll
      for (int r = 0; r < 4; ++r)
        op[(w * 16 + kk * 4 + r) * 64 + g * 16 + lrow] = o_acc[g][r];
  }
}

// combine (split qtiles 16..31 only): attn_o[srow][col] = bf16( (o0+o1) / (l0+l1) )
__global__ __launch_bounds__(256) void attn_combine_kernel(
    const float* __restrict__ opart, const float* __restrict__ lpart,
    short* __restrict__ O) {
  size_t e8 = ((size_t)blockIdx.x * 256 + threadIdx.x) * 8 + (size_t)2048 * 1024;
  const int srow = (int)(e8 >> 10);
  const int col = (int)(e8 & 1023);
  const int h = col >> 6, d = col & 63;
  const int qtile = srow >> 7, qr = srow & 127;
  const int pb = (h * 32 + qtile) * 2;
  const float* o0 = opart + (size_t)pb * 8192 + qr * 64 + d;
  const float* o1 = opart + (size_t)(pb + 1) * 8192 + qr * 64 + d;
  float l = lpart[pb * 128 + qr] + lpart[(pb + 1) * 128 + qr];
  float4 a0 = *(const float4*)o0;
  float4 a1 = *(const float4*)(o0 + 4);
  float4 b0 = *(const float4*)o1;
  float4 b1 = *(const float4*)(o1 + 4);
  a0.x += b0.x; a0.y += b0.y; a0.z += b0.z; a0.w += b0.w;
  a1.x += b1.x; a1.y += b1.y; a1.z += b1.z; a1.w += b1.w;
  float inv = 1.f / l;
  bf16x8 o;
  o[0] = f2bf(a0.x * inv); o[1] = f2bf(a0.y * inv);
  o[2] = f2bf(a0.z * inv); o[3] = f2bf(a0.w * inv);
  o[4] = f2bf(a1.x * inv); o[5] = f2bf(a1.y * inv);
  o[6] = f2bf(a1.z * inv); o[7] = f2bf(a1.w * inv);
  *(bf16x8*)&O[e8] = o;
}

// ---------------- launch ----------------
extern "C" void kernel_launch(void* const* d_in, const int* in_sizes, int n_in,
                              void* d_out, int out_size, void* d_ws, size_t ws_size,
                              hipStream_t stream) {
  const float* x  = (const float*)d_in[0];
  const float* g1 = (const float*)d_in[2];
  const float* WQ = (const float*)d_in[3];
  const float* WK = (const float*)d_in[4];
  const float* WV = (const float*)d_in[5];
  const float* WO = (const float*)d_in[6];
  const float* g2 = (const float*)d_in[7];
  const float* W1 = (const float*)d_in[8];
  const float* B1 = (const float*)d_in[9];
  const float* W2 = (const float*)d_in[10];
  const float* B2 = (const float*)d_in[11];
  float* out = (float*)d_out;

  const int S = 4096, D = 1024, H = 16;

  char* ws = (char*)d_ws;
  size_t off = 0;
  auto alloc = [&](size_t bytes) -> void* {
    void* p = ws + off;
    off += (bytes + 255) & ~(size_t)255;
    return p;
  };
  short* h1     = (short*)alloc((size_t)S * D * 2);
  short* wqkv_t = (short*)alloc((size_t)3072 * 1024 * 2);
  short* qkv    = (short*)alloc((size_t)S * 3072 * 2);   // fused QKV output
  short* vt     = (short*)alloc((size_t)1024 * S * 2);
  short* attn_o = (short*)alloc((size_t)S * D * 2);
  short* wo_t   = (short*)alloc((size_t)1024 * 1024 * 2);
  float* x2     = (float*)alloc((size_t)S * D * 4);
  short* h2     = (short*)alloc((size_t)S * D * 2);
  short* w1_t   = (short*)alloc((size_t)4096 * 1024 * 2);
  short* m1     = (short*)alloc((size_t)S * 4096 * 2);
  short* w2_t   = (short*)alloc((size_t)1024 * 4096 * 2);
  short* partW2 = qkv;         // W2 split-K partials (33.55MB) alias qkv(25.2)+vt(8.4) (dead by then)
  float* opart  = (float*)m1;  // attn o-partials (split qtiles only): aliases m1 (dead until W1)
  float* lpart  = (float*)h1;  // attn l-partials: 512KB (h1 dead after QKV gemm)

  // merged weight prep (pack QKV + 3 transposes), one dispatch
  prep_kernel<<<dim3(3072), 256, 0, stream>>>(WQ, WK, WV, wqkv_t,
                                              WO, wo_t, W1, w1_t, W2, w2_t);

  // attention sub-block
  rmsnorm_kernel<<<S, 256, 0, stream>>>(x, g1, h1, D);
  gemm256_kernel<0><<<dim3(3072 / 256, S / 256, 1), 512, 0, stream>>>(
      h1, wqkv_t, 3072, 1024, 1024, 0, qkv, nullptr);
  transpose_v_kernel<<<dim3(S / 64, 1024 / 64), 256, 0, stream>>>(qkv, vt, S);
  attn_kernel<<<dim3(768), 512, 0, stream>>>(qkv, vt, opart, lpart, attn_o);
  attn_combine_kernel<<<dim3((2048 * 1024 / 8) / 256), 256, 0, stream>>>(opart, lpart, attn_o);
  // WO: 128x64 tiles -> 512 blocks, 2 blocks/CU (vs 256 blocks at 1/CU)
  gemm_bt64_kernel<<<dim3(1024 / 64, S / 128), 256, 0, stream>>>(
      attn_o, wo_t, S, 1024, 1024, x2, x);

  // MLP sub-block
  rmsnorm_kernel<<<S, 256, 0, stream>>>(x2, g2, h2, D);
  gemm256_kernel<2><<<dim3(4096 / 256, 4096 / 256, 1), 512, 0, stream>>>(
      h2, w1_t, 4096, 1024, 1024, 0, m1, B1);
  gemm256_kernel<0><<<dim3(1024 / 256, 4096 / 256, 4), 512, 0, stream>>>(
      m1, w2_t, 1024, 4096, 1024, (size_t)4096 * 1024, partW2, nullptr);
  reduce4_kernel<<<2048, 256, 0, stream>>>(partW2, B2, x2, out);
}

// Round 14
// 231.789 us; speedup vs baseline: 1.2207x; 1.0312x over previous
//
#include <hip/hip_runtime.h>
#include <hip/hip_bf16.h>

typedef __attribute__((ext_vector_type(8))) short bf16x8;
typedef __attribute__((ext_vector_type(4))) float f32x4;
typedef __attribute__((ext_vector_type(4))) short s16x4;

#define GLOBAL_AS(p) ((const __attribute__((address_space(1))) void*)(p))
#define LDS_AS(p)    ((__attribute__((address_space(3))) void*)(p))

__device__ __forceinline__ short f2bf(float f) {
  return __builtin_bit_cast(short, __float2bfloat16(f));   // HW RNE cvt
}
__device__ __forceinline__ float bf2f(short s) {
  return __bfloat162float(__builtin_bit_cast(__hip_bfloat16, s));
}

// ---------------- merged weight prep (one dispatch) ----------------
// bid 0..767: pack WQ/WK/WV -> wqkv_t [3072][1024] (Q rows pre-scaled 0.125)
// bid 768..1023: WO^T; 1024..2047: W1^T; 2048..3071: W2^T (fp32 -> bf16)
__global__ __launch_bounds__(256) void prep_kernel(
    const float* __restrict__ WQ, const float* __restrict__ WK,
    const float* __restrict__ WV, short* __restrict__ wqkv_t,
    const float* __restrict__ WO, short* __restrict__ wo_t,
    const float* __restrict__ W1, short* __restrict__ w1_t,
    const float* __restrict__ W2, short* __restrict__ w2_t) {
  __shared__ short Ls[64][66];
  const int tid = threadIdx.x;
  const int l = tid & 63, q4 = tid >> 6;
  const int bid = blockIdx.x;

  if (bid < 768) {
    const int x = bid & 15, y = bid >> 4;     // x: d-block, y: hh|proj
    const int hh = y & 15, proj = y >> 4;
    const float* W = (proj == 0) ? WQ : ((proj == 1) ? WK : WV);
    const float scl = (proj == 0) ? 0.125f : 1.f;
    const int d0 = x * 64;
#pragma unroll
    for (int rep = 0; rep < 16; ++rep) {
      int dd = q4 * 16 + rep;
      Ls[dd][l] = f2bf(W[(size_t)hh * 65536 + (size_t)(d0 + dd) * 64 + l] * scl);
    }
    __syncthreads();
#pragma unroll
    for (int rep = 0; rep < 16; ++rep) {
      int ee = q4 * 16 + rep;
      wqkv_t[(size_t)(proj * 1024 + hh * 64 + ee) * 1024 + d0 + l] = Ls[l][ee];
    }
  } else {
    const float* in; short* out; int R, C, bx, by;
    if (bid < 1024) {
      int idx = bid - 768;  in = WO; out = wo_t; R = 1024; C = 1024;
      bx = idx & 15; by = idx >> 4;
    } else if (bid < 2048) {
      int idx = bid - 1024; in = W1; out = w1_t; R = 1024; C = 4096;
      bx = idx & 63; by = idx >> 6;
    } else {
      int idx = bid - 2048; in = W2; out = w2_t; R = 4096; C = 1024;
      bx = idx & 15; by = idx >> 4;
    }
    const int c0 = bx * 64, r0 = by * 64;
#pragma unroll
    for (int rep = 0; rep < 16; ++rep) {
      int rr = q4 * 16 + rep;
      Ls[rr][l] = f2bf(in[(size_t)(r0 + rr) * C + c0 + l]);
    }
    __syncthreads();
#pragma unroll
    for (int rep = 0; rep < 16; ++rep) {
      int cc = q4 * 16 + rep;
      out[(size_t)(c0 + cc) * R + r0 + l] = Ls[l][cc];
    }
  }
}

// V columns of qkv [S][3072] (cols 2048..3071) -> vt [1024][S], bf16->bf16
__global__ __launch_bounds__(256) void transpose_v_kernel(
    const short* __restrict__ qkv, short* __restrict__ vt, int S) {
  __shared__ short Ls[64][66];
  const int tid = threadIdx.x;
  const int l = tid & 63, q4 = tid >> 6;
  const int s0 = blockIdx.x * 64, e0 = blockIdx.y * 64;
#pragma unroll
  for (int rep = 0; rep < 16; ++rep) {
    int rr = q4 * 16 + rep;
    Ls[rr][l] = qkv[(size_t)(s0 + rr) * 3072 + 2048 + e0 + l];
  }
  __syncthreads();
#pragma unroll
  for (int rep = 0; rep < 16; ++rep) {
    int ee = q4 * 16 + rep;
    vt[(size_t)(e0 + ee) * S + s0 + l] = Ls[l][ee];
  }
}

// ---------------- RMSNorm (fp32 in -> bf16 out) ----------------
__global__ __launch_bounds__(256) void rmsnorm_kernel(
    const float* __restrict__ x, const float* __restrict__ g,
    short* __restrict__ out, int D) {
  const int row = blockIdx.x;
  const int tid = threadIdx.x;
  const float4 xv = *(const float4*)&x[(size_t)row * D + tid * 4];
  float ss = xv.x * xv.x + xv.y * xv.y + xv.z * xv.z + xv.w * xv.w;
#pragma unroll
  for (int off = 32; off; off >>= 1) ss += __shfl_xor(ss, off);
  __shared__ float red[4];
  if ((tid & 63) == 0) red[tid >> 6] = ss;
  __syncthreads();
  float tot = red[0] + red[1] + red[2] + red[3];
  float scale = rsqrtf(tot / (float)D + 1e-6f);
  const float4 gv = *(const float4*)&g[tid * 4];
  s16x4 o;
  o[0] = f2bf(xv.x * scale * gv.x);
  o[1] = f2bf(xv.y * scale * gv.y);
  o[2] = f2bf(xv.z * scale * gv.z);
  o[3] = f2bf(xv.w * scale * gv.w);
  *(s16x4*)&out[(size_t)row * D + tid * 4] = o;
}

// ---------------- 128x64 GEMM (WO): C = A[M,K] x BT[N,K]^T, fp32 out + addend ----------------
__global__ __launch_bounds__(256) void gemm_bt64_kernel(
    const short* __restrict__ A, const short* __restrict__ BT,
    int M, int N, int K,
    float* __restrict__ outF, const float* __restrict__ addend) {
  __shared__ short As[128 * 32];
  __shared__ short Bs[64 * 32];
  const int tid = threadIdx.x;
  const int lane = tid & 63;
  const int wid = tid >> 6;
  const int lrow = lane & 15;
  const int kk = lane >> 4;
  const int row0 = blockIdx.y * 128;
  const int col0 = blockIdx.x * 64;
  const int wm = wid >> 1, wn = wid & 1;

  f32x4 acc[4][2] = {};

  for (int k0 = 0; k0 < K; k0 += 32) {
    __syncthreads();
#pragma unroll
    for (int it = 0; it < 2; ++it) {
      int c = it * 256 + tid;
      int r = c >> 2, c8 = (c & 3) * 8;
      const short* ga = A + (size_t)(row0 + r) * K + k0 + c8;
      short* la = &As[(size_t)(it * 256 + wid * 64) * 8];
      __builtin_amdgcn_global_load_lds(GLOBAL_AS(ga), LDS_AS(la), 16, 0, 0);
    }
    {
      int r = tid >> 2, c8 = (tid & 3) * 8;
      const short* gb = BT + (size_t)(col0 + r) * K + k0 + c8;
      short* lb = &Bs[(size_t)(wid * 64) * 8];
      __builtin_amdgcn_global_load_lds(GLOBAL_AS(gb), LDS_AS(lb), 16, 0, 0);
    }
    __syncthreads();

    bf16x8 a[4], b[2];
#pragma unroll
    for (int i = 0; i < 4; ++i)
      a[i] = *(const bf16x8*)&As[(wm * 64 + i * 16 + lrow) * 32 + kk * 8];
#pragma unroll
    for (int j = 0; j < 2; ++j)
      b[j] = *(const bf16x8*)&Bs[(wn * 32 + j * 16 + lrow) * 32 + kk * 8];
#pragma unroll
    for (int i = 0; i < 4; ++i)
#pragma unroll
      for (int j = 0; j < 2; ++j)
        acc[i][j] = __builtin_amdgcn_mfma_f32_16x16x32_bf16(a[i], b[j], acc[i][j], 0, 0, 0);
  }

#pragma unroll
  for (int i = 0; i < 4; ++i) {
    int row = row0 + wm * 64 + i * 16 + kk * 4;
#pragma unroll
    for (int j = 0; j < 2; ++j) {
      int col = col0 + wn * 32 + j * 16 + lrow;
#pragma unroll
      for (int r = 0; r < 4; ++r) {
        size_t o = (size_t)(row + r) * N + col;
        outF[o] = acc[i][j][r] + addend[o];
      }
    }
  }
}

// ---------------- 256x256 8-phase GEMM (T2+T3+T4+T5), bf16 out ----------------
#define READ_A(buf, mh)                                                      \
  _Pragma("unroll") for (int m4 = 0; m4 < 4; ++m4) {                         \
    int row_ = wm * 128 + ((mh)*4 + m4) * 16 + lrow;                         \
    _Pragma("unroll") for (int k_ = 0; k_ < 2; ++k_) {                       \
      int sl_ = (k_ * 4 + kk) ^ (row_ & 7);                                  \
      aA[m4][k_] = *(const bf16x8*)&lds[buf][0][row_ * 64 + sl_ * 8];        \
    }                                                                        \
  }
#define READ_B2(buf, pr)                                                     \
  _Pragma("unroll") for (int nn = 0; nn < 2; ++nn) {                         \
    int n_ = (pr)*2 + nn;                                                    \
    int row_ = wn * 64 + n_ * 16 + lrow;                                     \
    _Pragma("unroll") for (int k_ = 0; k_ < 2; ++k_) {                       \
      int sl_ = (k_ * 4 + kk) ^ (row_ & 7);                                  \
      bB[n_][k_] = *(const bf16x8*)&lds[buf][1][row_ * 64 + sl_ * 8];        \
    }                                                                        \
  }
#define MFMA16(mh, nh)                                                       \
  _Pragma("unroll") for (int m4 = 0; m4 < 4; ++m4)                           \
  _Pragma("unroll") for (int n2 = 0; n2 < 2; ++n2)                           \
  _Pragma("unroll") for (int k_ = 0; k_ < 2; ++k_)                           \
    acc[(mh)*4 + m4][(nh)*2 + n2] = __builtin_amdgcn_mfma_f32_16x16x32_bf16( \
        aA[m4][k_], bB[(nh)*2 + n2][k_], acc[(mh)*4 + m4][(nh)*2 + n2], 0, 0, 0);
#define STAGE_HALF(buf, mat, half, kt)                                       \
  {                                                                          \
    const short* g_ = ((mat) ? Bb : Ab) + (size_t)((half)*128) * K + (kt)*64;\
    short* l_ = &lds[buf][mat][(half)*8192];                                 \
    _Pragma("unroll") for (int it_ = 0; it_ < 2; ++it_) {                    \
      int ci_ = it_ * 512 + tid;                                             \
      int r_ = ci_ >> 3, sl_ = (ci_ & 7) ^ (r_ & 7);                         \
      __builtin_amdgcn_global_load_lds(GLOBAL_AS(g_ + (size_t)r_ * K + sl_ * 8), \
                                       LDS_AS(l_ + ci_ * 8), 16, 0, 0);      \
    }                                                                        \
  }
#define PH_SYNC1()                                                           \
  __builtin_amdgcn_s_barrier();                                              \
  asm volatile("s_waitcnt lgkmcnt(0)" ::: "memory");                         \
  __builtin_amdgcn_sched_barrier(0);                                         \
  __builtin_amdgcn_s_setprio(1)
#define PH_SYNC2()                                                           \
  __builtin_amdgcn_s_setprio(0);                                             \
  __builtin_amdgcn_s_barrier()
#define PH_SYNC2_VM(n)                                                       \
  __builtin_amdgcn_s_setprio(0);                                             \
  asm volatile("s_waitcnt vmcnt(" #n ")" ::: "memory");                      \
  __builtin_amdgcn_s_barrier()

template <int EPI>
__global__ __launch_bounds__(512, 2) void gemm256_kernel(
    const short* __restrict__ A, const short* __restrict__ BT,
    int N, int K, int kslice, size_t pstride,
    short* __restrict__ outB, const float* __restrict__ bias) {
  __shared__ short lds[2][2][16384];   // [buf][A/B][256 rows x 64 k], 128 KiB
  const int tid = threadIdx.x;
  const int lane = tid & 63, wid = tid >> 6;
  const int lrow = lane & 15, kk = lane >> 4;
  const int wm = wid >> 2, wn = wid & 3;
  const int row0 = blockIdx.y * 256, col0 = blockIdx.x * 256;
  const int kbase = blockIdx.z * kslice;
  const int NT = kslice >> 6;

  const short* Ab = A + (size_t)row0 * K + kbase;
  const short* Bb = BT + (size_t)col0 * K + kbase;

  f32x4 acc[8][4] = {};
  bf16x8 aA[4][2], bB[4][2];

  STAGE_HALF(0, 1, 0, 0); STAGE_HALF(0, 0, 0, 0);
  STAGE_HALF(0, 1, 1, 0); STAGE_HALF(0, 0, 1, 0);
  STAGE_HALF(1, 1, 0, 1); STAGE_HALF(1, 0, 0, 1); STAGE_HALF(1, 0, 1, 1);
  asm volatile("s_waitcnt vmcnt(6)" ::: "memory");
  __builtin_amdgcn_s_barrier();

  const int iters = NT >> 1;
  for (int i = 0; i < iters; ++i) {
    const int t1 = 2 * i + 1;
    int kt2 = 2 * i + 2; if (kt2 >= NT) kt2 -= NT;
    int kt3 = 2 * i + 3; if (kt3 >= NT) kt3 -= NT;
    READ_A(0, 0); READ_B2(0, 0); STAGE_HALF(1, 1, 1, t1);
    PH_SYNC1(); MFMA16(0, 0); PH_SYNC2();
    READ_B2(0, 1);
    PH_SYNC1(); MFMA16(0, 1); PH_SYNC2();
    READ_A(0, 1); STAGE_HALF(0, 1, 0, kt2);
    PH_SYNC1(); MFMA16(1, 0); PH_SYNC2();
    STAGE_HALF(0, 0, 0, kt2);
    PH_SYNC1(); MFMA16(1, 1); PH_SYNC2_VM(4);
    READ_A(1, 0); READ_B2(1, 0); STAGE_HALF(0, 1, 1, kt2);
    PH_SYNC1(); MFMA16(0, 0); PH_SYNC2();
    READ_B2(1, 1); STAGE_HALF(0, 0, 1, kt2);
    PH_SYNC1(); MFMA16(0, 1); PH_SYNC2();
    READ_A(1, 1); STAGE_HALF(1, 1, 0, kt3);
    PH_SYNC1(); MFMA16(1, 0); PH_SYNC2();
    STAGE_HALF(1, 0, 0, kt3); STAGE_HALF(1, 0, 1, kt3);
    PH_SYNC1(); MFMA16(1, 1); PH_SYNC2_VM(6);
  }

  short* ob = outB + (size_t)blockIdx.z * pstride;
#pragma unroll
  for (int m = 0; m < 8; ++m) {
    int row = row0 + wm * 128 + m * 16 + kk * 4;
#pragma unroll
    for (int n = 0; n < 4; ++n) {
      int col = col0 + wn * 64 + n * 16 + lrow;
#pragma unroll
      for (int r = 0; r < 4; ++r) {
        float v = acc[m][n][r];
        size_t o = (size_t)(row + r) * N + col;
        if (EPI == 0) {
          ob[o] = f2bf(v);
        } else {
          v += bias[col];
          ob[o] = f2bf(v > 0.f ? v : 0.f);
        }
      }
    }
  }
}

// out[i] = sum_{s<4} part[s][i] + bias[i % 1024] + addend[i]   (W2 split-K reduce)
__global__ __launch_bounds__(256) void reduce4_kernel(
    const short* __restrict__ part, const float* __restrict__ bias,
    const float* __restrict__ addend, float* __restrict__ out) {
  const size_t MN = (size_t)4096 * 1024;
  size_t i8 = ((size_t)blockIdx.x * 256 + threadIdx.x) * 8;
  bf16x8 p0 = *(const bf16x8*)&part[i8];
  bf16x8 p1 = *(const bf16x8*)&part[MN + i8];
  bf16x8 p2 = *(const bf16x8*)&part[2 * MN + i8];
  bf16x8 p3 = *(const bf16x8*)&part[3 * MN + i8];
  int col = (int)(i8 & 1023);
#pragma unroll
  for (int j = 0; j < 8; ++j) {
    float v = (bf2f(p0[j]) + bf2f(p1[j])) + (bf2f(p2[j]) + bf2f(p3[j]));
    out[i8 + j] = v + bias[col + j] + addend[i8 + j];
  }
}

// ---------------- flash attention v12: KVBLK=64, 3 blocks/CU ----------------
// LDS 48KB (Ks/Vs dbuf 64x64 + per-wave Ps) -> 3 blocks/CU = 24 waves/CU
// (6/SIMD), all 768 blocks co-resident in one block-round. Swapped QK^T +
// packed b64 P stores as v11. 64-key tiles: T = 2*qtile+2, split at qtile+1.
__device__ const unsigned char QT_SLOT[48] = {
    31, 31, 30, 15, 30, 29, 29, 28, 14, 28, 27, 27, 26, 13, 26, 25,
    25, 24, 12, 24, 23, 23, 22, 11, 22, 21, 21, 20, 10, 20, 19, 19,
    18,  9, 18, 17, 17, 16,  8, 16,  7,  6,  5,  4,  3,  2,  1,  0};
__device__ const unsigned char SP_SLOT[48] = {
    0, 1, 0, 0, 1, 0, 1, 0, 0, 1, 0, 1, 0, 0, 1, 0,
    1, 0, 0, 1, 0, 1, 0, 0, 1, 0, 1, 0, 0, 1, 0, 1,
    0, 0, 1, 0, 1, 0, 0, 1, 0, 0, 0, 0, 0, 0, 0, 0};

__global__ __launch_bounds__(512, 6) void attn_kernel(
    const short* __restrict__ QKV, const short* __restrict__ VT,
    float* __restrict__ opart, float* __restrict__ lpart,
    short* __restrict__ O) {
  const int S = 4096;
  __shared__ short Ks[2][64 * 64];
  __shared__ short Vs[2][64 * 64];
  __shared__ short Ps[8][16 * 64];

  const int tid = threadIdx.x;
  const int lane = tid & 63;
  const int w = tid >> 6;                     // 0..7
  const int lrow = lane & 15;
  const int kk = lane >> 4;
  const int bid = blockIdx.x;
  const int h = bid & 15;
  const int slot = bid >> 4;
  const int qtile = QT_SLOT[slot];
  const int sp = SP_SLOT[slot];
  const int T = 2 * qtile + 2;                // total 64-key tiles for this qtile
  const bool split = (qtile >= 16);
  const int half = qtile + 1;
  const int t0 = (split && sp) ? half : 0;
  const int t1 = (split && !sp) ? half : T;
  const int q0 = qtile * 128;
  const int qw = q0 + w * 16;                 // 16 q-rows per wave
  const int myq = qw + lrow;                  // this lane's q row (swapped layout)

  auto stage = [&](int buf, int t) {
    const int kv0 = t * 64;
    // 512 chunks (16B) per matrix; thread tid handles chunk tid of each.
    int krow = tid >> 3;                      // 64 rows x 8 slots
    int ksl = (tid & 7) ^ (krow & 7);
    const short* gk = QKV + (size_t)(kv0 + krow) * 3072 + 1024 + h * 64 + ksl * 8;
    const short* gv = VT + (size_t)(h * 64 + krow) * S + kv0 + ksl * 8;
    __builtin_amdgcn_global_load_lds(GLOBAL_AS(gk),
                                     LDS_AS(&Ks[buf][(w * 64) * 8]), 16, 0, 0);
    __builtin_amdgcn_global_load_lds(GLOBAL_AS(gv),
                                     LDS_AS(&Vs[buf][(w * 64) * 8]), 16, 0, 0);
  };

  bf16x8 qf[2];
#pragma unroll
  for (int half2 = 0; half2 < 2; ++half2)
    qf[half2] = *(const bf16x8*)&QKV[(size_t)(qw + lrow) * 3072 +
                                     h * 64 + half2 * 32 + kk * 8];

  float rs_acc = 0.f;
  f32x4 o_acc[4] = {};

  stage(0, t0);
  __syncthreads();
  int cur = 0;

  for (int t = t0; t < t1; ++t) {
    if (t + 1 < t1) stage(cur ^ 1, t + 1);    // prefetch next 64-key tile

    const int kvc = t * 64;
    if (kvc <= qw + 15) {
      // ---- QK^T (swapped): sc[c] row=key(kk*4+r), col=q(lrow) ----
      bf16x8 kf[4][2];
#pragma unroll
      for (int c = 0; c < 4; ++c)
#pragma unroll
        for (int half2 = 0; half2 < 2; ++half2) {
          int krow = c * 16 + lrow;
          kf[c][half2] = *(const bf16x8*)&Ks[cur][krow * 64 + (((half2 * 4 + kk) ^ (krow & 7)) * 8)];
        }
      f32x4 sc[4];
      __builtin_amdgcn_s_setprio(1);
#pragma unroll
      for (int c = 0; c < 4; ++c) {
        f32x4 z = {};
        z = __builtin_amdgcn_mfma_f32_16x16x32_bf16(kf[c][0], qf[0], z, 0, 0, 0);
        z = __builtin_amdgcn_mfma_f32_16x16x32_bf16(kf[c][1], qf[1], z, 0, 0, 0);
        sc[c] = z;
      }
      __builtin_amdgcn_s_setprio(0);

      // ---- softmax numerator: lane holds 4 consecutive keys for q=myq ----
      if (kvc + 63 <= qw) {
#pragma unroll
        for (int c = 0; c < 4; ++c) {
          float p0 = __expf(sc[c][0]), p1 = __expf(sc[c][1]);
          float p2 = __expf(sc[c][2]), p3 = __expf(sc[c][3]);
          rs_acc += (p0 + p1) + (p2 + p3);
          s16x4 pk;
          pk[0] = f2bf(p0); pk[1] = f2bf(p1); pk[2] = f2bf(p2); pk[3] = f2bf(p3);
          int slot8 = c * 2 + (kk >> 1);
          *(s16x4*)&Ps[w][lrow * 64 + ((slot8 ^ (lrow & 7)) * 8) + (kk & 1) * 4] = pk;
        }
      } else {
#pragma unroll
        for (int c = 0; c < 4; ++c) {
          const int keyb = kvc + c * 16 + kk * 4;
          float pv[4];
#pragma unroll
          for (int r = 0; r < 4; ++r) {
            float p = __expf(sc[c][r]);
            if (keyb + r > myq) p = 0.f;
            pv[r] = p;
          }
          rs_acc += (pv[0] + pv[1]) + (pv[2] + pv[3]);
          s16x4 pk;
          pk[0] = f2bf(pv[0]); pk[1] = f2bf(pv[1]); pk[2] = f2bf(pv[2]); pk[3] = f2bf(pv[3]);
          int slot8 = c * 2 + (kk >> 1);
          *(s16x4*)&Ps[w][lrow * 64 + ((slot8 ^ (lrow & 7)) * 8) + (kk & 1) * 4] = pk;
        }
      }

      // ---- PV over this chunk (8 MFMA) ----
#pragma unroll
      for (int ks = 0; ks < 2; ++ks) {
        bf16x8 pf2, vf[4];
        {
          int qrow = lrow;
          pf2 = *(const bf16x8*)&Ps[w][qrow * 64 + (((ks * 4 + kk) ^ (qrow & 7)) * 8)];
        }
#pragma unroll
        for (int g = 0; g < 4; ++g) {
          int erow = g * 16 + lrow;
          vf[g] = *(const bf16x8*)&Vs[cur][erow * 64 + (((ks * 4 + kk) ^ (erow & 7)) * 8)];
        }
        __builtin_amdgcn_s_setprio(1);
#pragma unroll
        for (int g = 0; g < 4; ++g)
          o_acc[g] = __builtin_amdgcn_mfma_f32_16x16x32_bf16(pf2, vf[g], o_acc[g], 0, 0, 0);
        __builtin_amdgcn_s_setprio(0);
      }
    }

    __syncthreads();                          // drain prefetch + swap
    cur ^= 1;
  }

  // ---- epilogue: 2-shuffle l reduce (lanes with same lrow hold partials) ----
  float l = rs_acc;
  l += __shfl_xor(l, 16);
  l += __shfl_xor(l, 32);

  if (!split) {
    float inv_[4];
#pragma unroll
    for (int r = 0; r < 4; ++r) inv_[r] = 1.f / __shfl(l, kk * 4 + r);
#pragma unroll
    for (int g = 0; g < 4; ++g)
#pragma unroll
      for (int r = 0; r < 4; ++r) {
        int s_idx = qw + kk * 4 + r;
        O[(size_t)s_idx * 1024 + h * 64 + g * 16 + lrow] =
            f2bf(o_acc[g][r] * inv_[r]);
      }
  } else {
    const int pidx = (h * 32 + qtile) * 2 + sp;
    float* op = opart + (size_t)pidx * 8192;  // [128 q][64 d]
    float* lp = lpart + pidx * 128;
    if (lane < 16) lp[w * 16 + lrow] = l;
#pragma unroll
    for (int g = 0; g < 4; ++g)
#pragma unroll
      for (int r = 0; r < 4; ++r)
        op[(w * 16 + kk * 4 + r) * 64 + g * 16 + lrow] = o_acc[g][r];
  }
}

// combine (split qtiles 16..31 only): attn_o[srow][col] = bf16( (o0+o1) / (l0+l1) )
__global__ __launch_bounds__(256) void attn_combine_kernel(
    const float* __restrict__ opart, const float* __restrict__ lpart,
    short* __restrict__ O) {
  size_t e8 = ((size_t)blockIdx.x * 256 + threadIdx.x) * 8 + (size_t)2048 * 1024;
  const int srow = (int)(e8 >> 10);
  const int col = (int)(e8 & 1023);
  const int h = col >> 6, d = col & 63;
  const int qtile = srow >> 7, qr = srow & 127;
  const int pb = (h * 32 + qtile) * 2;
  const float* o0 = opart + (size_t)pb * 8192 + qr * 64 + d;
  const float* o1 = opart + (size_t)(pb + 1) * 8192 + qr * 64 + d;
  float l = lpart[pb * 128 + qr] + lpart[(pb + 1) * 128 + qr];
  float4 a0 = *(const float4*)o0;
  float4 a1 = *(const float4*)(o0 + 4);
  float4 b0 = *(const float4*)o1;
  float4 b1 = *(const float4*)(o1 + 4);
  a0.x += b0.x; a0.y += b0.y; a0.z += b0.z; a0.w += b0.w;
  a1.x += b1.x; a1.y += b1.y; a1.z += b1.z; a1.w += b1.w;
  float inv = 1.f / l;
  bf16x8 o;
  o[0] = f2bf(a0.x * inv); o[1] = f2bf(a0.y * inv);
  o[2] = f2bf(a0.z * inv); o[3] = f2bf(a0.w * inv);
  o[4] = f2bf(a1.x * inv); o[5] = f2bf(a1.y * inv);
  o[6] = f2bf(a1.z * inv); o[7] = f2bf(a1.w * inv);
  *(bf16x8*)&O[e8] = o;
}

// ---------------- launch ----------------
extern "C" void kernel_launch(void* const* d_in, const int* in_sizes, int n_in,
                              void* d_out, int out_size, void* d_ws, size_t ws_size,
                              hipStream_t stream) {
  const float* x  = (const float*)d_in[0];
  const float* g1 = (const float*)d_in[2];
  const float* WQ = (const float*)d_in[3];
  const float* WK = (const float*)d_in[4];
  const float* WV = (const float*)d_in[5];
  const float* WO = (const float*)d_in[6];
  const float* g2 = (const float*)d_in[7];
  const float* W1 = (const float*)d_in[8];
  const float* B1 = (const float*)d_in[9];
  const float* W2 = (const float*)d_in[10];
  const float* B2 = (const float*)d_in[11];
  float* out = (float*)d_out;

  const int S = 4096, D = 1024, H = 16;

  char* ws = (char*)d_ws;
  size_t off = 0;
  auto alloc = [&](size_t bytes) -> void* {
    void* p = ws + off;
    off += (bytes + 255) & ~(size_t)255;
    return p;
  };
  short* h1     = (short*)alloc((size_t)S * D * 2);
  short* wqkv_t = (short*)alloc((size_t)3072 * 1024 * 2);
  short* qkv    = (short*)alloc((size_t)S * 3072 * 2);   // fused QKV output
  short* vt     = (short*)alloc((size_t)1024 * S * 2);
  short* attn_o = (short*)alloc((size_t)S * D * 2);
  short* wo_t   = (short*)alloc((size_t)1024 * 1024 * 2);
  float* x2     = (float*)alloc((size_t)S * D * 4);
  short* h2     = (short*)alloc((size_t)S * D * 2);
  short* w1_t   = (short*)alloc((size_t)4096 * 1024 * 2);
  short* m1     = (short*)alloc((size_t)S * 4096 * 2);
  short* w2_t   = (short*)alloc((size_t)1024 * 4096 * 2);
  short* partW2 = qkv;         // W2 split-K partials (33.55MB) alias qkv(25.2)+vt(8.4) (dead by then)
  float* opart  = (float*)m1;  // attn o-partials (split qtiles only): aliases m1 (dead until W1)
  float* lpart  = (float*)h1;  // attn l-partials: 512KB (h1 dead after QKV gemm)

  // merged weight prep (pack QKV + 3 transposes), one dispatch
  prep_kernel<<<dim3(3072), 256, 0, stream>>>(WQ, WK, WV, wqkv_t,
                                              WO, wo_t, W1, w1_t, W2, w2_t);

  // attention sub-block
  rmsnorm_kernel<<<S, 256, 0, stream>>>(x, g1, h1, D);
  gemm256_kernel<0><<<dim3(3072 / 256, S / 256, 1), 512, 0, stream>>>(
      h1, wqkv_t, 3072, 1024, 1024, 0, qkv, nullptr);
  transpose_v_kernel<<<dim3(S / 64, 1024 / 64), 256, 0, stream>>>(qkv, vt, S);
  attn_kernel<<<dim3(768), 512, 0, stream>>>(qkv, vt, opart, lpart, attn_o);
  attn_combine_kernel<<<dim3((2048 * 1024 / 8) / 256), 256, 0, stream>>>(opart, lpart, attn_o);
  // WO: 128x64 tiles -> 512 blocks, 2 blocks/CU
  gemm_bt64_kernel<<<dim3(1024 / 64, S / 128), 256, 0, stream>>>(
      attn_o, wo_t, S, 1024, 1024, x2, x);

  // MLP sub-block
  rmsnorm_kernel<<<S, 256, 0, stream>>>(x2, g2, h2, D);
  gemm256_kernel<2><<<dim3(4096 / 256, 4096 / 256, 1), 512, 0, stream>>>(
      h2, w1_t, 4096, 1024, 1024, 0, m1, B1);
  gemm256_kernel<0><<<dim3(1024 / 256, 4096 / 256, 4), 512, 0, stream>>>(
      m1, w2_t, 1024, 4096, 1024, (size_t)4096 * 1024, partW2, nullptr);
  reduce4_kernel<<<2048, 256, 0, stream>>>(partW2, B2, x2, out);
}